// Round 1
// baseline (2651.687 us; speedup 1.0000x reference)
//
#include <hip/hip_runtime.h>
#include <math.h>

#define NTRK 256
#define DLAT 128
#define CDIM 7
#define CD2  49
#define CD4  2401
#define NH1  384
#define NH2  256

// ---------------- helpers ----------------

__device__ __forceinline__ float bilin(const float* __restrict__ img, int v, float X, float Y) {
    float vm1 = (float)(v - 1);
    X = fminf(fmaxf(X, 0.f), vm1);
    Y = fminf(fmaxf(Y, 0.f), vm1);
    float xf = floorf(X), yf = floorf(Y);
    int x0 = (int)xf, y0 = (int)yf;
    int x1 = min(x0 + 1, v - 1), y1 = min(y0 + 1, v - 1);
    float wx = X - xf, wy = Y - yf;
    float v00 = img[y0 * v + x0], v01 = img[y0 * v + x1];
    float v10 = img[y1 * v + x0], v11 = img[y1 * v + x1];
    return v00 * (1.f - wy) * (1.f - wx) + v01 * (1.f - wy) * wx
         + v10 * wy * (1.f - wx) + v11 * wy * wx;
}

__device__ __forceinline__ float gelu_tanh(float x) {
    float x3 = x * x * x;
    float u = 0.7978845608028654f * (x + 0.044715f * x3);
    return 0.5f * x * (1.f + tanhf(u));
}

// plane pair (a,b) for k: k0->(0,1) k1->(0,2) k2->(1,2)
__device__ __forceinline__ int plane_a(int k) { return (k == 2) ? 1 : 0; }
__device__ __forceinline__ int plane_b(int k) { return (k == 0) ? 1 : 2; }

// ---------------- 2x2 avg pool ----------------

__global__ __launch_bounds__(256) void pool_kernel(const float* __restrict__ in,
                                                   float* __restrict__ out,
                                                   int vin, int total) {
    int idx = blockIdx.x * 256 + threadIdx.x;
    if (idx >= total) return;
    int vout = vin >> 1;
    int x = idx % vout;
    int t = idx / vout;
    int y = t % vout;
    t /= vout;  // t = frame*384 + channel
    const float* p = in + ((size_t)t * vin + 2 * y) * vin + 2 * x;
    out[idx] = 0.25f * (p[0] + p[1] + p[vin] + p[vin + 1]);
}

// ---------------- track features (frame 0 bilinear) ----------------
// tf_ws layout: [k][n][dd][xy]  (xy = ix*7 + iy)

__global__ __launch_bounds__(256) void tf_kernel(const float* __restrict__ lev,
                                                 const float* __restrict__ coords_init,
                                                 float* __restrict__ tf_ws,
                                                 int v, float inv_scale) {
    int bid = blockIdx.x;         // k*256 + n
    int k = bid >> 8;
    int n = bid & 255;
    float cx = coords_init[n * 3 + plane_a(k)] * inv_scale;
    float cy = coords_init[n * 3 + plane_b(k)] * inv_scale;
    float* dst = tf_ws + ((size_t)(k * NTRK + n)) * DLAT * CD2;
    for (int idx = threadIdx.x; idx < DLAT * CD2; idx += 256) {
        int dd = idx / CD2;
        int xy = idx % CD2;
        int i = xy / CDIM, j = xy % CDIM;
        const float* img = lev + (size_t)(dd * 3 + k) * v * v;  // frame 0
        dst[idx] = bilin(img, v, cx + (float)(i - 3), cy + (float)(j - 3));
    }
}

// ---------------- fused sampling + 49x128x49 correlation ----------------
// one block per (k, s, n); c4_ws row = k*2048 + s*256 + n, 2401 floats

__global__ __launch_bounds__(256) void corr_kernel(const float* __restrict__ lev,
                                                   const float* __restrict__ coords,
                                                   const float* __restrict__ tf_ws,
                                                   float* __restrict__ c4_ws,
                                                   int v, float inv_scale) {
    __shared__ __align__(16) float cf[DLAT * 64];   // [dd][hw] pitch 64
    __shared__ __align__(16) float tfs[DLAT * 64];  // [dd][xy] pitch 64
    int bid = blockIdx.x;
    int k = bid / 2048;
    int sn = bid % 2048;
    int s = sn >> 8;
    int n = sn & 255;
    float cx = coords[sn * 3 + plane_a(k)] * inv_scale;
    float cy = coords[sn * 3 + plane_b(k)] * inv_scale;
    const float* frame = lev + (size_t)(s * 384) * v * v;
    for (int idx = threadIdx.x; idx < DLAT * CD2; idx += 256) {
        int dd = idx / CD2;
        int hw = idx % CD2;
        int h = hw / CDIM, w = hw % CDIM;
        cf[dd * 64 + hw] = bilin(frame + (size_t)(dd * 3 + k) * v * v, v,
                                 cx + (float)(h - 3), cy + (float)(w - 3));
    }
    const float* tfp = tf_ws + ((size_t)(k * NTRK + n)) * DLAT * CD2;
    for (int idx = threadIdx.x; idx < DLAT * CD2; idx += 256) {
        int dd = idx / CD2;
        int xy = idx % CD2;
        tfs[dd * 64 + xy] = tfp[idx];
    }
    __syncthreads();

    int ty = threadIdx.x >> 4, tx = threadIdx.x & 15;
    float acc[4][4] = {{0.f}};
    #pragma unroll 4
    for (int dd = 0; dd < DLAT; ++dd) {
        float4 a4 = *(const float4*)&cf[dd * 64 + 4 * ty];
        float4 b4 = *(const float4*)&tfs[dd * 64 + 4 * tx];
        float aa[4] = {a4.x, a4.y, a4.z, a4.w};
        float bb[4] = {b4.x, b4.y, b4.z, b4.w};
        #pragma unroll
        for (int r = 0; r < 4; ++r)
            #pragma unroll
            for (int c = 0; c < 4; ++c)
                acc[r][c] = fmaf(aa[r], bb[c], acc[r][c]);
    }
    float* crow = c4_ws + (size_t)bid * CD4;
    #pragma unroll
    for (int r = 0; r < 4; ++r) {
        int hw = 4 * ty + r;
        if (hw < CD2) {
            #pragma unroll
            for (int c = 0; c < 4; ++c) {
                int xy = 4 * tx + c;
                if (xy < CD2) crow[hw * CD2 + xy] = acc[r][c];
            }
        }
    }
}

// ---------------- GEMM1: (6144 x 2401) @ (2401 x 384), gelu epilogue ----------------

__global__ __launch_bounds__(256) void gemm1_kernel(const float* __restrict__ A,
                                                    const float* __restrict__ W1,
                                                    const float* __restrict__ b1,
                                                    float* __restrict__ Hout) {
    __shared__ __align__(16) float As[16][68];
    __shared__ __align__(16) float Bs[16][68];
    int m0 = blockIdx.x * 64, n0 = blockIdx.y * 64;
    int tid = threadIdx.x;
    int ty = tid >> 4, tx = tid & 15;
    int lm = tid >> 4, lk = tid & 15;   // A loads
    int lkb = tid >> 6, ln = tid & 63;  // B loads
    float acc[4][4] = {{0.f}};
    for (int k0 = 0; k0 < CD4; k0 += 16) {
        #pragma unroll
        for (int r = 0; r < 4; ++r) {
            int kk = k0 + lk;
            As[lk][lm + 16 * r] = (kk < CD4) ? A[(size_t)(m0 + lm + 16 * r) * CD4 + kk] : 0.f;
        }
        #pragma unroll
        for (int r = 0; r < 4; ++r) {
            int kk = k0 + lkb + 4 * r;
            Bs[lkb + 4 * r][ln] = (kk < CD4) ? W1[(size_t)kk * NH1 + n0 + ln] : 0.f;
        }
        __syncthreads();
        #pragma unroll
        for (int kk = 0; kk < 16; ++kk) {
            float4 a4 = *(const float4*)&As[kk][4 * ty];
            float4 b4 = *(const float4*)&Bs[kk][4 * tx];
            float aa[4] = {a4.x, a4.y, a4.z, a4.w};
            float bb[4] = {b4.x, b4.y, b4.z, b4.w};
            #pragma unroll
            for (int r = 0; r < 4; ++r)
                #pragma unroll
                for (int c = 0; c < 4; ++c)
                    acc[r][c] = fmaf(aa[r], bb[c], acc[r][c]);
        }
        __syncthreads();
    }
    #pragma unroll
    for (int r = 0; r < 4; ++r) {
        int m = m0 + 4 * ty + r;
        #pragma unroll
        for (int c = 0; c < 4; ++c) {
            int n = n0 + 4 * tx + c;
            Hout[(size_t)m * NH1 + n] = gelu_tanh(acc[r][c] + b1[n]);
        }
    }
}

// ---------------- GEMM2: (2048 x 1152) @ stacked w2, +3*b2, writes out slice ----------------

__global__ __launch_bounds__(256) void gemm2_kernel(const float* __restrict__ Hin,
                                                    const float* __restrict__ W2,
                                                    const float* __restrict__ b2,
                                                    float* __restrict__ out,
                                                    int level) {
    __shared__ __align__(16) float As[16][68];
    __shared__ __align__(16) float Bs[16][68];
    int m0 = blockIdx.x * 64, n0 = blockIdx.y * 64;
    int tid = threadIdx.x;
    int ty = tid >> 4, tx = tid & 15;
    int lm = tid >> 4, lk = tid & 15;
    int lkb = tid >> 6, ln = tid & 63;
    float acc[4][4] = {{0.f}};
    for (int k0 = 0; k0 < 3 * NH1; k0 += 16) {
        int plane = k0 / NH1;
        int jbase = k0 - plane * NH1;
        #pragma unroll
        for (int r = 0; r < 4; ++r) {
            As[lk][lm + 16 * r] =
                Hin[((size_t)plane * 2048 + m0 + lm + 16 * r) * NH1 + jbase + lk];
        }
        #pragma unroll
        for (int r = 0; r < 4; ++r) {
            Bs[lkb + 4 * r][ln] = W2[(size_t)(jbase + lkb + 4 * r) * NH2 + n0 + ln];
        }
        __syncthreads();
        #pragma unroll
        for (int kk = 0; kk < 16; ++kk) {
            float4 a4 = *(const float4*)&As[kk][4 * ty];
            float4 b4 = *(const float4*)&Bs[kk][4 * tx];
            float aa[4] = {a4.x, a4.y, a4.z, a4.w};
            float bb[4] = {b4.x, b4.y, b4.z, b4.w};
            #pragma unroll
            for (int r = 0; r < 4; ++r)
                #pragma unroll
                for (int c = 0; c < 4; ++c)
                    acc[r][c] = fmaf(aa[r], bb[c], acc[r][c]);
        }
        __syncthreads();
    }
    #pragma unroll
    for (int r = 0; r < 4; ++r) {
        int m = m0 + 4 * ty + r;  // sn
        #pragma unroll
        for (int c = 0; c < 4; ++c) {
            int n = n0 + 4 * tx + c;
            out[(size_t)m * 1024 + level * NH2 + n] = acc[r][c] + 3.f * b2[n];
        }
    }
}

// ---------------- launch ----------------

extern "C" void kernel_launch(void* const* d_in, const int* in_sizes, int n_in,
                              void* d_out, int out_size, void* d_ws, size_t ws_size,
                              hipStream_t stream) {
    const float* coords      = (const float*)d_in[0];
    const float* coords_init = (const float*)d_in[1];
    const float* fp0         = (const float*)d_in[2];
    const float* w1          = (const float*)d_in[3];
    const float* b1          = (const float*)d_in[4];
    const float* w2          = (const float*)d_in[5];
    const float* b2          = (const float*)d_in[6];
    float* out = (float*)d_out;
    float* ws  = (float*)d_ws;

    const size_t SZ_PYR1 = (size_t)8 * 384 * 48 * 48;  // 7077888
    const size_t SZ_PYR2 = (size_t)8 * 384 * 24 * 24;  // 1769472
    const size_t SZ_PYR3 = (size_t)8 * 384 * 12 * 12;  // 442368
    const size_t SZ_TF   = (size_t)3 * NTRK * DLAT * CD2;
    const size_t SZ_C4   = (size_t)3 * 2048 * CD4;

    float* pyr1  = ws;
    float* pyr2  = pyr1 + SZ_PYR1;
    float* pyr3  = pyr2 + SZ_PYR2;
    float* tf_ws = pyr3 + SZ_PYR3;
    float* c4_ws = tf_ws + SZ_TF;
    float* h_ws  = c4_ws + SZ_C4;

    pool_kernel<<<(int)((SZ_PYR1 + 255) / 256), 256, 0, stream>>>(fp0, pyr1, 96, (int)SZ_PYR1);
    pool_kernel<<<(int)((SZ_PYR2 + 255) / 256), 256, 0, stream>>>(pyr1, pyr2, 48, (int)SZ_PYR2);
    pool_kernel<<<(int)((SZ_PYR3 + 255) / 256), 256, 0, stream>>>(pyr2, pyr3, 24, (int)SZ_PYR3);

    const float* levs[4] = {fp0, pyr1, pyr2, pyr3};
    const int vs[4] = {96, 48, 24, 12};
    for (int i = 0; i < 4; ++i) {
        float inv = 1.f / (float)(1 << i);
        tf_kernel<<<3 * NTRK, 256, 0, stream>>>(levs[i], coords_init, tf_ws, vs[i], inv);
        corr_kernel<<<3 * 2048, 256, 0, stream>>>(levs[i], coords, tf_ws, c4_ws, vs[i], inv);
        gemm1_kernel<<<dim3(96, 6), 256, 0, stream>>>(c4_ws, w1, b1, h_ws);
        gemm2_kernel<<<dim3(32, 4), 256, 0, stream>>>(h_ws, w2, b2, out, i);
    }
}

// Round 2
// 1195.183 us; speedup vs baseline: 2.2186x; 2.2186x over previous
//
#include <hip/hip_runtime.h>
#include <hip/hip_bf16.h>
#include <math.h>

#define NTRK 256
#define DLAT 128
#define CDIM 7
#define CD2  49
#define CD4  2401
#define NH1  384
#define NH2  256
#define LDK  2432   // CD4 padded to multiple of 32 (76*32)

typedef __attribute__((ext_vector_type(8))) short short8;
typedef __attribute__((ext_vector_type(4))) float f32x4;

// ---------------- helpers ----------------

__device__ __forceinline__ float bilin(const float* __restrict__ img, int v, float X, float Y) {
    float vm1 = (float)(v - 1);
    X = fminf(fmaxf(X, 0.f), vm1);
    Y = fminf(fmaxf(Y, 0.f), vm1);
    float xf = floorf(X), yf = floorf(Y);
    int x0 = (int)xf, y0 = (int)yf;
    int x1 = min(x0 + 1, v - 1), y1 = min(y0 + 1, v - 1);
    float wx = X - xf, wy = Y - yf;
    float v00 = img[y0 * v + x0], v01 = img[y0 * v + x1];
    float v10 = img[y1 * v + x0], v11 = img[y1 * v + x1];
    return v00 * (1.f - wy) * (1.f - wx) + v01 * (1.f - wy) * wx
         + v10 * wy * (1.f - wx) + v11 * wy * wx;
}

__device__ __forceinline__ float gelu_tanh(float x) {
    float x3 = x * x * x;
    float u = 0.7978845608028654f * (x + 0.044715f * x3);
    return 0.5f * x * (1.f + tanhf(u));
}

__device__ __forceinline__ int plane_a(int k) { return (k == 2) ? 1 : 0; }
__device__ __forceinline__ int plane_b(int k) { return (k == 0) ? 1 : 2; }

// async global->LDS, 16B per lane; LDS dst must be wave-uniform base
__device__ __forceinline__ void gload16(const void* g, void* l) {
    __builtin_amdgcn_global_load_lds(
        (const __attribute__((address_space(1))) unsigned int*)g,
        (__attribute__((address_space(3))) unsigned int*)l,
        16, 0, 0);
}

// ---------------- 2x2 avg pool ----------------

__global__ __launch_bounds__(256) void pool_kernel(const float* __restrict__ in,
                                                   float* __restrict__ out,
                                                   int vin, int total) {
    int idx = blockIdx.x * 256 + threadIdx.x;
    if (idx >= total) return;
    int vout = vin >> 1;
    int x = idx % vout;
    int t = idx / vout;
    int y = t % vout;
    t /= vout;  // t = frame*384 + channel
    const float* p = in + ((size_t)t * vin + 2 * y) * vin + 2 * x;
    out[idx] = 0.25f * (p[0] + p[1] + p[vin] + p[vin + 1]);
}

// ---------------- track features (frame 0 bilinear) ----------------
// tf_ws layout: [k][n][dd][xy]  (xy = ix*7 + iy), fp32

__global__ __launch_bounds__(256) void tf_kernel(const float* __restrict__ lev,
                                                 const float* __restrict__ coords_init,
                                                 float* __restrict__ tf_ws,
                                                 int v, float inv_scale) {
    int bid = blockIdx.x;         // k*256 + n
    int k = bid >> 8;
    int n = bid & 255;
    float cx = coords_init[n * 3 + plane_a(k)] * inv_scale;
    float cy = coords_init[n * 3 + plane_b(k)] * inv_scale;
    float* dst = tf_ws + ((size_t)(k * NTRK + n)) * DLAT * CD2;
    for (int idx = threadIdx.x; idx < DLAT * CD2; idx += 256) {
        int dd = idx / CD2;
        int xy = idx % CD2;
        int i = xy / CDIM, j = xy % CDIM;
        const float* img = lev + (size_t)(dd * 3 + k) * v * v;  // frame 0
        dst[idx] = bilin(img, v, cx + (float)(i - 3), cy + (float)(j - 3));
    }
}

// ---------------- fused sampling + 49x128x49 correlation, bf16 out ----------------
// one block per (k, s, n); c4b row = k*2048 + s*256 + n, pitch LDK (pad zeroed)

__global__ __launch_bounds__(256) void corr_kernel(const float* __restrict__ lev,
                                                   const float* __restrict__ coords,
                                                   const float* __restrict__ tf_ws,
                                                   __hip_bfloat16* __restrict__ c4b,
                                                   int v, float inv_scale) {
    __shared__ __align__(16) float cf[DLAT * 64];   // [dd][hw] pitch 64
    __shared__ __align__(16) float tfs[DLAT * 64];  // [dd][xy] pitch 64
    int bid = blockIdx.x;
    int k = bid / 2048;
    int sn = bid % 2048;
    int s = sn >> 8;
    float cx = coords[sn * 3 + plane_a(k)] * inv_scale;
    float cy = coords[sn * 3 + plane_b(k)] * inv_scale;
    const float* frame = lev + (size_t)(s * 384) * v * v;
    for (int idx = threadIdx.x; idx < DLAT * CD2; idx += 256) {
        int dd = idx / CD2;
        int hw = idx % CD2;
        int h = hw / CDIM, w = hw % CDIM;
        cf[dd * 64 + hw] = bilin(frame + (size_t)(dd * 3 + k) * v * v, v,
                                 cx + (float)(h - 3), cy + (float)(w - 3));
    }
    {
        int n = bid & 255;
        const float* tfp = tf_ws + ((size_t)(k * NTRK + n)) * DLAT * CD2;
        for (int idx = threadIdx.x; idx < DLAT * CD2; idx += 256) {
            int dd = idx / CD2;
            int xy = idx % CD2;
            tfs[dd * 64 + xy] = tfp[idx];
        }
    }
    __syncthreads();

    int ty = threadIdx.x >> 4, tx = threadIdx.x & 15;
    float acc[4][4] = {{0.f}};
    #pragma unroll 4
    for (int dd = 0; dd < DLAT; ++dd) {
        float4 a4 = *(const float4*)&cf[dd * 64 + 4 * ty];
        float4 b4 = *(const float4*)&tfs[dd * 64 + 4 * tx];
        float aa[4] = {a4.x, a4.y, a4.z, a4.w};
        float bb[4] = {b4.x, b4.y, b4.z, b4.w};
        #pragma unroll
        for (int r = 0; r < 4; ++r)
            #pragma unroll
            for (int c = 0; c < 4; ++c)
                acc[r][c] = fmaf(aa[r], bb[c], acc[r][c]);
    }
    __hip_bfloat16* crow = c4b + (size_t)bid * LDK;
    #pragma unroll
    for (int r = 0; r < 4; ++r) {
        int hw = 4 * ty + r;
        if (hw < CD2) {
            #pragma unroll
            for (int c = 0; c < 4; ++c) {
                int xy = 4 * tx + c;
                if (xy < CD2) crow[hw * CD2 + xy] = __float2bfloat16(acc[r][c]);
            }
        }
    }
    if (threadIdx.x < LDK - CD4) crow[CD4 + threadIdx.x] = __float2bfloat16(0.f);
}

// ---------------- weight prep: transpose + bf16 ----------------

__global__ __launch_bounds__(256) void prep_w1t(const float* __restrict__ w1,
                                                __hip_bfloat16* __restrict__ w1t) {
    int idx = blockIdx.x * 256 + threadIdx.x;  // n*LDK + kk
    if (idx >= NH1 * LDK) return;
    int n = idx / LDK, kk = idx - n * LDK;
    float v = (kk < CD4) ? w1[(size_t)kk * NH1 + n] : 0.f;
    w1t[idx] = __float2bfloat16(v);
}

__global__ __launch_bounds__(256) void prep_w2t(const float* __restrict__ w2,
                                                __hip_bfloat16* __restrict__ w2t) {
    int idx = blockIdx.x * 256 + threadIdx.x;  // n*NH1 + j
    if (idx >= NH2 * NH1) return;
    int n = idx / NH1, j = idx - n * NH1;
    w2t[idx] = __float2bfloat16(w2[(size_t)j * NH2 + n]);
}

// ---------------- GEMM1 MFMA: (6144 x LDK) @ w1t^T -> gelu -> H bf16 ----------------
// BM=128 BN=64 BK=32, 4 waves (2x2), wave tile 64x32 = 4x2 frags of 16x16

__global__ __launch_bounds__(256) void gemm1_mfma(
    const __hip_bfloat16* __restrict__ A,    // [6144][LDK]
    const __hip_bfloat16* __restrict__ Bt,   // [NH1][LDK]
    const float* __restrict__ b1,
    __hip_bfloat16* __restrict__ H) {        // [6144][NH1]
    __shared__ __align__(16) char smem[12288];
    char* Asm = smem;          // 128 rows x 64B
    char* Bsm = smem + 8192;   // 64 rows x 64B
    const int m0 = blockIdx.x * 128, n0 = blockIdx.y * 64;
    const int tid = threadIdx.x;
    const int w = tid >> 6, l = tid & 63;
    const int wr = w >> 1, wc = w & 1;
    const int l15 = l & 15, l4 = l >> 4;
    f32x4 acc[4][2];
    #pragma unroll
    for (int m = 0; m < 4; ++m)
        #pragma unroll
        for (int n = 0; n < 2; ++n) acc[m][n] = (f32x4){0.f, 0.f, 0.f, 0.f};
    const char* Ag = (const char*)(A + (size_t)(m0 + (tid >> 2)) * LDK) + (tid & 3) * 16;
    const char* Bg = (const char*)(Bt + (size_t)(n0 + (tid >> 2)) * LDK) + (tid & 3) * 16;
    char* AsmW = Asm + w * 1024;
    char* BsmW = Bsm + w * 1024;
    for (int kb = 0; kb < LDK * 2; kb += 64) {  // byte offset along K
        gload16(Ag + kb, AsmW);                               // rows 0..63
        gload16(Ag + (size_t)64 * LDK * 2 + kb, AsmW + 4096); // rows 64..127
        gload16(Bg + kb, BsmW);
        __syncthreads();
        short8 af[4], bfr[2];
        #pragma unroll
        for (int m = 0; m < 4; ++m)
            af[m] = *(const short8*)(Asm + (wr * 64 + m * 16 + l15) * 64 + l4 * 16);
        #pragma unroll
        for (int n = 0; n < 2; ++n)
            bfr[n] = *(const short8*)(Bsm + (wc * 32 + n * 16 + l15) * 64 + l4 * 16);
        #pragma unroll
        for (int m = 0; m < 4; ++m)
            #pragma unroll
            for (int n = 0; n < 2; ++n)
                acc[m][n] = __builtin_amdgcn_mfma_f32_16x16x32_bf16(af[m], bfr[n], acc[m][n], 0, 0, 0);
        __syncthreads();
    }
    #pragma unroll
    for (int m = 0; m < 4; ++m) {
        int row = m0 + wr * 64 + m * 16 + l4 * 4;
        #pragma unroll
        for (int n = 0; n < 2; ++n) {
            int col = n0 + wc * 32 + n * 16 + l15;
            float bias = b1[col];
            #pragma unroll
            for (int j = 0; j < 4; ++j)
                H[(size_t)(row + j) * NH1 + col] = __float2bfloat16(gelu_tanh(acc[m][n][j] + bias));
        }
    }
}

// ---------------- GEMM2 MFMA: (2048 x 1152) @ stacked w2t -> out slice ----------------
// BM=64 BN=64 BK=32, 4 waves (2x2), wave tile 32x32 = 2x2 frags

__global__ __launch_bounds__(256) void gemm2_mfma(
    const __hip_bfloat16* __restrict__ Hin,  // [3*2048][NH1]
    const __hip_bfloat16* __restrict__ Bt,   // [NH2][NH1]
    const float* __restrict__ b2,
    float* __restrict__ out, int level) {
    __shared__ __align__(16) char smem[8192];
    char* Asm = smem;         // 64 rows x 64B
    char* Bsm = smem + 4096;
    const int m0 = blockIdx.x * 64, n0 = blockIdx.y * 64;
    const int tid = threadIdx.x;
    const int w = tid >> 6, l = tid & 63;
    const int wr = w >> 1, wc = w & 1;
    const int l15 = l & 15, l4 = l >> 4;
    f32x4 acc[2][2];
    #pragma unroll
    for (int m = 0; m < 2; ++m)
        #pragma unroll
        for (int n = 0; n < 2; ++n) acc[m][n] = (f32x4){0.f, 0.f, 0.f, 0.f};
    const char* Bg = (const char*)(Bt + (size_t)(n0 + (tid >> 2)) * NH1) + (tid & 3) * 16;
    char* AsmW = Asm + w * 1024;
    char* BsmW = Bsm + w * 1024;
    for (int p = 0; p < 3; ++p) {
        const char* Ag = (const char*)(Hin + (size_t)(p * 2048 + m0 + (tid >> 2)) * NH1) + (tid & 3) * 16;
        for (int jb = 0; jb < NH1 * 2; jb += 64) {
            gload16(Ag + jb, AsmW);
            gload16(Bg + jb, BsmW);
            __syncthreads();
            short8 af[2], bfr[2];
            #pragma unroll
            for (int m = 0; m < 2; ++m)
                af[m] = *(const short8*)(Asm + (wr * 32 + m * 16 + l15) * 64 + l4 * 16);
            #pragma unroll
            for (int n = 0; n < 2; ++n)
                bfr[n] = *(const short8*)(Bsm + (wc * 32 + n * 16 + l15) * 64 + l4 * 16);
            #pragma unroll
            for (int m = 0; m < 2; ++m)
                #pragma unroll
                for (int n = 0; n < 2; ++n)
                    acc[m][n] = __builtin_amdgcn_mfma_f32_16x16x32_bf16(af[m], bfr[n], acc[m][n], 0, 0, 0);
            __syncthreads();
        }
    }
    #pragma unroll
    for (int m = 0; m < 2; ++m) {
        int row = m0 + wr * 32 + m * 16 + l4 * 4;
        #pragma unroll
        for (int n = 0; n < 2; ++n) {
            int col = n0 + wc * 32 + n * 16 + l15;
            float bias3 = 3.f * b2[col];
            #pragma unroll
            for (int j = 0; j < 4; ++j)
                out[(size_t)(row + j) * 1024 + level * NH2 + col] = acc[m][n][j] + bias3;
        }
    }
}

// ---------------- launch ----------------

extern "C" void kernel_launch(void* const* d_in, const int* in_sizes, int n_in,
                              void* d_out, int out_size, void* d_ws, size_t ws_size,
                              hipStream_t stream) {
    const float* coords      = (const float*)d_in[0];
    const float* coords_init = (const float*)d_in[1];
    const float* fp0         = (const float*)d_in[2];
    const float* w1          = (const float*)d_in[3];
    const float* b1          = (const float*)d_in[4];
    const float* w2          = (const float*)d_in[5];
    const float* b2          = (const float*)d_in[6];
    float* out = (float*)d_out;
    char* ws = (char*)d_ws;

    const size_t SZ_PYR1 = (size_t)8 * 384 * 48 * 48;  // elems
    const size_t SZ_PYR2 = (size_t)8 * 384 * 24 * 24;
    const size_t SZ_PYR3 = (size_t)8 * 384 * 12 * 12;
    const size_t SZ_TF   = (size_t)3 * NTRK * DLAT * CD2;

    float* pyr1  = (float*)ws;                       ws += SZ_PYR1 * 4;
    float* pyr2  = (float*)ws;                       ws += SZ_PYR2 * 4;
    float* pyr3  = (float*)ws;                       ws += SZ_PYR3 * 4;
    float* tf_ws = (float*)ws;                       ws += SZ_TF * 4;
    __hip_bfloat16* c4b  = (__hip_bfloat16*)ws;      ws += (size_t)6144 * LDK * 2;
    __hip_bfloat16* h_ws = (__hip_bfloat16*)ws;      ws += (size_t)6144 * NH1 * 2;
    __hip_bfloat16* w1t  = (__hip_bfloat16*)ws;      ws += (size_t)NH1 * LDK * 2;
    __hip_bfloat16* w2t  = (__hip_bfloat16*)ws;      ws += (size_t)NH2 * NH1 * 2;

    prep_w1t<<<(NH1 * LDK + 255) / 256, 256, 0, stream>>>(w1, w1t);
    prep_w2t<<<(NH2 * NH1 + 255) / 256, 256, 0, stream>>>(w2, w2t);

    pool_kernel<<<(int)((SZ_PYR1 + 255) / 256), 256, 0, stream>>>(fp0, pyr1, 96, (int)SZ_PYR1);
    pool_kernel<<<(int)((SZ_PYR2 + 255) / 256), 256, 0, stream>>>(pyr1, pyr2, 48, (int)SZ_PYR2);
    pool_kernel<<<(int)((SZ_PYR3 + 255) / 256), 256, 0, stream>>>(pyr2, pyr3, 24, (int)SZ_PYR3);

    const float* levs[4] = {fp0, pyr1, pyr2, pyr3};
    const int vs[4] = {96, 48, 24, 12};
    for (int i = 0; i < 4; ++i) {
        float inv = 1.f / (float)(1 << i);
        tf_kernel<<<3 * NTRK, 256, 0, stream>>>(levs[i], coords_init, tf_ws, vs[i], inv);
        corr_kernel<<<3 * 2048, 256, 0, stream>>>(levs[i], coords, tf_ws, c4b, vs[i], inv);
        gemm1_mfma<<<dim3(48, 6), 256, 0, stream>>>(c4b, w1t, b1, h_ws);
        gemm2_mfma<<<dim3(32, 4), 256, 0, stream>>>(h_ws, w2t, b2, out, i);
    }
}

// Round 3
// 1002.758 us; speedup vs baseline: 2.6444x; 1.1919x over previous
//
#include <hip/hip_runtime.h>
#include <hip/hip_bf16.h>
#include <math.h>

#define NTRK 256
#define DLAT 128
#define CDIM 7
#define CD2  49
#define CD4  2401
#define NH1  384
#define NH2  256
#define LDK  2432    // CD4 padded to multiple of 32
#define PITCHB 272   // corr LDS row pitch in bytes (136 bf16) -> +16B skew per row

typedef __attribute__((ext_vector_type(8))) short short8;
typedef __attribute__((ext_vector_type(4))) float f32x4;

// ---------------- helpers ----------------

__device__ __forceinline__ float bilin(const float* __restrict__ img, int v, float X, float Y) {
    float vm1 = (float)(v - 1);
    X = fminf(fmaxf(X, 0.f), vm1);
    Y = fminf(fmaxf(Y, 0.f), vm1);
    float xf = floorf(X), yf = floorf(Y);
    int x0 = (int)xf, y0 = (int)yf;
    int x1 = min(x0 + 1, v - 1), y1 = min(y0 + 1, v - 1);
    float wx = X - xf, wy = Y - yf;
    float v00 = img[y0 * v + x0], v01 = img[y0 * v + x1];
    float v10 = img[y1 * v + x0], v11 = img[y1 * v + x1];
    return v00 * (1.f - wy) * (1.f - wx) + v01 * (1.f - wy) * wx
         + v10 * wy * (1.f - wx) + v11 * wy * wx;
}

__device__ __forceinline__ float gelu_tanh(float x) {
    float x3 = x * x * x;
    float u = 0.7978845608028654f * (x + 0.044715f * x3);
    return 0.5f * x * (1.f + tanhf(u));
}

__device__ __forceinline__ int plane_a(int k) { return (k == 2) ? 1 : 0; }
__device__ __forceinline__ int plane_b(int k) { return (k == 0) ? 1 : 2; }

// async global->LDS, 16B per lane; LDS dst must be wave-uniform base
__device__ __forceinline__ void gload16(const void* g, void* l) {
    __builtin_amdgcn_global_load_lds(
        (const __attribute__((address_space(1))) unsigned int*)g,
        (__attribute__((address_space(3))) unsigned int*)l,
        16, 0, 0);
}

// ---------------- 2x2 avg pool ----------------

__global__ __launch_bounds__(256) void pool_kernel(const float* __restrict__ in,
                                                   float* __restrict__ out,
                                                   int vin, int total) {
    int idx = blockIdx.x * 256 + threadIdx.x;
    if (idx >= total) return;
    int vout = vin >> 1;
    int x = idx % vout;
    int t = idx / vout;
    int y = t % vout;
    t /= vout;  // t = frame*384 + channel
    const float* p = in + ((size_t)t * vin + 2 * y) * vin + 2 * x;
    out[idx] = 0.25f * (p[0] + p[1] + p[vin] + p[vin + 1]);
}

// ---------------- track features (frame 0 bilinear), bf16, [k][n][xy][dd] ----------------

__global__ __launch_bounds__(256) void tf_kernel(const float* __restrict__ lev,
                                                 const float* __restrict__ coords_init,
                                                 __hip_bfloat16* __restrict__ tfb,
                                                 int v, float inv_scale) {
    int bid = blockIdx.x;         // k*256 + n
    int k = bid >> 8;
    int n = bid & 255;
    float cx = coords_init[n * 3 + plane_a(k)] * inv_scale;
    float cy = coords_init[n * 3 + plane_b(k)] * inv_scale;
    __hip_bfloat16* dst = tfb + ((size_t)(k * NTRK + n)) * (DLAT * CD2);
    for (int idx = threadIdx.x; idx < DLAT * CD2; idx += 256) {
        int xy = idx >> 7;           // 0..48
        int dd = idx & 127;
        int i = xy / CDIM, j = xy % CDIM;
        const float* img = lev + (size_t)(dd * 3 + k) * v * v;  // frame 0
        dst[idx] = __float2bfloat16(bilin(img, v, cx + (float)(i - 3), cy + (float)(j - 3)));
    }
}

// ---------------- fused sampling + MFMA correlation ----------------
// one block per (k, s, n); C = cf(49x128) @ tf^T(128x49), padded to 64x64
// c4b row = bid, pitch LDK, bf16, pad zeroed

__global__ __launch_bounds__(256) void corr_mfma(const float* __restrict__ lev,
                                                 const float* __restrict__ coords,
                                                 const __hip_bfloat16* __restrict__ tfb,
                                                 __hip_bfloat16* __restrict__ c4b,
                                                 int v, float inv_scale) {
    __shared__ __align__(16) char cfs[64 * PITCHB];  // A: [hw][dd] bf16, skewed pitch
    __shared__ __align__(16) char tfs[64 * PITCHB];  // B: [xy][dd] bf16, skewed pitch
    const int bid = blockIdx.x;
    const int k = bid / 2048;
    const int sn = bid % 2048;
    const int s = sn >> 8;
    const int n = bid & 255;
    const int tid = threadIdx.x;
    float cx = coords[sn * 3 + plane_a(k)] * inv_scale;
    float cy = coords[sn * 3 + plane_b(k)] * inv_scale;
    const float* frame = lev + (size_t)(s * 384 + k) * v * v;  // channel dd at + dd*3*v*v
    const int vv3 = 3 * v * v;

    // stage tf: 49 rows x 256B = 784 x 16B chunks
    const short8* tfg = (const short8*)(tfb + ((size_t)(k * NTRK + n)) * (DLAT * CD2));
    for (int idx = tid; idx < 784; idx += 256) {
        int row = idx >> 4, c16 = idx & 15;
        *(short8*)(tfs + row * PITCHB + c16 * 16) = tfg[idx];
    }
    // sample cf: idx = dd*49 + hw (hw-fast: one wave covers a 7x7 window per channel)
    for (int idx = tid; idx < DLAT * CD2; idx += 256) {
        int dd = idx / CD2;
        int hw = idx - dd * CD2;
        int h = hw / CDIM, w = hw - h * CDIM;
        float val = bilin(frame + (size_t)dd * vv3, v,
                          cx + (float)(h - 3), cy + (float)(w - 3));
        *(__hip_bfloat16*)(cfs + hw * PITCHB + dd * 2) = __float2bfloat16(val);
    }
    __syncthreads();

    const int w4 = tid >> 6, l = tid & 63;
    const int l15 = l & 15, l4 = l >> 4;
    f32x4 acc[4];
    #pragma unroll
    for (int nt = 0; nt < 4; ++nt) acc[nt] = (f32x4){0.f, 0.f, 0.f, 0.f};
    #pragma unroll
    for (int ks = 0; ks < 4; ++ks) {
        short8 af = *(const short8*)(cfs + (16 * w4 + l15) * PITCHB + ks * 64 + l4 * 16);
        #pragma unroll
        for (int nt = 0; nt < 4; ++nt) {
            short8 bf = *(const short8*)(tfs + (16 * nt + l15) * PITCHB + ks * 64 + l4 * 16);
            acc[nt] = __builtin_amdgcn_mfma_f32_16x16x32_bf16(af, bf, acc[nt], 0, 0, 0);
        }
    }
    __hip_bfloat16* crow = c4b + (size_t)bid * LDK;
    const int row0 = 16 * w4 + l4 * 4;
    #pragma unroll
    for (int nt = 0; nt < 4; ++nt) {
        int col = nt * 16 + l15;
        if (col < CD2) {
            #pragma unroll
            for (int j = 0; j < 4; ++j) {
                int row = row0 + j;
                if (row < CD2) crow[row * CD2 + col] = __float2bfloat16(acc[nt][j]);
            }
        }
    }
    if (tid < LDK - CD4) crow[CD4 + tid] = __float2bfloat16(0.f);
}

// ---------------- weight prep: transpose + bf16 ----------------

__global__ __launch_bounds__(256) void prep_w1t(const float* __restrict__ w1,
                                                __hip_bfloat16* __restrict__ w1t) {
    int idx = blockIdx.x * 256 + threadIdx.x;  // n*LDK + kk
    if (idx >= NH1 * LDK) return;
    int n = idx / LDK, kk = idx - n * LDK;
    float v = (kk < CD4) ? w1[(size_t)kk * NH1 + n] : 0.f;
    w1t[idx] = __float2bfloat16(v);
}

__global__ __launch_bounds__(256) void prep_w2t(const float* __restrict__ w2,
                                                __hip_bfloat16* __restrict__ w2t) {
    int idx = blockIdx.x * 256 + threadIdx.x;  // n*NH1 + j
    if (idx >= NH2 * NH1) return;
    int n = idx / NH1, j = idx - n * NH1;
    w2t[idx] = __float2bfloat16(w2[(size_t)j * NH2 + n]);
}

// ---------------- GEMM1 MFMA: (6144 x LDK) @ w1t^T -> gelu -> H bf16 ----------------
// BM=128 BN=64 BK=32, 4 waves (2x2), wave tile 64x32 = 4x2 frags of 16x16

__global__ __launch_bounds__(256) void gemm1_mfma(
    const __hip_bfloat16* __restrict__ A,    // [6144][LDK]
    const __hip_bfloat16* __restrict__ Bt,   // [NH1][LDK]
    const float* __restrict__ b1,
    __hip_bfloat16* __restrict__ H) {        // [6144][NH1]
    __shared__ __align__(16) char smem[12288];
    char* Asm = smem;          // 128 rows x 64B
    char* Bsm = smem + 8192;   // 64 rows x 64B
    const int m0 = blockIdx.x * 128, n0 = blockIdx.y * 64;
    const int tid = threadIdx.x;
    const int w = tid >> 6, l = tid & 63;
    const int wr = w >> 1, wc = w & 1;
    const int l15 = l & 15, l4 = l >> 4;
    f32x4 acc[4][2];
    #pragma unroll
    for (int m = 0; m < 4; ++m)
        #pragma unroll
        for (int n = 0; n < 2; ++n) acc[m][n] = (f32x4){0.f, 0.f, 0.f, 0.f};
    const char* Ag = (const char*)(A + (size_t)(m0 + (tid >> 2)) * LDK) + (tid & 3) * 16;
    const char* Bg = (const char*)(Bt + (size_t)(n0 + (tid >> 2)) * LDK) + (tid & 3) * 16;
    char* AsmW = Asm + w * 1024;
    char* BsmW = Bsm + w * 1024;
    for (int kb = 0; kb < LDK * 2; kb += 64) {  // byte offset along K
        gload16(Ag + kb, AsmW);                               // rows 0..63
        gload16(Ag + (size_t)64 * LDK * 2 + kb, AsmW + 4096); // rows 64..127
        gload16(Bg + kb, BsmW);
        __syncthreads();
        short8 af[4], bfr[2];
        #pragma unroll
        for (int m = 0; m < 4; ++m)
            af[m] = *(const short8*)(Asm + (wr * 64 + m * 16 + l15) * 64 + l4 * 16);
        #pragma unroll
        for (int n = 0; n < 2; ++n)
            bfr[n] = *(const short8*)(Bsm + (wc * 32 + n * 16 + l15) * 64 + l4 * 16);
        #pragma unroll
        for (int m = 0; m < 4; ++m)
            #pragma unroll
            for (int n = 0; n < 2; ++n)
                acc[m][n] = __builtin_amdgcn_mfma_f32_16x16x32_bf16(af[m], bfr[n], acc[m][n], 0, 0, 0);
        __syncthreads();
    }
    #pragma unroll
    for (int m = 0; m < 4; ++m) {
        int row = m0 + wr * 64 + m * 16 + l4 * 4;
        #pragma unroll
        for (int n = 0; n < 2; ++n) {
            int col = n0 + wc * 32 + n * 16 + l15;
            float bias = b1[col];
            #pragma unroll
            for (int j = 0; j < 4; ++j)
                H[(size_t)(row + j) * NH1 + col] = __float2bfloat16(gelu_tanh(acc[m][n][j] + bias));
        }
    }
}

// ---------------- GEMM2 MFMA: (2048 x 1152) @ stacked w2t -> out slice ----------------

__global__ __launch_bounds__(256) void gemm2_mfma(
    const __hip_bfloat16* __restrict__ Hin,  // [3*2048][NH1]
    const __hip_bfloat16* __restrict__ Bt,   // [NH2][NH1]
    const float* __restrict__ b2,
    float* __restrict__ out, int level) {
    __shared__ __align__(16) char smem[8192];
    char* Asm = smem;         // 64 rows x 64B
    char* Bsm = smem + 4096;
    const int m0 = blockIdx.x * 64, n0 = blockIdx.y * 64;
    const int tid = threadIdx.x;
    const int w = tid >> 6, l = tid & 63;
    const int wr = w >> 1, wc = w & 1;
    const int l15 = l & 15, l4 = l >> 4;
    f32x4 acc[2][2];
    #pragma unroll
    for (int m = 0; m < 2; ++m)
        #pragma unroll
        for (int n = 0; n < 2; ++n) acc[m][n] = (f32x4){0.f, 0.f, 0.f, 0.f};
    const char* Bg = (const char*)(Bt + (size_t)(n0 + (tid >> 2)) * NH1) + (tid & 3) * 16;
    char* AsmW = Asm + w * 1024;
    char* BsmW = Bsm + w * 1024;
    for (int p = 0; p < 3; ++p) {
        const char* Ag = (const char*)(Hin + (size_t)(p * 2048 + m0 + (tid >> 2)) * NH1) + (tid & 3) * 16;
        for (int jb = 0; jb < NH1 * 2; jb += 64) {
            gload16(Ag + jb, AsmW);
            gload16(Bg + jb, BsmW);
            __syncthreads();
            short8 af[2], bfr[2];
            #pragma unroll
            for (int m = 0; m < 2; ++m)
                af[m] = *(const short8*)(Asm + (wr * 32 + m * 16 + l15) * 64 + l4 * 16);
            #pragma unroll
            for (int n = 0; n < 2; ++n)
                bfr[n] = *(const short8*)(Bsm + (wc * 32 + n * 16 + l15) * 64 + l4 * 16);
            #pragma unroll
            for (int m = 0; m < 2; ++m)
                #pragma unroll
                for (int n = 0; n < 2; ++n)
                    acc[m][n] = __builtin_amdgcn_mfma_f32_16x16x32_bf16(af[m], bfr[n], acc[m][n], 0, 0, 0);
            __syncthreads();
        }
    }
    #pragma unroll
    for (int m = 0; m < 2; ++m) {
        int row = m0 + wr * 32 + m * 16 + l4 * 4;
        #pragma unroll
        for (int n = 0; n < 2; ++n) {
            int col = n0 + wc * 32 + n * 16 + l15;
            float bias3 = 3.f * b2[col];
            #pragma unroll
            for (int j = 0; j < 4; ++j)
                out[(size_t)(row + j) * 1024 + level * NH2 + col] = acc[m][n][j] + bias3;
        }
    }
}

// ---------------- launch ----------------

extern "C" void kernel_launch(void* const* d_in, const int* in_sizes, int n_in,
                              void* d_out, int out_size, void* d_ws, size_t ws_size,
                              hipStream_t stream) {
    const float* coords      = (const float*)d_in[0];
    const float* coords_init = (const float*)d_in[1];
    const float* fp0         = (const float*)d_in[2];
    const float* w1          = (const float*)d_in[3];
    const float* b1          = (const float*)d_in[4];
    const float* w2          = (const float*)d_in[5];
    const float* b2          = (const float*)d_in[6];
    float* out = (float*)d_out;
    char* ws = (char*)d_ws;

    const size_t SZ_PYR1 = (size_t)8 * 384 * 48 * 48;  // elems
    const size_t SZ_PYR2 = (size_t)8 * 384 * 24 * 24;
    const size_t SZ_PYR3 = (size_t)8 * 384 * 12 * 12;
    const size_t SZ_TF   = (size_t)3 * NTRK * DLAT * CD2;

    float* pyr1  = (float*)ws;                       ws += SZ_PYR1 * 4;
    float* pyr2  = (float*)ws;                       ws += SZ_PYR2 * 4;
    float* pyr3  = (float*)ws;                       ws += SZ_PYR3 * 4;
    __hip_bfloat16* tfb  = (__hip_bfloat16*)ws;      ws += SZ_TF * 2;
    __hip_bfloat16* c4b  = (__hip_bfloat16*)ws;      ws += (size_t)6144 * LDK * 2;
    __hip_bfloat16* h_ws = (__hip_bfloat16*)ws;      ws += (size_t)6144 * NH1 * 2;
    __hip_bfloat16* w1t  = (__hip_bfloat16*)ws;      ws += (size_t)NH1 * LDK * 2;
    __hip_bfloat16* w2t  = (__hip_bfloat16*)ws;      ws += (size_t)NH2 * NH1 * 2;

    prep_w1t<<<(NH1 * LDK + 255) / 256, 256, 0, stream>>>(w1, w1t);
    prep_w2t<<<(NH2 * NH1 + 255) / 256, 256, 0, stream>>>(w2, w2t);

    pool_kernel<<<(int)((SZ_PYR1 + 255) / 256), 256, 0, stream>>>(fp0, pyr1, 96, (int)SZ_PYR1);
    pool_kernel<<<(int)((SZ_PYR2 + 255) / 256), 256, 0, stream>>>(pyr1, pyr2, 48, (int)SZ_PYR2);
    pool_kernel<<<(int)((SZ_PYR3 + 255) / 256), 256, 0, stream>>>(pyr2, pyr3, 24, (int)SZ_PYR3);

    const float* levs[4] = {fp0, pyr1, pyr2, pyr3};
    const int vs[4] = {96, 48, 24, 12};
    for (int i = 0; i < 4; ++i) {
        float inv = 1.f / (float)(1 << i);
        tf_kernel<<<3 * NTRK, 256, 0, stream>>>(levs[i], coords_init, tfb, vs[i], inv);
        corr_mfma<<<3 * 2048, 256, 0, stream>>>(levs[i], coords, tfb, c4b, vs[i], inv);
        gemm1_mfma<<<dim3(48, 6), 256, 0, stream>>>(c4b, w1t, b1, h_ws);
        gemm2_mfma<<<dim3(32, 4), 256, 0, stream>>>(h_ws, w2t, b2, out, i);
    }
}

// Round 4
// 927.378 us; speedup vs baseline: 2.8593x; 1.0813x over previous
//
#include <hip/hip_runtime.h>
#include <hip/hip_bf16.h>
#include <math.h>

#define NTRK 256
#define DLAT 128
#define CDIM 7
#define CD2  49
#define CD4  2401
#define NH1  384
#define NH2  256
#define LDK  2432    // CD4 padded to multiple of 32
#define PITCHB 272   // corr LDS row pitch in bytes (136 bf16) -> 4-bank skew per row

typedef __attribute__((ext_vector_type(8))) short short8;
typedef __attribute__((ext_vector_type(4))) float f32x4;

// ---------------- helpers ----------------

__device__ __forceinline__ float b2f(unsigned short u) {
    union { unsigned int i; float f; } c;
    c.i = ((unsigned int)u) << 16;
    return c.f;
}
__device__ __forceinline__ unsigned short f2b(float x) {
    __hip_bfloat16 h = __float2bfloat16(x);
    return *(unsigned short*)&h;
}

__device__ __forceinline__ float bilin_bf(const __hip_bfloat16* __restrict__ img, int v,
                                          float X, float Y) {
    float vm1 = (float)(v - 1);
    X = fminf(fmaxf(X, 0.f), vm1);
    Y = fminf(fmaxf(Y, 0.f), vm1);
    float xf = floorf(X), yf = floorf(Y);
    int x0 = (int)xf, y0 = (int)yf;
    int x1 = min(x0 + 1, v - 1), y1 = min(y0 + 1, v - 1);
    float wx = X - xf, wy = Y - yf;
    const unsigned short* p = (const unsigned short*)img;
    float v00 = b2f(p[y0 * v + x0]), v01 = b2f(p[y0 * v + x1]);
    float v10 = b2f(p[y1 * v + x0]), v11 = b2f(p[y1 * v + x1]);
    return v00 * (1.f - wy) * (1.f - wx) + v01 * (1.f - wy) * wx
         + v10 * wy * (1.f - wx) + v11 * wy * wx;
}

__device__ __forceinline__ float gelu_tanh(float x) {
    float x3 = x * x * x;
    float u = 0.7978845608028654f * (x + 0.044715f * x3);
    return 0.5f * x * (1.f + tanhf(u));
}

__device__ __forceinline__ int plane_a(int k) { return (k == 2) ? 1 : 0; }
__device__ __forceinline__ int plane_b(int k) { return (k == 0) ? 1 : 2; }

// async global->LDS, 16B per lane; LDS dst must be wave-uniform base
__device__ __forceinline__ void gload16(const void* g, void* l) {
    __builtin_amdgcn_global_load_lds(
        (const __attribute__((address_space(1))) unsigned int*)g,
        (__attribute__((address_space(3))) unsigned int*)l,
        16, 0, 0);
}

// ---------------- fp32 -> bf16 convert (8 elems/thread) ----------------

__global__ __launch_bounds__(256) void cvt_bf16_kernel(const float* __restrict__ in,
                                                       __hip_bfloat16* __restrict__ out,
                                                       int total8) {
    int idx = blockIdx.x * 256 + threadIdx.x;
    if (idx >= total8) return;
    const float4* p = (const float4*)in + (size_t)idx * 2;
    float4 a = p[0], b = p[1];
    short8 r;
    r[0] = (short)f2b(a.x); r[1] = (short)f2b(a.y);
    r[2] = (short)f2b(a.z); r[3] = (short)f2b(a.w);
    r[4] = (short)f2b(b.x); r[5] = (short)f2b(b.y);
    r[6] = (short)f2b(b.z); r[7] = (short)f2b(b.w);
    *(short8*)((unsigned short*)out + (size_t)idx * 8) = r;
}

// ---------------- 2x2 avg pool, bf16 ----------------

__global__ __launch_bounds__(256) void pool_bf16(const __hip_bfloat16* __restrict__ in,
                                                 __hip_bfloat16* __restrict__ out,
                                                 int vin, int total) {
    int idx = blockIdx.x * 256 + threadIdx.x;
    if (idx >= total) return;
    int vout = vin >> 1;
    int x = idx % vout;
    int t = idx / vout;
    int y = t % vout;
    t /= vout;  // t = frame*384 + channel
    const unsigned int* row0 = (const unsigned int*)((const unsigned short*)in + ((size_t)t * vin + 2 * y) * vin);
    unsigned int p0 = row0[x];
    unsigned int p1 = row0[x + (vin >> 1)];
    float s = b2f((unsigned short)(p0 & 0xffff)) + b2f((unsigned short)(p0 >> 16))
            + b2f((unsigned short)(p1 & 0xffff)) + b2f((unsigned short)(p1 >> 16));
    ((unsigned short*)out)[idx] = f2b(0.25f * s);
}

// ---------------- track features (frame 0 bilinear), bf16, [k][n][xy][dd] ----------------

__global__ __launch_bounds__(256) void tf_kernel(const __hip_bfloat16* __restrict__ lev,
                                                 const float* __restrict__ coords_init,
                                                 __hip_bfloat16* __restrict__ tfb,
                                                 int v, float inv_scale) {
    int bid = blockIdx.x;         // k*256 + n
    int k = bid >> 8;
    int n = bid & 255;
    float cx = coords_init[n * 3 + plane_a(k)] * inv_scale;
    float cy = coords_init[n * 3 + plane_b(k)] * inv_scale;
    __hip_bfloat16* dst = tfb + ((size_t)(k * NTRK + n)) * (DLAT * CD2);
    for (int idx = threadIdx.x; idx < DLAT * CD2; idx += 256) {
        int xy = idx >> 7;           // 0..48
        int dd = idx & 127;
        int i = xy / CDIM, j = xy % CDIM;
        const __hip_bfloat16* img = lev + (size_t)(dd * 3 + k) * v * v;  // frame 0
        dst[idx] = __float2bfloat16(bilin_bf(img, v, cx + (float)(i - 3), cy + (float)(j - 3)));
    }
}

// ---------------- fused sampling + MFMA correlation ----------------
// grid 6144; XCD-locality decode: s = bid&7, n = (bid>>3)&255, k = bid>>11
// (round-robin XCD dispatch puts all 256 blocks of a (k,s) frame-group on one XCD,
//  whose bf16 slice ~2.4 MB fits the 4 MB XCD L2)
// C = cf(49x128) @ tf^T(128x49), padded to 64x64; c4b row = k*2048+s*256+n

__global__ __launch_bounds__(256) void corr_mfma(const __hip_bfloat16* __restrict__ lev,
                                                 const float* __restrict__ coords,
                                                 const __hip_bfloat16* __restrict__ tfb,
                                                 __hip_bfloat16* __restrict__ c4b,
                                                 int v, float inv_scale) {
    __shared__ __align__(16) char cfs[64 * PITCHB];  // A: [hw][dd] bf16, skewed pitch
    __shared__ __align__(16) char tfs[64 * PITCHB];  // B: [xy][dd] bf16, skewed pitch
    const int B = blockIdx.x;
    const int s = B & 7;
    const int n = (B >> 3) & 255;
    const int k = B >> 11;
    const int sn = s * 256 + n;
    const int tid = threadIdx.x;
    float cx = coords[sn * 3 + plane_a(k)] * inv_scale;
    float cy = coords[sn * 3 + plane_b(k)] * inv_scale;
    const __hip_bfloat16* frame = lev + (size_t)(s * 384 + k) * v * v;  // channel dd at + dd*3*v*v
    const int vv3 = 3 * v * v;

    // stage tf: 49 rows x 256B = 784 x 16B chunks
    const short8* tfg = (const short8*)(tfb + ((size_t)(k * NTRK + n)) * (DLAT * CD2));
    for (int idx = tid; idx < 784; idx += 256) {
        int row = idx >> 4, c16 = idx & 15;
        *(short8*)(tfs + row * PITCHB + c16 * 16) = tfg[idx];
    }
    // sample cf: idx = dd*49 + hw
    for (int idx = tid; idx < DLAT * CD2; idx += 256) {
        int dd = idx / CD2;
        int hw = idx - dd * CD2;
        int h = hw / CDIM, w = hw - h * CDIM;
        float val = bilin_bf(frame + (size_t)dd * vv3, v,
                             cx + (float)(h - 3), cy + (float)(w - 3));
        *(unsigned short*)(cfs + hw * PITCHB + dd * 2) = f2b(val);
    }
    __syncthreads();

    const int w4 = tid >> 6, l = tid & 63;
    const int l15 = l & 15, l4 = l >> 4;
    f32x4 acc[4];
    #pragma unroll
    for (int nt = 0; nt < 4; ++nt) acc[nt] = (f32x4){0.f, 0.f, 0.f, 0.f};
    #pragma unroll
    for (int ks = 0; ks < 4; ++ks) {
        short8 af = *(const short8*)(cfs + (16 * w4 + l15) * PITCHB + ks * 64 + l4 * 16);
        #pragma unroll
        for (int nt = 0; nt < 4; ++nt) {
            short8 bf = *(const short8*)(tfs + (16 * nt + l15) * PITCHB + ks * 64 + l4 * 16);
            acc[nt] = __builtin_amdgcn_mfma_f32_16x16x32_bf16(af, bf, acc[nt], 0, 0, 0);
        }
    }
    __hip_bfloat16* crow = c4b + (size_t)(k * 2048 + sn) * LDK;
    const int row0 = 16 * w4 + l4 * 4;
    #pragma unroll
    for (int nt = 0; nt < 4; ++nt) {
        int col = nt * 16 + l15;
        if (col < CD2) {
            #pragma unroll
            for (int j = 0; j < 4; ++j) {
                int row = row0 + j;
                if (row < CD2) crow[row * CD2 + col] = __float2bfloat16(acc[nt][j]);
            }
        }
    }
    if (tid < LDK - CD4) crow[CD4 + tid] = __float2bfloat16(0.f);
}

// ---------------- weight prep: transpose + bf16 ----------------

__global__ __launch_bounds__(256) void prep_w1t(const float* __restrict__ w1,
                                                __hip_bfloat16* __restrict__ w1t) {
    int idx = blockIdx.x * 256 + threadIdx.x;  // n*LDK + kk
    if (idx >= NH1 * LDK) return;
    int n = idx / LDK, kk = idx - n * LDK;
    float v = (kk < CD4) ? w1[(size_t)kk * NH1 + n] : 0.f;
    w1t[idx] = __float2bfloat16(v);
}

__global__ __launch_bounds__(256) void prep_w2t(const float* __restrict__ w2,
                                                __hip_bfloat16* __restrict__ w2t) {
    int idx = blockIdx.x * 256 + threadIdx.x;  // n*NH1 + j
    if (idx >= NH2 * NH1) return;
    int n = idx / NH1, j = idx - n * NH1;
    w2t[idx] = __float2bfloat16(w2[(size_t)j * NH2 + n]);
}

// ---------------- GEMM1 MFMA: (6144 x LDK) @ w1t^T -> gelu -> H bf16 ----------------
// BM=128 BN=64 BK=32, 4 waves (2x2), wave tile 64x32 = 4x2 frags of 16x16

__global__ __launch_bounds__(256) void gemm1_mfma(
    const __hip_bfloat16* __restrict__ A,    // [6144][LDK]
    const __hip_bfloat16* __restrict__ Bt,   // [NH1][LDK]
    const float* __restrict__ b1,
    __hip_bfloat16* __restrict__ H) {        // [6144][NH1]
    __shared__ __align__(16) char smem[12288];
    char* Asm = smem;          // 128 rows x 64B
    char* Bsm = smem + 8192;   // 64 rows x 64B
    const int m0 = blockIdx.x * 128, n0 = blockIdx.y * 64;
    const int tid = threadIdx.x;
    const int w = tid >> 6, l = tid & 63;
    const int wr = w >> 1, wc = w & 1;
    const int l15 = l & 15, l4 = l >> 4;
    f32x4 acc[4][2];
    #pragma unroll
    for (int m = 0; m < 4; ++m)
        #pragma unroll
        for (int n = 0; n < 2; ++n) acc[m][n] = (f32x4){0.f, 0.f, 0.f, 0.f};
    const char* Ag = (const char*)(A + (size_t)(m0 + (tid >> 2)) * LDK) + (tid & 3) * 16;
    const char* Bg = (const char*)(Bt + (size_t)(n0 + (tid >> 2)) * LDK) + (tid & 3) * 16;
    char* AsmW = Asm + w * 1024;
    char* BsmW = Bsm + w * 1024;
    for (int kb = 0; kb < LDK * 2; kb += 64) {  // byte offset along K
        gload16(Ag + kb, AsmW);                               // rows 0..63
        gload16(Ag + (size_t)64 * LDK * 2 + kb, AsmW + 4096); // rows 64..127
        gload16(Bg + kb, BsmW);
        __syncthreads();
        short8 af[4], bfr[2];
        #pragma unroll
        for (int m = 0; m < 4; ++m)
            af[m] = *(const short8*)(Asm + (wr * 64 + m * 16 + l15) * 64 + l4 * 16);
        #pragma unroll
        for (int n = 0; n < 2; ++n)
            bfr[n] = *(const short8*)(Bsm + (wc * 32 + n * 16 + l15) * 64 + l4 * 16);
        #pragma unroll
        for (int m = 0; m < 4; ++m)
            #pragma unroll
            for (int n = 0; n < 2; ++n)
                acc[m][n] = __builtin_amdgcn_mfma_f32_16x16x32_bf16(af[m], bfr[n], acc[m][n], 0, 0, 0);
        __syncthreads();
    }
    #pragma unroll
    for (int m = 0; m < 4; ++m) {
        int row = m0 + wr * 64 + m * 16 + l4 * 4;
        #pragma unroll
        for (int n = 0; n < 2; ++n) {
            int col = n0 + wc * 32 + n * 16 + l15;
            float bias = b1[col];
            #pragma unroll
            for (int j = 0; j < 4; ++j)
                H[(size_t)(row + j) * NH1 + col] = __float2bfloat16(gelu_tanh(acc[m][n][j] + bias));
        }
    }
}

// ---------------- GEMM2 MFMA: (2048 x 1152) @ stacked w2t -> out slice ----------------

__global__ __launch_bounds__(256) void gemm2_mfma(
    const __hip_bfloat16* __restrict__ Hin,  // [3*2048][NH1]
    const __hip_bfloat16* __restrict__ Bt,   // [NH2][NH1]
    const float* __restrict__ b2,
    float* __restrict__ out, int level) {
    __shared__ __align__(16) char smem[8192];
    char* Asm = smem;         // 64 rows x 64B
    char* Bsm = smem + 4096;
    const int m0 = blockIdx.x * 64, n0 = blockIdx.y * 64;
    const int tid = threadIdx.x;
    const int w = tid >> 6, l = tid & 63;
    const int wr = w >> 1, wc = w & 1;
    const int l15 = l & 15, l4 = l >> 4;
    f32x4 acc[2][2];
    #pragma unroll
    for (int m = 0; m < 2; ++m)
        #pragma unroll
        for (int n = 0; n < 2; ++n) acc[m][n] = (f32x4){0.f, 0.f, 0.f, 0.f};
    const char* Bg = (const char*)(Bt + (size_t)(n0 + (tid >> 2)) * NH1) + (tid & 3) * 16;
    char* AsmW = Asm + w * 1024;
    char* BsmW = Bsm + w * 1024;
    for (int p = 0; p < 3; ++p) {
        const char* Ag = (const char*)(Hin + (size_t)(p * 2048 + m0 + (tid >> 2)) * NH1) + (tid & 3) * 16;
        for (int jb = 0; jb < NH1 * 2; jb += 64) {
            gload16(Ag + jb, AsmW);
            gload16(Bg + jb, BsmW);
            __syncthreads();
            short8 af[2], bfr[2];
            #pragma unroll
            for (int m = 0; m < 2; ++m)
                af[m] = *(const short8*)(Asm + (wr * 32 + m * 16 + l15) * 64 + l4 * 16);
            #pragma unroll
            for (int n = 0; n < 2; ++n)
                bfr[n] = *(const short8*)(Bsm + (wc * 32 + n * 16 + l15) * 64 + l4 * 16);
            #pragma unroll
            for (int m = 0; m < 2; ++m)
                #pragma unroll
                for (int n = 0; n < 2; ++n)
                    acc[m][n] = __builtin_amdgcn_mfma_f32_16x16x32_bf16(af[m], bfr[n], acc[m][n], 0, 0, 0);
            __syncthreads();
        }
    }
    #pragma unroll
    for (int m = 0; m < 2; ++m) {
        int row = m0 + wr * 32 + m * 16 + l4 * 4;
        #pragma unroll
        for (int n = 0; n < 2; ++n) {
            int col = n0 + wc * 32 + n * 16 + l15;
            float bias3 = 3.f * b2[col];
            #pragma unroll
            for (int j = 0; j < 4; ++j)
                out[(size_t)(row + j) * 1024 + level * NH2 + col] = acc[m][n][j] + bias3;
        }
    }
}

// ---------------- launch ----------------

extern "C" void kernel_launch(void* const* d_in, const int* in_sizes, int n_in,
                              void* d_out, int out_size, void* d_ws, size_t ws_size,
                              hipStream_t stream) {
    const float* coords      = (const float*)d_in[0];
    const float* coords_init = (const float*)d_in[1];
    const float* fp0         = (const float*)d_in[2];
    const float* w1          = (const float*)d_in[3];
    const float* b1          = (const float*)d_in[4];
    const float* w2          = (const float*)d_in[5];
    const float* b2          = (const float*)d_in[6];
    float* out = (float*)d_out;
    char* ws = (char*)d_ws;

    const size_t SZ_PYR0 = (size_t)8 * 384 * 96 * 96;  // elems
    const size_t SZ_PYR1 = (size_t)8 * 384 * 48 * 48;
    const size_t SZ_PYR2 = (size_t)8 * 384 * 24 * 24;
    const size_t SZ_PYR3 = (size_t)8 * 384 * 12 * 12;
    const size_t SZ_TF   = (size_t)3 * NTRK * DLAT * CD2;

    __hip_bfloat16* fpb0 = (__hip_bfloat16*)ws;      ws += SZ_PYR0 * 2;
    __hip_bfloat16* pyr1 = (__hip_bfloat16*)ws;      ws += SZ_PYR1 * 2;
    __hip_bfloat16* pyr2 = (__hip_bfloat16*)ws;      ws += SZ_PYR2 * 2;
    __hip_bfloat16* pyr3 = (__hip_bfloat16*)ws;      ws += SZ_PYR3 * 2;
    __hip_bfloat16* tfb  = (__hip_bfloat16*)ws;      ws += SZ_TF * 2;
    __hip_bfloat16* c4b  = (__hip_bfloat16*)ws;      ws += (size_t)6144 * LDK * 2;
    __hip_bfloat16* h_ws = (__hip_bfloat16*)ws;      ws += (size_t)6144 * NH1 * 2;
    __hip_bfloat16* w1t  = (__hip_bfloat16*)ws;      ws += (size_t)NH1 * LDK * 2;
    __hip_bfloat16* w2t  = (__hip_bfloat16*)ws;      ws += (size_t)NH2 * NH1 * 2;

    prep_w1t<<<(NH1 * LDK + 255) / 256, 256, 0, stream>>>(w1, w1t);
    prep_w2t<<<(NH2 * NH1 + 255) / 256, 256, 0, stream>>>(w2, w2t);

    cvt_bf16_kernel<<<(int)((SZ_PYR0 / 8 + 255) / 256), 256, 0, stream>>>(fp0, fpb0, (int)(SZ_PYR0 / 8));
    pool_bf16<<<(int)((SZ_PYR1 + 255) / 256), 256, 0, stream>>>(fpb0, pyr1, 96, (int)SZ_PYR1);
    pool_bf16<<<(int)((SZ_PYR2 + 255) / 256), 256, 0, stream>>>(pyr1, pyr2, 48, (int)SZ_PYR2);
    pool_bf16<<<(int)((SZ_PYR3 + 255) / 256), 256, 0, stream>>>(pyr2, pyr3, 24, (int)SZ_PYR3);

    const __hip_bfloat16* levs[4] = {fpb0, pyr1, pyr2, pyr3};
    const int vs[4] = {96, 48, 24, 12};
    for (int i = 0; i < 4; ++i) {
        float inv = 1.f / (float)(1 << i);
        tf_kernel<<<3 * NTRK, 256, 0, stream>>>(levs[i], coords_init, tfb, vs[i], inv);
        corr_mfma<<<3 * 2048, 256, 0, stream>>>(levs[i], coords, tfb, c4b, vs[i], inv);
        gemm1_mfma<<<dim3(48, 6), 256, 0, stream>>>(c4b, w1t, b1, h_ws);
        gemm2_mfma<<<dim3(32, 4), 256, 0, stream>>>(h_ws, w2t, b2, out, i);
    }
}

// Round 6
// 619.366 us; speedup vs baseline: 4.2813x; 1.4973x over previous
//
#include <hip/hip_runtime.h>
#include <hip/hip_bf16.h>
#include <math.h>

#define NTRK 256
#define DLAT 128
#define CDIM 7
#define CD2  49
#define CD4  2401
#define NH1  384
#define NH2  256
#define LDK  2432    // CD4 padded to multiple of 32
#define PITCHB 272   // corr LDS row pitch in bytes (136 bf16 / 68 dwords) -> 4-bank skew per row

typedef __attribute__((ext_vector_type(8))) short short8;
typedef __attribute__((ext_vector_type(4))) float f32x4;

// ---------------- helpers ----------------

__device__ __forceinline__ float b2f(unsigned short u) {
    union { unsigned int i; float f; } c;
    c.i = ((unsigned int)u) << 16;
    return c.f;
}
__device__ __forceinline__ unsigned short f2b(float x) {
    __hip_bfloat16 h = __float2bfloat16(x);
    return *(unsigned short*)&h;
}

__device__ __forceinline__ float bilin_bf(const __hip_bfloat16* __restrict__ img, int v,
                                          float X, float Y) {
    float vm1 = (float)(v - 1);
    X = fminf(fmaxf(X, 0.f), vm1);
    Y = fminf(fmaxf(Y, 0.f), vm1);
    float xf = floorf(X), yf = floorf(Y);
    int x0 = (int)xf, y0 = (int)yf;
    int x1 = min(x0 + 1, v - 1), y1 = min(y0 + 1, v - 1);
    float wx = X - xf, wy = Y - yf;
    const unsigned short* p = (const unsigned short*)img;
    float v00 = b2f(p[y0 * v + x0]), v01 = b2f(p[y0 * v + x1]);
    float v10 = b2f(p[y1 * v + x0]), v11 = b2f(p[y1 * v + x1]);
    return v00 * (1.f - wy) * (1.f - wx) + v01 * (1.f - wy) * wx
         + v10 * wy * (1.f - wx) + v11 * wy * wx;
}

__device__ __forceinline__ float gelu_tanh(float x) {
    float x3 = x * x * x;
    float u = 0.7978845608028654f * (x + 0.044715f * x3);
    return 0.5f * x * (1.f + tanhf(u));
}

__device__ __forceinline__ int plane_a(int k) { return (k == 2) ? 1 : 0; }
__device__ __forceinline__ int plane_b(int k) { return (k == 0) ? 1 : 2; }

// async global->LDS, 16B per lane; LDS dst must be wave-uniform base
__device__ __forceinline__ void gload16(const void* g, void* l) {
    __builtin_amdgcn_global_load_lds(
        (const __attribute__((address_space(1))) unsigned int*)g,
        (__attribute__((address_space(3))) unsigned int*)l,
        16, 0, 0);
}

// ---------------- fp32 -> bf16 convert (8 elems/thread) ----------------

__global__ __launch_bounds__(256) void cvt_bf16_kernel(const float* __restrict__ in,
                                                       __hip_bfloat16* __restrict__ out,
                                                       int total8) {
    int idx = blockIdx.x * 256 + threadIdx.x;
    if (idx >= total8) return;
    const float4* p = (const float4*)in + (size_t)idx * 2;
    float4 a = p[0], b = p[1];
    short8 r;
    r[0] = (short)f2b(a.x); r[1] = (short)f2b(a.y);
    r[2] = (short)f2b(a.z); r[3] = (short)f2b(a.w);
    r[4] = (short)f2b(b.x); r[5] = (short)f2b(b.y);
    r[6] = (short)f2b(b.z); r[7] = (short)f2b(b.w);
    *(short8*)((unsigned short*)out + (size_t)idx * 8) = r;
}

// ---------------- 2x2 avg pool, bf16 ----------------

__global__ __launch_bounds__(256) void pool_bf16(const __hip_bfloat16* __restrict__ in,
                                                 __hip_bfloat16* __restrict__ out,
                                                 int vin, int total) {
    int idx = blockIdx.x * 256 + threadIdx.x;
    if (idx >= total) return;
    int vout = vin >> 1;
    int x = idx % vout;
    int t = idx / vout;
    int y = t % vout;
    t /= vout;  // t = frame*384 + channel
    const unsigned int* row0 = (const unsigned int*)((const unsigned short*)in + ((size_t)t * vin + 2 * y) * vin);
    unsigned int p0 = row0[x];
    unsigned int p1 = row0[x + (vin >> 1)];
    float s = b2f((unsigned short)(p0 & 0xffff)) + b2f((unsigned short)(p0 >> 16))
            + b2f((unsigned short)(p1 & 0xffff)) + b2f((unsigned short)(p1 >> 16));
    ((unsigned short*)out)[idx] = f2b(0.25f * s);
}

// ---------------- track features (frame 0 bilinear), bf16, [k][n][xy][dd] ----------------

__global__ __launch_bounds__(256) void tf_kernel(const __hip_bfloat16* __restrict__ lev,
                                                 const float* __restrict__ coords_init,
                                                 __hip_bfloat16* __restrict__ tfb,
                                                 int v, float inv_scale) {
    int bid = blockIdx.x;         // k*256 + n
    int k = bid >> 8;
    int n = bid & 255;
    float cx = coords_init[n * 3 + plane_a(k)] * inv_scale;
    float cy = coords_init[n * 3 + plane_b(k)] * inv_scale;
    __hip_bfloat16* dst = tfb + ((size_t)(k * NTRK + n)) * (DLAT * CD2);
    for (int idx = threadIdx.x; idx < DLAT * CD2; idx += 256) {
        int xy = idx >> 7;           // 0..48
        int dd = idx & 127;
        int i = xy / CDIM, j = xy % CDIM;
        const __hip_bfloat16* img = lev + (size_t)(dd * 3 + k) * v * v;  // frame 0
        dst[idx] = __float2bfloat16(bilin_bf(img, v, cx + (float)(i - 3), cy + (float)(j - 3)));
    }
}

// ---------------- fused patch-MFMA correlation ----------------
// grid 6144; XCD-locality decode: s = bid&7, n = (bid>>3)&255, k = bid>>11
// Bilinear with integer window offsets is separable with block-uniform weights:
//   c4 = W_interp (P @ tf^T), where P is the 8x8 integer-aligned patch per channel.
// Patch axis convention (matches round-4 verified sampling): output (h,w) samples
// X = cx+(h-3) [x-axis], Y = cy+(w-3) [y-axis]; patch pos = py*8+px with px<->x.
// So the tap for output (h,w) is pos = w*8 + h, weights wx=wxs[h], wy=wys[w].

__global__ __launch_bounds__(256) void corr_mfma(const __hip_bfloat16* __restrict__ lev,
                                                 const float* __restrict__ coords,
                                                 const __hip_bfloat16* __restrict__ tfb,
                                                 __hip_bfloat16* __restrict__ c4b,
                                                 int v, float inv_scale) {
    __shared__ __align__(16) char patch[64 * PITCHB];  // P: [pos][dd] bf16; later Cfull fp32 [pos][xy]
    __shared__ __align__(16) char tfs[64 * PITCHB];    // B: [xy][dd] bf16
    __shared__ float wxs[8], wys[8];
    const int B = blockIdx.x;
    const int s = B & 7;
    const int n = (B >> 3) & 255;
    const int k = B >> 11;
    const int sn = s * 256 + n;
    const int tid = threadIdx.x;
    const float vm1 = (float)(v - 1);
    float cx = coords[sn * 3 + plane_a(k)] * inv_scale;
    float cy = coords[sn * 3 + plane_b(k)] * inv_scale;
    const int fx = (int)floorf(cx), fy = (int)floorf(cy);

    // block-uniform interpolation weights (0 at clamped taps)
    if (tid < 7) {
        float X = fminf(fmaxf(cx + (float)(tid - 3), 0.f), vm1);
        int g = min(max(fx + tid - 3, 0), v - 1);
        wxs[tid] = X - (float)g;
        float Y = fminf(fmaxf(cy + (float)(tid - 3), 0.f), vm1);
        int gy_ = min(max(fy + tid - 3, 0), v - 1);
        wys[tid] = Y - (float)gy_;
    }

    // stage tf: 49 rows x 256B = 784 x 16B chunks
    const short8* tfg = (const short8*)(tfb + ((size_t)(k * NTRK + n)) * (DLAT * CD2));
    for (int idx = tid; idx < 784; idx += 256) {
        int row = idx >> 4, c16 = idx & 15;
        *(short8*)(tfs + row * PITCHB + c16 * 16) = tfg[idx];
    }

    // stage patch: lane owns fixed pos = tid&63, walks channels dd = (tid>>6) + 4*it
    {
        const int pos = tid & 63;
        const int px = pos & 7, py = pos >> 3;
        const int gx = min(max(fx + px - 3, 0), v - 1);
        const int gy = min(max(fy + py - 3, 0), v - 1);
        const int vv3 = 3 * v * v;
        const unsigned short* frp = (const unsigned short*)lev
            + (size_t)(s * 384 + k) * v * v + (size_t)(tid >> 6) * vv3 + (gy * v + gx);
        char* pdst = patch + pos * PITCHB + (tid >> 6) * 2;
        #pragma unroll 8
        for (int it = 0; it < 32; ++it) {
            *(unsigned short*)(pdst + it * 8) = frp[(size_t)it * 4 * vv3];
        }
    }
    __syncthreads();

    const int w4 = tid >> 6, l = tid & 63;
    const int l15 = l & 15, l4 = l >> 4;
    f32x4 acc[4];
    #pragma unroll
    for (int nt = 0; nt < 4; ++nt) acc[nt] = (f32x4){0.f, 0.f, 0.f, 0.f};
    #pragma unroll
    for (int ks = 0; ks < 4; ++ks) {
        short8 af = *(const short8*)(patch + (16 * w4 + l15) * PITCHB + ks * 64 + l4 * 16);
        #pragma unroll
        for (int nt = 0; nt < 4; ++nt) {
            short8 bf = *(const short8*)(tfs + (16 * nt + l15) * PITCHB + ks * 64 + l4 * 16);
            acc[nt] = __builtin_amdgcn_mfma_f32_16x16x32_bf16(af, bf, acc[nt], 0, 0, 0);
        }
    }
    __syncthreads();  // all patch reads done before overwrite

    // write Cfull fp32 [pos][xy] into the patch region (64 x 272B >= 64 x 256B)
    {
        const int row0 = 16 * w4 + l4 * 4;
        #pragma unroll
        for (int nt = 0; nt < 4; ++nt) {
            int col = nt * 16 + l15;
            #pragma unroll
            for (int j = 0; j < 4; ++j)
                *(float*)(patch + (row0 + j) * PITCHB + col * 4) = acc[nt][j];
        }
    }
    __syncthreads();

    // 4-tap interpolation on the 49x49 output.
    // Output (h,w): tap pos = w*8 + h; +PITCHB = x+1 (weight wx=wxs[h]);
    // +8*PITCHB = y+1 (weight wy=wys[w]).
    __hip_bfloat16* crow = c4b + (size_t)(k * 2048 + sn) * LDK;
    for (int o = tid; o < CD4; o += 256) {
        int hw = o / CD2;
        int xy = o - hw * CD2;
        int h = hw / CDIM, w_ = hw - h * CDIM;
        float wxv = wxs[h], wyv = wys[w_];
        const char* base = patch + (w_ * 8 + h) * PITCHB + xy * 4;
        float p00 = *(const float*)(base);
        float p01 = *(const float*)(base + PITCHB);        // x+1
        float p10 = *(const float*)(base + 8 * PITCHB);    // y+1
        float p11 = *(const float*)(base + 9 * PITCHB);
        float val = p00 * (1.f - wyv) * (1.f - wxv) + p01 * (1.f - wyv) * wxv
                  + p10 * wyv * (1.f - wxv) + p11 * wyv * wxv;
        crow[o] = __float2bfloat16(val);
    }
    if (tid < LDK - CD4) crow[CD4 + tid] = __float2bfloat16(0.f);
}

// ---------------- weight prep: transpose + bf16 ----------------

__global__ __launch_bounds__(256) void prep_w1t(const float* __restrict__ w1,
                                                __hip_bfloat16* __restrict__ w1t) {
    int idx = blockIdx.x * 256 + threadIdx.x;  // n*LDK + kk
    if (idx >= NH1 * LDK) return;
    int n = idx / LDK, kk = idx - n * LDK;
    float v = (kk < CD4) ? w1[(size_t)kk * NH1 + n] : 0.f;
    w1t[idx] = __float2bfloat16(v);
}

__global__ __launch_bounds__(256) void prep_w2t(const float* __restrict__ w2,
                                                __hip_bfloat16* __restrict__ w2t) {
    int idx = blockIdx.x * 256 + threadIdx.x;  // n*NH1 + j
    if (idx >= NH2 * NH1) return;
    int n = idx / NH1, j = idx - n * NH1;
    w2t[idx] = __float2bfloat16(w2[(size_t)j * NH2 + n]);
}

// ---------------- GEMM1 MFMA: (6144 x LDK) @ w1t^T -> gelu -> H bf16 ----------------
// BM=128 BN=64 BK=32, 4 waves (2x2), wave tile 64x32 = 4x2 frags of 16x16

__global__ __launch_bounds__(256) void gemm1_mfma(
    const __hip_bfloat16* __restrict__ A,    // [6144][LDK]
    const __hip_bfloat16* __restrict__ Bt,   // [NH1][LDK]
    const float* __restrict__ b1,
    __hip_bfloat16* __restrict__ H) {        // [6144][NH1]
    __shared__ __align__(16) char smem[12288];
    char* Asm = smem;          // 128 rows x 64B
    char* Bsm = smem + 8192;   // 64 rows x 64B
    const int m0 = blockIdx.x * 128, n0 = blockIdx.y * 64;
    const int tid = threadIdx.x;
    const int w = tid >> 6, l = tid & 63;
    const int wr = w >> 1, wc = w & 1;
    const int l15 = l & 15, l4 = l >> 4;
    f32x4 acc[4][2];
    #pragma unroll
    for (int m = 0; m < 4; ++m)
        #pragma unroll
        for (int n = 0; n < 2; ++n) acc[m][n] = (f32x4){0.f, 0.f, 0.f, 0.f};
    const char* Ag = (const char*)(A + (size_t)(m0 + (tid >> 2)) * LDK) + (tid & 3) * 16;
    const char* Bg = (const char*)(Bt + (size_t)(n0 + (tid >> 2)) * LDK) + (tid & 3) * 16;
    char* AsmW = Asm + w * 1024;
    char* BsmW = Bsm + w * 1024;
    for (int kb = 0; kb < LDK * 2; kb += 64) {  // byte offset along K
        gload16(Ag + kb, AsmW);                               // rows 0..63
        gload16(Ag + (size_t)64 * LDK * 2 + kb, AsmW + 4096); // rows 64..127
        gload16(Bg + kb, BsmW);
        __syncthreads();
        short8 af[4], bfr[2];
        #pragma unroll
        for (int m = 0; m < 4; ++m)
            af[m] = *(const short8*)(Asm + (wr * 64 + m * 16 + l15) * 64 + l4 * 16);
        #pragma unroll
        for (int n = 0; n < 2; ++n)
            bfr[n] = *(const short8*)(Bsm + (wc * 32 + n * 16 + l15) * 64 + l4 * 16);
        #pragma unroll
        for (int m = 0; m < 4; ++m)
            #pragma unroll
            for (int n = 0; n < 2; ++n)
                acc[m][n] = __builtin_amdgcn_mfma_f32_16x16x32_bf16(af[m], bfr[n], acc[m][n], 0, 0, 0);
        __syncthreads();
    }
    #pragma unroll
    for (int m = 0; m < 4; ++m) {
        int row = m0 + wr * 64 + m * 16 + l4 * 4;
        #pragma unroll
        for (int n = 0; n < 2; ++n) {
            int col = n0 + wc * 32 + n * 16 + l15;
            float bias = b1[col];
            #pragma unroll
            for (int j = 0; j < 4; ++j)
                H[(size_t)(row + j) * NH1 + col] = __float2bfloat16(gelu_tanh(acc[m][n][j] + bias));
        }
    }
}

// ---------------- GEMM2 MFMA: (2048 x 1152) @ stacked w2t -> out slice ----------------

__global__ __launch_bounds__(256) void gemm2_mfma(
    const __hip_bfloat16* __restrict__ Hin,  // [3*2048][NH1]
    const __hip_bfloat16* __restrict__ Bt,   // [NH2][NH1]
    const float* __restrict__ b2,
    float* __restrict__ out, int level) {
    __shared__ __align__(16) char smem[8192];
    char* Asm = smem;         // 64 rows x 64B
    char* Bsm = smem + 4096;
    const int m0 = blockIdx.x * 64, n0 = blockIdx.y * 64;
    const int tid = threadIdx.x;
    const int w = tid >> 6, l = tid & 63;
    const int wr = w >> 1, wc = w & 1;
    const int l15 = l & 15, l4 = l >> 4;
    f32x4 acc[2][2];
    #pragma unroll
    for (int m = 0; m < 2; ++m)
        #pragma unroll
        for (int n = 0; n < 2; ++n) acc[m][n] = (f32x4){0.f, 0.f, 0.f, 0.f};
    const char* Bg = (const char*)(Bt + (size_t)(n0 + (tid >> 2)) * NH1) + (tid & 3) * 16;
    char* AsmW = Asm + w * 1024;
    char* BsmW = Bsm + w * 1024;
    for (int p = 0; p < 3; ++p) {
        const char* Ag = (const char*)(Hin + (size_t)(p * 2048 + m0 + (tid >> 2)) * NH1) + (tid & 3) * 16;
        for (int jb = 0; jb < NH1 * 2; jb += 64) {
            gload16(Ag + jb, AsmW);
            gload16(Bg + jb, BsmW);
            __syncthreads();
            short8 af[2], bfr[2];
            #pragma unroll
            for (int m = 0; m < 2; ++m)
                af[m] = *(const short8*)(Asm + (wr * 32 + m * 16 + l15) * 64 + l4 * 16);
            #pragma unroll
            for (int n = 0; n < 2; ++n)
                bfr[n] = *(const short8*)(Bsm + (wc * 32 + n * 16 + l15) * 64 + l4 * 16);
            #pragma unroll
            for (int m = 0; m < 2; ++m)
                #pragma unroll
                for (int n = 0; n < 2; ++n)
                    acc[m][n] = __builtin_amdgcn_mfma_f32_16x16x32_bf16(af[m], bfr[n], acc[m][n], 0, 0, 0);
            __syncthreads();
        }
    }
    #pragma unroll
    for (int m = 0; m < 2; ++m) {
        int row = m0 + wr * 32 + m * 16 + l4 * 4;
        #pragma unroll
        for (int n = 0; n < 2; ++n) {
            int col = n0 + wc * 32 + n * 16 + l15;
            float bias3 = 3.f * b2[col];
            #pragma unroll
            for (int j = 0; j < 4; ++j)
                out[(size_t)(row + j) * 1024 + level * NH2 + col] = acc[m][n][j] + bias3;
        }
    }
}

// ---------------- launch ----------------

extern "C" void kernel_launch(void* const* d_in, const int* in_sizes, int n_in,
                              void* d_out, int out_size, void* d_ws, size_t ws_size,
                              hipStream_t stream) {
    const float* coords      = (const float*)d_in[0];
    const float* coords_init = (const float*)d_in[1];
    const float* fp0         = (const float*)d_in[2];
    const float* w1          = (const float*)d_in[3];
    const float* b1          = (const float*)d_in[4];
    const float* w2          = (const float*)d_in[5];
    const float* b2          = (const float*)d_in[6];
    float* out = (float*)d_out;
    char* ws = (char*)d_ws;

    const size_t SZ_PYR0 = (size_t)8 * 384 * 96 * 96;  // elems
    const size_t SZ_PYR1 = (size_t)8 * 384 * 48 * 48;
    const size_t SZ_PYR2 = (size_t)8 * 384 * 24 * 24;
    const size_t SZ_PYR3 = (size_t)8 * 384 * 12 * 12;
    const size_t SZ_TF   = (size_t)3 * NTRK * DLAT * CD2;

    __hip_bfloat16* fpb0 = (__hip_bfloat16*)ws;      ws += SZ_PYR0 * 2;
    __hip_bfloat16* pyr1 = (__hip_bfloat16*)ws;      ws += SZ_PYR1 * 2;
    __hip_bfloat16* pyr2 = (__hip_bfloat16*)ws;      ws += SZ_PYR2 * 2;
    __hip_bfloat16* pyr3 = (__hip_bfloat16*)ws;      ws += SZ_PYR3 * 2;
    __hip_bfloat16* tfb  = (__hip_bfloat16*)ws;      ws += SZ_TF * 2;
    __hip_bfloat16* c4b  = (__hip_bfloat16*)ws;      ws += (size_t)6144 * LDK * 2;
    __hip_bfloat16* h_ws = (__hip_bfloat16*)ws;      ws += (size_t)6144 * NH1 * 2;
    __hip_bfloat16* w1t  = (__hip_bfloat16*)ws;      ws += (size_t)NH1 * LDK * 2;
    __hip_bfloat16* w2t  = (__hip_bfloat16*)ws;      ws += (size_t)NH2 * NH1 * 2;

    prep_w1t<<<(NH1 * LDK + 255) / 256, 256, 0, stream>>>(w1, w1t);
    prep_w2t<<<(NH2 * NH1 + 255) / 256, 256, 0, stream>>>(w2, w2t);

    cvt_bf16_kernel<<<(int)((SZ_PYR0 / 8 + 255) / 256), 256, 0, stream>>>(fp0, fpb0, (int)(SZ_PYR0 / 8));
    pool_bf16<<<(int)((SZ_PYR1 + 255) / 256), 256, 0, stream>>>(fpb0, pyr1, 96, (int)SZ_PYR1);
    pool_bf16<<<(int)((SZ_PYR2 + 255) / 256), 256, 0, stream>>>(pyr1, pyr2, 48, (int)SZ_PYR2);
    pool_bf16<<<(int)((SZ_PYR3 + 255) / 256), 256, 0, stream>>>(pyr2, pyr3, 24, (int)SZ_PYR3);

    const __hip_bfloat16* levs[4] = {fpb0, pyr1, pyr2, pyr3};
    const int vs[4] = {96, 48, 24, 12};
    for (int i = 0; i < 4; ++i) {
        float inv = 1.f / (float)(1 << i);
        tf_kernel<<<3 * NTRK, 256, 0, stream>>>(levs[i], coords_init, tfb, vs[i], inv);
        corr_mfma<<<3 * 2048, 256, 0, stream>>>(levs[i], coords, tfb, c4b, vs[i], inv);
        gemm1_mfma<<<dim3(48, 6), 256, 0, stream>>>(c4b, w1t, b1, h_ws);
        gemm2_mfma<<<dim3(32, 4), 256, 0, stream>>>(h_ws, w2t, b2, out, i);
    }
}

// Round 7
// 463.012 us; speedup vs baseline: 5.7270x; 1.3377x over previous
//
#include <hip/hip_runtime.h>
#include <hip/hip_bf16.h>
#include <math.h>

#define NTRK 256
#define DLAT 128
#define CDIM 7
#define CD2  49
#define CD4  2401
#define NH1  384
#define NH2  256
#define LDK  2432    // CD4 padded to multiple of 32
#define PITCHB 272   // corr LDS row pitch in bytes (136 bf16 / 68 dwords) -> 4-bank skew per row

typedef __attribute__((ext_vector_type(8))) short short8;
typedef __attribute__((ext_vector_type(4))) float f32x4;

// ---------------- helpers ----------------

__device__ __forceinline__ float b2f(unsigned short u) {
    union { unsigned int i; float f; } c;
    c.i = ((unsigned int)u) << 16;
    return c.f;
}
__device__ __forceinline__ unsigned short f2b(float x) {
    __hip_bfloat16 h = __float2bfloat16(x);
    return *(unsigned short*)&h;
}

__device__ __forceinline__ float gelu_tanh(float x) {
    float x3 = x * x * x;
    float u = 0.7978845608028654f * (x + 0.044715f * x3);
    return 0.5f * x * (1.f + tanhf(u));
}

__device__ __forceinline__ int plane_a(int k) { return (k == 2) ? 1 : 0; }
__device__ __forceinline__ int plane_b(int k) { return (k == 0) ? 1 : 2; }

// async global->LDS, 16B per lane; LDS dst must be wave-uniform base
__device__ __forceinline__ void gload16(const void* g, void* l) {
    __builtin_amdgcn_global_load_lds(
        (const __attribute__((address_space(1))) unsigned int*)g,
        (__attribute__((address_space(3))) unsigned int*)l,
        16, 0, 0);
}

// ---------------- fp32 channel-first -> bf16 channel-last transpose ----------------
// in:  fp0[((s*384 + dd*3 + k)*96 + y)*96 + x]  fp32
// out: lev0[(((k*8+s)*96 + y)*96 + x)*128 + dd] bf16
// one block per (k,s,y); LDS tile [128][97] fp32 (conflict-free both phases)

__global__ __launch_bounds__(256) void cvt_cl_kernel(const float* __restrict__ in,
                                                     __hip_bfloat16* __restrict__ out) {
    __shared__ float lds[128][97];
    const int b = blockIdx.x;      // (k*8+s)*96 + y
    const int y = b % 96;
    const int ks = b / 96;         // k*8+s
    const int k = ks >> 3, s = ks & 7;
    const int tid = threadIdx.x;
    for (int idx = tid; idx < 128 * 96; idx += 256) {
        int dd = idx / 96, x = idx - dd * 96;
        lds[dd][x] = in[(((size_t)s * 384 + dd * 3 + k) * 96 + y) * 96 + x];
    }
    __syncthreads();
    unsigned int* orow = (unsigned int*)((unsigned short*)out + ((size_t)ks * 96 + y) * 96 * 128);
    for (int idx = tid; idx < 96 * 64; idx += 256) {
        int x = idx >> 6, d2 = idx & 63;
        unsigned int lo = f2b(lds[2 * d2][x]);
        unsigned int hi = f2b(lds[2 * d2 + 1][x]);
        orow[x * 64 + d2] = lo | (hi << 16);
    }
}

// ---------------- 2x2 avg pool, channel-last bf16 ----------------
// idx -> (ks, y, x, d8); in rows are 256B-contiguous channel vectors

__global__ __launch_bounds__(256) void pool_cl(const __hip_bfloat16* __restrict__ in,
                                               __hip_bfloat16* __restrict__ out,
                                               int vin, int total8) {
    int idx = blockIdx.x * 256 + threadIdx.x;
    if (idx >= total8) return;
    int vout = vin >> 1;
    int d8 = idx & 15;
    int t = idx >> 4;
    int x = t % vout; t /= vout;
    int y = t % vout; t /= vout;   // t = ks
    const unsigned short* base = (const unsigned short*)in
        + (((size_t)t * vin + 2 * y) * vin + 2 * x) * 128 + d8 * 8;
    short8 a = *(const short8*)(base);
    short8 bq = *(const short8*)(base + 128);
    short8 c = *(const short8*)(base + (size_t)vin * 128);
    short8 d = *(const short8*)(base + (size_t)vin * 128 + 128);
    short8 r;
    #pragma unroll
    for (int j = 0; j < 8; ++j) {
        float sum = b2f((unsigned short)a[j]) + b2f((unsigned short)bq[j])
                  + b2f((unsigned short)c[j]) + b2f((unsigned short)d[j]);
        r[j] = (short)f2b(0.25f * sum);
    }
    *(short8*)((unsigned short*)out + ((((size_t)t * vout + y) * vout + x)) * 128 + d8 * 8) = r;
}

// ---------------- track features (frame 0 bilinear), channel-last in, [k][n][xy][dd] out ----------------
// XCD-local decode: g = (bid&7)*96 + (bid>>3); k = g>>8, n = g&255
// (each XCD mostly touches one k-plane of frame 0, ~2.4 MB -> L2-resident)

__global__ __launch_bounds__(256) void tf_kernel(const __hip_bfloat16* __restrict__ lev,
                                                 const float* __restrict__ coords_init,
                                                 __hip_bfloat16* __restrict__ tfb,
                                                 int v, float inv_scale) {
    const int bid = blockIdx.x;
    const int g = (bid & 7) * 96 + (bid >> 3);
    const int k = g >> 8;
    const int n = g & 255;
    const float vm1 = (float)(v - 1);
    float cx = coords_init[n * 3 + plane_a(k)] * inv_scale;
    float cy = coords_init[n * 3 + plane_b(k)] * inv_scale;
    const unsigned short* frame = (const unsigned short*)lev + (size_t)(k * 8) * v * v * 128;
    unsigned short* dst = (unsigned short*)tfb + ((size_t)(k * NTRK + n)) * (DLAT * CD2);
    for (int idx = threadIdx.x; idx < CD2 * 16; idx += 256) {
        int xy = idx >> 4;
        int c8 = idx & 15;
        int i = xy / CDIM, j = xy % CDIM;
        float X = fminf(fmaxf(cx + (float)(i - 3), 0.f), vm1);
        float Y = fminf(fmaxf(cy + (float)(j - 3), 0.f), vm1);
        float xf = floorf(X), yf = floorf(Y);
        int x0 = (int)xf, y0 = (int)yf;
        int x1 = min(x0 + 1, v - 1), y1 = min(y0 + 1, v - 1);
        float wx = X - xf, wy = Y - yf;
        const unsigned short* r00 = frame + ((size_t)y0 * v + x0) * 128 + c8 * 8;
        const unsigned short* r01 = frame + ((size_t)y0 * v + x1) * 128 + c8 * 8;
        const unsigned short* r10 = frame + ((size_t)y1 * v + x0) * 128 + c8 * 8;
        const unsigned short* r11 = frame + ((size_t)y1 * v + x1) * 128 + c8 * 8;
        short8 a = *(const short8*)r00, bq = *(const short8*)r01;
        short8 c = *(const short8*)r10, d = *(const short8*)r11;
        float w00 = (1.f - wy) * (1.f - wx), w01 = (1.f - wy) * wx;
        float w10 = wy * (1.f - wx), w11 = wy * wx;
        short8 r;
        #pragma unroll
        for (int e = 0; e < 8; ++e) {
            float val = b2f((unsigned short)a[e]) * w00 + b2f((unsigned short)bq[e]) * w01
                      + b2f((unsigned short)c[e]) * w10 + b2f((unsigned short)d[e]) * w11;
            r[e] = (short)f2b(val);
        }
        *(short8*)(dst + xy * 128 + c8 * 8) = r;
    }
}

// ---------------- fused patch-MFMA correlation (channel-last frames) ----------------
// grid 6144; XCD-locality decode: s = bid&7, n = (bid>>3)&255, k = bid>>11
// c4 = W_interp (P @ tf^T); P = 8x8 integer-aligned patch per channel.
// Output (h,w) samples X = cx+(h-3) [x-axis], Y = cy+(w-3) [y-axis];
// patch pos = py*8+px with px<->x; tap for (h,w) is pos = w*8 + h.

__global__ __launch_bounds__(256) void corr_mfma(const __hip_bfloat16* __restrict__ lev,
                                                 const float* __restrict__ coords,
                                                 const __hip_bfloat16* __restrict__ tfb,
                                                 __hip_bfloat16* __restrict__ c4b,
                                                 int v, float inv_scale) {
    __shared__ __align__(16) char patch[64 * PITCHB];  // P: [pos][dd] bf16; later Cfull fp32 [pos][xy]
    __shared__ __align__(16) char tfs[64 * PITCHB];    // B: [xy][dd] bf16
    __shared__ float wxs[8], wys[8];
    const int B = blockIdx.x;
    const int s = B & 7;
    const int n = (B >> 3) & 255;
    const int k = B >> 11;
    const int sn = s * 256 + n;
    const int tid = threadIdx.x;
    const float vm1 = (float)(v - 1);
    float cx = coords[sn * 3 + plane_a(k)] * inv_scale;
    float cy = coords[sn * 3 + plane_b(k)] * inv_scale;
    const int fx = (int)floorf(cx), fy = (int)floorf(cy);

    // block-uniform interpolation weights (0 at clamped taps)
    if (tid < 7) {
        float X = fminf(fmaxf(cx + (float)(tid - 3), 0.f), vm1);
        int g = min(max(fx + tid - 3, 0), v - 1);
        wxs[tid] = X - (float)g;
        float Y = fminf(fmaxf(cy + (float)(tid - 3), 0.f), vm1);
        int gy_ = min(max(fy + tid - 3, 0), v - 1);
        wys[tid] = Y - (float)gy_;
    }

    // stage tf: 49 rows x 256B = 784 x 16B chunks
    const short8* tfg = (const short8*)(tfb + ((size_t)(k * NTRK + n)) * (DLAT * CD2));
    for (int idx = tid; idx < 784; idx += 256) {
        int row = idx >> 4, c16 = idx & 15;
        *(short8*)(tfs + row * PITCHB + c16 * 16) = tfg[idx];
    }

    // stage patch: 64 pos x 16 chunks, coalesced 256B channel-last rows
    {
        const unsigned short* frame = (const unsigned short*)lev + (size_t)(k * 8 + s) * v * v * 128;
        for (int idx = tid; idx < 1024; idx += 256) {
            int pos = idx >> 4, c8 = idx & 15;
            int px = pos & 7, py = pos >> 3;
            int gx = min(max(fx + px - 3, 0), v - 1);
            int gy = min(max(fy + py - 3, 0), v - 1);
            short8 val = *(const short8*)(frame + ((size_t)gy * v + gx) * 128 + c8 * 8);
            *(short8*)(patch + pos * PITCHB + c8 * 16) = val;
        }
    }
    __syncthreads();

    const int w4 = tid >> 6, l = tid & 63;
    const int l15 = l & 15, l4 = l >> 4;
    f32x4 acc[4];
    #pragma unroll
    for (int nt = 0; nt < 4; ++nt) acc[nt] = (f32x4){0.f, 0.f, 0.f, 0.f};
    #pragma unroll
    for (int ks = 0; ks < 4; ++ks) {
        short8 af = *(const short8*)(patch + (16 * w4 + l15) * PITCHB + ks * 64 + l4 * 16);
        #pragma unroll
        for (int nt = 0; nt < 4; ++nt) {
            short8 bf = *(const short8*)(tfs + (16 * nt + l15) * PITCHB + ks * 64 + l4 * 16);
            acc[nt] = __builtin_amdgcn_mfma_f32_16x16x32_bf16(af, bf, acc[nt], 0, 0, 0);
        }
    }
    __syncthreads();  // all patch reads done before overwrite

    // write Cfull fp32 [pos][xy] into the patch region (64 x 272B >= 64 x 256B)
    {
        const int row0 = 16 * w4 + l4 * 4;
        #pragma unroll
        for (int nt = 0; nt < 4; ++nt) {
            int col = nt * 16 + l15;
            #pragma unroll
            for (int j = 0; j < 4; ++j)
                *(float*)(patch + (row0 + j) * PITCHB + col * 4) = acc[nt][j];
        }
    }
    __syncthreads();

    // 4-tap interpolation on the 49x49 output.
    // Output (h,w): tap pos = w*8 + h; +PITCHB = x+1 (weight wx=wxs[h]);
    // +8*PITCHB = y+1 (weight wy=wys[w]).
    __hip_bfloat16* crow = c4b + (size_t)(k * 2048 + sn) * LDK;
    for (int o = tid; o < CD4; o += 256) {
        int hw = o / CD2;
        int xy = o - hw * CD2;
        int h = hw / CDIM, w_ = hw - h * CDIM;
        float wxv = wxs[h], wyv = wys[w_];
        const char* base = patch + (w_ * 8 + h) * PITCHB + xy * 4;
        float p00 = *(const float*)(base);
        float p01 = *(const float*)(base + PITCHB);        // x+1
        float p10 = *(const float*)(base + 8 * PITCHB);    // y+1
        float p11 = *(const float*)(base + 9 * PITCHB);
        float val = p00 * (1.f - wyv) * (1.f - wxv) + p01 * (1.f - wyv) * wxv
                  + p10 * wyv * (1.f - wxv) + p11 * wyv * wxv;
        crow[o] = __float2bfloat16(val);
    }
    if (tid < LDK - CD4) crow[CD4 + tid] = __float2bfloat16(0.f);
}

// ---------------- weight prep: transpose + bf16 ----------------

__global__ __launch_bounds__(256) void prep_w1t(const float* __restrict__ w1,
                                                __hip_bfloat16* __restrict__ w1t) {
    int idx = blockIdx.x * 256 + threadIdx.x;  // n*LDK + kk
    if (idx >= NH1 * LDK) return;
    int n = idx / LDK, kk = idx - n * LDK;
    float v = (kk < CD4) ? w1[(size_t)kk * NH1 + n] : 0.f;
    w1t[idx] = __float2bfloat16(v);
}

__global__ __launch_bounds__(256) void prep_w2t(const float* __restrict__ w2,
                                                __hip_bfloat16* __restrict__ w2t) {
    int idx = blockIdx.x * 256 + threadIdx.x;  // n*NH1 + j
    if (idx >= NH2 * NH1) return;
    int n = idx / NH1, j = idx - n * NH1;
    w2t[idx] = __float2bfloat16(w2[(size_t)j * NH2 + n]);
}

// ---------------- GEMM1 MFMA: (6144 x LDK) @ w1t^T -> gelu -> H bf16 ----------------
// BM=128 BN=64 BK=32, 4 waves (2x2), wave tile 64x32 = 4x2 frags of 16x16

__global__ __launch_bounds__(256) void gemm1_mfma(
    const __hip_bfloat16* __restrict__ A,    // [6144][LDK]
    const __hip_bfloat16* __restrict__ Bt,   // [NH1][LDK]
    const float* __restrict__ b1,
    __hip_bfloat16* __restrict__ H) {        // [6144][NH1]
    __shared__ __align__(16) char smem[12288];
    char* Asm = smem;          // 128 rows x 64B
    char* Bsm = smem + 8192;   // 64 rows x 64B
    const int m0 = blockIdx.x * 128, n0 = blockIdx.y * 64;
    const int tid = threadIdx.x;
    const int w = tid >> 6, l = tid & 63;
    const int wr = w >> 1, wc = w & 1;
    const int l15 = l & 15, l4 = l >> 4;
    f32x4 acc[4][2];
    #pragma unroll
    for (int m = 0; m < 4; ++m)
        #pragma unroll
        for (int n = 0; n < 2; ++n) acc[m][n] = (f32x4){0.f, 0.f, 0.f, 0.f};
    const char* Ag = (const char*)(A + (size_t)(m0 + (tid >> 2)) * LDK) + (tid & 3) * 16;
    const char* Bg = (const char*)(Bt + (size_t)(n0 + (tid >> 2)) * LDK) + (tid & 3) * 16;
    char* AsmW = Asm + w * 1024;
    char* BsmW = Bsm + w * 1024;
    for (int kb = 0; kb < LDK * 2; kb += 64) {  // byte offset along K
        gload16(Ag + kb, AsmW);                               // rows 0..63
        gload16(Ag + (size_t)64 * LDK * 2 + kb, AsmW + 4096); // rows 64..127
        gload16(Bg + kb, BsmW);
        __syncthreads();
        short8 af[4], bfr[2];
        #pragma unroll
        for (int m = 0; m < 4; ++m)
            af[m] = *(const short8*)(Asm + (wr * 64 + m * 16 + l15) * 64 + l4 * 16);
        #pragma unroll
        for (int n = 0; n < 2; ++n)
            bfr[n] = *(const short8*)(Bsm + (wc * 32 + n * 16 + l15) * 64 + l4 * 16);
        #pragma unroll
        for (int m = 0; m < 4; ++m)
            #pragma unroll
            for (int n = 0; n < 2; ++n)
                acc[m][n] = __builtin_amdgcn_mfma_f32_16x16x32_bf16(af[m], bfr[n], acc[m][n], 0, 0, 0);
        __syncthreads();
    }
    #pragma unroll
    for (int m = 0; m < 4; ++m) {
        int row = m0 + wr * 64 + m * 16 + l4 * 4;
        #pragma unroll
        for (int n = 0; n < 2; ++n) {
            int col = n0 + wc * 32 + n * 16 + l15;
            float bias = b1[col];
            #pragma unroll
            for (int j = 0; j < 4; ++j)
                H[(size_t)(row + j) * NH1 + col] = __float2bfloat16(gelu_tanh(acc[m][n][j] + bias));
        }
    }
}

// ---------------- GEMM2 MFMA: (2048 x 1152) @ stacked w2t -> out slice ----------------

__global__ __launch_bounds__(256) void gemm2_mfma(
    const __hip_bfloat16* __restrict__ Hin,  // [3*2048][NH1]
    const __hip_bfloat16* __restrict__ Bt,   // [NH2][NH1]
    const float* __restrict__ b2,
    float* __restrict__ out, int level) {
    __shared__ __align__(16) char smem[8192];
    char* Asm = smem;         // 64 rows x 64B
    char* Bsm = smem + 4096;
    const int m0 = blockIdx.x * 64, n0 = blockIdx.y * 64;
    const int tid = threadIdx.x;
    const int w = tid >> 6, l = tid & 63;
    const int wr = w >> 1, wc = w & 1;
    const int l15 = l & 15, l4 = l >> 4;
    f32x4 acc[2][2];
    #pragma unroll
    for (int m = 0; m < 2; ++m)
        #pragma unroll
        for (int n = 0; n < 2; ++n) acc[m][n] = (f32x4){0.f, 0.f, 0.f, 0.f};
    const char* Bg = (const char*)(Bt + (size_t)(n0 + (tid >> 2)) * NH1) + (tid & 3) * 16;
    char* AsmW = Asm + w * 1024;
    char* BsmW = Bsm + w * 1024;
    for (int p = 0; p < 3; ++p) {
        const char* Ag = (const char*)(Hin + (size_t)(p * 2048 + m0 + (tid >> 2)) * NH1) + (tid & 3) * 16;
        for (int jb = 0; jb < NH1 * 2; jb += 64) {
            gload16(Ag + jb, AsmW);
            gload16(Bg + jb, BsmW);
            __syncthreads();
            short8 af[2], bfr[2];
            #pragma unroll
            for (int m = 0; m < 2; ++m)
                af[m] = *(const short8*)(Asm + (wr * 32 + m * 16 + l15) * 64 + l4 * 16);
            #pragma unroll
            for (int n = 0; n < 2; ++n)
                bfr[n] = *(const short8*)(Bsm + (wc * 32 + n * 16 + l15) * 64 + l4 * 16);
            #pragma unroll
            for (int m = 0; m < 2; ++m)
                #pragma unroll
                for (int n = 0; n < 2; ++n)
                    acc[m][n] = __builtin_amdgcn_mfma_f32_16x16x32_bf16(af[m], bfr[n], acc[m][n], 0, 0, 0);
            __syncthreads();
        }
    }
    #pragma unroll
    for (int m = 0; m < 2; ++m) {
        int row = m0 + wr * 32 + m * 16 + l4 * 4;
        #pragma unroll
        for (int n = 0; n < 2; ++n) {
            int col = n0 + wc * 32 + n * 16 + l15;
            float bias3 = 3.f * b2[col];
            #pragma unroll
            for (int j = 0; j < 4; ++j)
                out[(size_t)(row + j) * 1024 + level * NH2 + col] = acc[m][n][j] + bias3;
        }
    }
}

// ---------------- launch ----------------

extern "C" void kernel_launch(void* const* d_in, const int* in_sizes, int n_in,
                              void* d_out, int out_size, void* d_ws, size_t ws_size,
                              hipStream_t stream) {
    const float* coords      = (const float*)d_in[0];
    const float* coords_init = (const float*)d_in[1];
    const float* fp0         = (const float*)d_in[2];
    const float* w1          = (const float*)d_in[3];
    const float* b1          = (const float*)d_in[4];
    const float* w2          = (const float*)d_in[5];
    const float* b2          = (const float*)d_in[6];
    float* out = (float*)d_out;
    char* ws = (char*)d_ws;

    const size_t SZ_L0 = (size_t)3 * 8 * 96 * 96 * 128;   // channel-last elems
    const size_t SZ_L1 = (size_t)3 * 8 * 48 * 48 * 128;
    const size_t SZ_L2 = (size_t)3 * 8 * 24 * 24 * 128;
    const size_t SZ_L3 = (size_t)3 * 8 * 12 * 12 * 128;
    const size_t SZ_TF = (size_t)3 * NTRK * DLAT * CD2;

    __hip_bfloat16* lev0 = (__hip_bfloat16*)ws;      ws += SZ_L0 * 2;
    __hip_bfloat16* lev1 = (__hip_bfloat16*)ws;      ws += SZ_L1 * 2;
    __hip_bfloat16* lev2 = (__hip_bfloat16*)ws;      ws += SZ_L2 * 2;
    __hip_bfloat16* lev3 = (__hip_bfloat16*)ws;      ws += SZ_L3 * 2;
    __hip_bfloat16* tfb  = (__hip_bfloat16*)ws;      ws += SZ_TF * 2;
    __hip_bfloat16* c4b  = (__hip_bfloat16*)ws;      ws += (size_t)6144 * LDK * 2;
    __hip_bfloat16* h_ws = (__hip_bfloat16*)ws;      ws += (size_t)6144 * NH1 * 2;
    __hip_bfloat16* w1t  = (__hip_bfloat16*)ws;      ws += (size_t)NH1 * LDK * 2;
    __hip_bfloat16* w2t  = (__hip_bfloat16*)ws;      ws += (size_t)NH2 * NH1 * 2;

    prep_w1t<<<(NH1 * LDK + 255) / 256, 256, 0, stream>>>(w1, w1t);
    prep_w2t<<<(NH2 * NH1 + 255) / 256, 256, 0, stream>>>(w2, w2t);

    cvt_cl_kernel<<<24 * 96, 256, 0, stream>>>(fp0, lev0);
    pool_cl<<<(int)((SZ_L1 / 8 + 255) / 256), 256, 0, stream>>>(lev0, lev1, 96, (int)(SZ_L1 / 8));
    pool_cl<<<(int)((SZ_L2 / 8 + 255) / 256), 256, 0, stream>>>(lev1, lev2, 48, (int)(SZ_L2 / 8));
    pool_cl<<<(int)((SZ_L3 / 8 + 255) / 256), 256, 0, stream>>>(lev2, lev3, 24, (int)(SZ_L3 / 8));

    const __hip_bfloat16* levs[4] = {lev0, lev1, lev2, lev3};
    const int vs[4] = {96, 48, 24, 12};
    for (int i = 0; i < 4; ++i) {
        float inv = 1.f / (float)(1 << i);
        tf_kernel<<<3 * NTRK, 256, 0, stream>>>(levs[i], coords_init, tfb, vs[i], inv);
        corr_mfma<<<3 * 2048, 256, 0, stream>>>(levs[i], coords, tfb, c4b, vs[i], inv);
        gemm1_mfma<<<dim3(48, 6), 256, 0, stream>>>(c4b, w1t, b1, h_ws);
        gemm2_mfma<<<dim3(32, 4), 256, 0, stream>>>(h_ws, w2t, b2, out, i);
    }
}

// Round 8
// 439.777 us; speedup vs baseline: 6.0296x; 1.0528x over previous
//
#include <hip/hip_runtime.h>
#include <hip/hip_bf16.h>
#include <math.h>

#define NTRK 256
#define DLAT 128
#define CDIM 7
#define CD2  49
#define CD4  2401
#define NH1  384
#define NH2  256
#define LDK  2432    // CD4 padded to multiple of 32
#define PITCHB 272   // corr LDS row pitch in bytes (136 bf16 / 68 dwords) -> 4-bank skew per row

typedef __attribute__((ext_vector_type(8))) short short8;
typedef __attribute__((ext_vector_type(4))) float f32x4;
typedef __attribute__((ext_vector_type(4))) unsigned int u32x4;

// ---------------- helpers ----------------

__device__ __forceinline__ float b2f(unsigned short u) {
    union { unsigned int i; float f; } c;
    c.i = ((unsigned int)u) << 16;
    return c.f;
}
__device__ __forceinline__ unsigned int f2b(float x) {
    __hip_bfloat16 h = __float2bfloat16(x);
    return (unsigned int)(*(unsigned short*)&h);
}

__device__ __forceinline__ float gelu_tanh(float x) {
    float x3 = x * x * x;
    float u = 0.7978845608028654f * (x + 0.044715f * x3);
    return 0.5f * x * (1.f + tanhf(u));
}

__device__ __forceinline__ int plane_a(int k) { return (k == 2) ? 1 : 0; }
__device__ __forceinline__ int plane_b(int k) { return (k == 0) ? 1 : 2; }

// async global->LDS, 16B per lane; LDS dst must be wave-uniform base
__device__ __forceinline__ void gload16(const void* g, void* l) {
    __builtin_amdgcn_global_load_lds(
        (const __attribute__((address_space(1))) unsigned int*)g,
        (__attribute__((address_space(3))) unsigned int*)l,
        16, 0, 0);
}

// ---------------- fp32 channel-first -> bf16 channel-last transpose ----------------
// in:  fp0[((s*384 + dd*3 + k)*96 + y)*96 + x]  fp32
// out: lev0[(((k*8+s)*96 + y)*96 + x)*128 + dd] bf16
// one block per (k,s,y); LDS u32 tile [64][97] = packed bf16 pairs (24.8 KB -> 6 blocks/CU).
// Phase 1: float4 loads + pack (conflict-free row writes).
// Phase 2: 4 column reads (stride 97 == 1 mod 32, conflict-free) + dwordx4 store.

__global__ __launch_bounds__(256) void cvt_cl_kernel(const float* __restrict__ in,
                                                     __hip_bfloat16* __restrict__ out) {
    __shared__ unsigned int lds[64][97];   // lds[d2][x] = bf16(2*d2) | bf16(2*d2+1)<<16
    const int b = blockIdx.x;      // (k*8+s)*96 + y
    const int y = b % 96;
    const int ks = b / 96;         // k*8+s
    const int k = ks >> 3, s = ks & 7;
    const int tid = threadIdx.x;
    for (int idx = tid; idx < 64 * 24; idx += 256) {
        int d2 = idx / 24, x4 = (idx - d2 * 24) * 4;
        const float* rlo = in + (((size_t)s * 384 + (2 * d2) * 3 + k) * 96 + y) * 96 + x4;
        const float* rhi = in + (((size_t)s * 384 + (2 * d2 + 1) * 3 + k) * 96 + y) * 96 + x4;
        float4 lo = *(const float4*)rlo;
        float4 hi = *(const float4*)rhi;
        lds[d2][x4 + 0] = f2b(lo.x) | (f2b(hi.x) << 16);
        lds[d2][x4 + 1] = f2b(lo.y) | (f2b(hi.y) << 16);
        lds[d2][x4 + 2] = f2b(lo.z) | (f2b(hi.z) << 16);
        lds[d2][x4 + 3] = f2b(lo.w) | (f2b(hi.w) << 16);
    }
    __syncthreads();
    unsigned int* orow = (unsigned int*)((unsigned short*)out + ((size_t)ks * 96 + y) * 96 * 128);
    for (int idx = tid; idx < 96 * 16; idx += 256) {
        int x = idx >> 4, q = idx & 15;   // q = group of 4 d2 (8 channels)
        u32x4 r;
        r[0] = lds[4 * q + 0][x];
        r[1] = lds[4 * q + 1][x];
        r[2] = lds[4 * q + 2][x];
        r[3] = lds[4 * q + 3][x];
        *(u32x4*)(orow + x * 64 + q * 4) = r;
    }
}

// ---------------- 2x2 avg pool, channel-last bf16 ----------------
// idx -> (ks, y, x, d8); in rows are 256B-contiguous channel vectors

__global__ __launch_bounds__(256) void pool_cl(const __hip_bfloat16* __restrict__ in,
                                               __hip_bfloat16* __restrict__ out,
                                               int vin, int total8) {
    int idx = blockIdx.x * 256 + threadIdx.x;
    if (idx >= total8) return;
    int vout = vin >> 1;
    int d8 = idx & 15;
    int t = idx >> 4;
    int x = t % vout; t /= vout;
    int y = t % vout; t /= vout;   // t = ks
    const unsigned short* base = (const unsigned short*)in
        + (((size_t)t * vin + 2 * y) * vin + 2 * x) * 128 + d8 * 8;
    short8 a = *(const short8*)(base);
    short8 bq = *(const short8*)(base + 128);
    short8 c = *(const short8*)(base + (size_t)vin * 128);
    short8 d = *(const short8*)(base + (size_t)vin * 128 + 128);
    short8 r;
    #pragma unroll
    for (int j = 0; j < 8; ++j) {
        float sum = b2f((unsigned short)a[j]) + b2f((unsigned short)bq[j])
                  + b2f((unsigned short)c[j]) + b2f((unsigned short)d[j]);
        r[j] = (short)f2b(0.25f * sum);
    }
    *(short8*)((unsigned short*)out + ((((size_t)t * vout + y) * vout + x)) * 128 + d8 * 8) = r;
}

// ---------------- track features (frame 0 bilinear), channel-last in, [k][n][xy][dd] out ----------------
// XCD-local decode: g = (bid&7)*96 + (bid>>3); k = g>>8, n = g&255

__global__ __launch_bounds__(256) void tf_kernel(const __hip_bfloat16* __restrict__ lev,
                                                 const float* __restrict__ coords_init,
                                                 __hip_bfloat16* __restrict__ tfb,
                                                 int v, float inv_scale) {
    const int bid = blockIdx.x;
    const int g = (bid & 7) * 96 + (bid >> 3);
    const int k = g >> 8;
    const int n = g & 255;
    const float vm1 = (float)(v - 1);
    float cx = coords_init[n * 3 + plane_a(k)] * inv_scale;
    float cy = coords_init[n * 3 + plane_b(k)] * inv_scale;
    const unsigned short* frame = (const unsigned short*)lev + (size_t)(k * 8) * v * v * 128;
    unsigned short* dst = (unsigned short*)tfb + ((size_t)(k * NTRK + n)) * (DLAT * CD2);
    for (int idx = threadIdx.x; idx < CD2 * 16; idx += 256) {
        int xy = idx >> 4;
        int c8 = idx & 15;
        int i = xy / CDIM, j = xy % CDIM;
        float X = fminf(fmaxf(cx + (float)(i - 3), 0.f), vm1);
        float Y = fminf(fmaxf(cy + (float)(j - 3), 0.f), vm1);
        float xf = floorf(X), yf = floorf(Y);
        int x0 = (int)xf, y0 = (int)yf;
        int x1 = min(x0 + 1, v - 1), y1 = min(y0 + 1, v - 1);
        float wx = X - xf, wy = Y - yf;
        const unsigned short* r00 = frame + ((size_t)y0 * v + x0) * 128 + c8 * 8;
        const unsigned short* r01 = frame + ((size_t)y0 * v + x1) * 128 + c8 * 8;
        const unsigned short* r10 = frame + ((size_t)y1 * v + x0) * 128 + c8 * 8;
        const unsigned short* r11 = frame + ((size_t)y1 * v + x1) * 128 + c8 * 8;
        short8 a = *(const short8*)r00, bq = *(const short8*)r01;
        short8 c = *(const short8*)r10, d = *(const short8*)r11;
        float w00 = (1.f - wy) * (1.f - wx), w01 = (1.f - wy) * wx;
        float w10 = wy * (1.f - wx), w11 = wy * wx;
        short8 r;
        #pragma unroll
        for (int e = 0; e < 8; ++e) {
            float val = b2f((unsigned short)a[e]) * w00 + b2f((unsigned short)bq[e]) * w01
                      + b2f((unsigned short)c[e]) * w10 + b2f((unsigned short)d[e]) * w11;
            r[e] = (short)f2b(val);
        }
        *(short8*)(dst + xy * 128 + c8 * 8) = r;
    }
}

// ---------------- fused patch-MFMA correlation (channel-last frames) ----------------
// grid 6144; XCD-locality decode: s = bid&7, n = (bid>>3)&255, k = bid>>11
// c4 = W_interp (P @ tf^T); P = 8x8 integer-aligned patch per channel.
// Output (h,w) samples X = cx+(h-3) [x-axis], Y = cy+(w-3) [y-axis];
// patch pos = py*8+px with px<->x; tap for (h,w) is pos = w*8 + h.

__global__ __launch_bounds__(256) void corr_mfma(const __hip_bfloat16* __restrict__ lev,
                                                 const float* __restrict__ coords,
                                                 const __hip_bfloat16* __restrict__ tfb,
                                                 __hip_bfloat16* __restrict__ c4b,
                                                 int v, float inv_scale) {
    __shared__ __align__(16) char patch[64 * PITCHB];  // P: [pos][dd] bf16; later Cfull fp32 [pos][xy]
    __shared__ __align__(16) char tfs[64 * PITCHB];    // B: [xy][dd] bf16
    __shared__ float wxs[8], wys[8];
    const int B = blockIdx.x;
    const int s = B & 7;
    const int n = (B >> 3) & 255;
    const int k = B >> 11;
    const int sn = s * 256 + n;
    const int tid = threadIdx.x;
    const float vm1 = (float)(v - 1);
    float cx = coords[sn * 3 + plane_a(k)] * inv_scale;
    float cy = coords[sn * 3 + plane_b(k)] * inv_scale;
    const int fx = (int)floorf(cx), fy = (int)floorf(cy);

    // block-uniform interpolation weights (0 at clamped taps)
    if (tid < 7) {
        float X = fminf(fmaxf(cx + (float)(tid - 3), 0.f), vm1);
        int g = min(max(fx + tid - 3, 0), v - 1);
        wxs[tid] = X - (float)g;
        float Y = fminf(fmaxf(cy + (float)(tid - 3), 0.f), vm1);
        int gy_ = min(max(fy + tid - 3, 0), v - 1);
        wys[tid] = Y - (float)gy_;
    }

    // stage tf: 49 rows x 256B = 784 x 16B chunks
    const short8* tfg = (const short8*)(tfb + ((size_t)(k * NTRK + n)) * (DLAT * CD2));
    for (int idx = tid; idx < 784; idx += 256) {
        int row = idx >> 4, c16 = idx & 15;
        *(short8*)(tfs + row * PITCHB + c16 * 16) = tfg[idx];
    }

    // stage patch: 64 pos x 16 chunks, coalesced 256B channel-last rows
    {
        const unsigned short* frame = (const unsigned short*)lev + (size_t)(k * 8 + s) * v * v * 128;
        for (int idx = tid; idx < 1024; idx += 256) {
            int pos = idx >> 4, c8 = idx & 15;
            int px = pos & 7, py = pos >> 3;
            int gx = min(max(fx + px - 3, 0), v - 1);
            int gy = min(max(fy + py - 3, 0), v - 1);
            short8 val = *(const short8*)(frame + ((size_t)gy * v + gx) * 128 + c8 * 8);
            *(short8*)(patch + pos * PITCHB + c8 * 16) = val;
        }
    }
    __syncthreads();

    const int w4 = tid >> 6, l = tid & 63;
    const int l15 = l & 15, l4 = l >> 4;
    f32x4 acc[4];
    #pragma unroll
    for (int nt = 0; nt < 4; ++nt) acc[nt] = (f32x4){0.f, 0.f, 0.f, 0.f};
    #pragma unroll
    for (int ks = 0; ks < 4; ++ks) {
        short8 af = *(const short8*)(patch + (16 * w4 + l15) * PITCHB + ks * 64 + l4 * 16);
        #pragma unroll
        for (int nt = 0; nt < 4; ++nt) {
            short8 bf = *(const short8*)(tfs + (16 * nt + l15) * PITCHB + ks * 64 + l4 * 16);
            acc[nt] = __builtin_amdgcn_mfma_f32_16x16x32_bf16(af, bf, acc[nt], 0, 0, 0);
        }
    }
    __syncthreads();  // all patch reads done before overwrite

    // write Cfull fp32 [pos][xy] into the patch region (64 x 272B >= 64 x 256B)
    {
        const int row0 = 16 * w4 + l4 * 4;
        #pragma unroll
        for (int nt = 0; nt < 4; ++nt) {
            int col = nt * 16 + l15;
            #pragma unroll
            for (int j = 0; j < 4; ++j)
                *(float*)(patch + (row0 + j) * PITCHB + col * 4) = acc[nt][j];
        }
    }
    __syncthreads();

    // 4-tap interpolation on the 49x49 output.
    // Output (h,w): tap pos = w*8 + h; +PITCHB = x+1 (weight wx=wxs[h]);
    // +8*PITCHB = y+1 (weight wy=wys[w]).
    __hip_bfloat16* crow = c4b + (size_t)(k * 2048 + sn) * LDK;
    for (int o = tid; o < CD4; o += 256) {
        int hw = o / CD2;
        int xy = o - hw * CD2;
        int h = hw / CDIM, w_ = hw - h * CDIM;
        float wxv = wxs[h], wyv = wys[w_];
        const char* base = patch + (w_ * 8 + h) * PITCHB + xy * 4;
        float p00 = *(const float*)(base);
        float p01 = *(const float*)(base + PITCHB);        // x+1
        float p10 = *(const float*)(base + 8 * PITCHB);    // y+1
        float p11 = *(const float*)(base + 9 * PITCHB);
        float val = p00 * (1.f - wyv) * (1.f - wxv) + p01 * (1.f - wyv) * wxv
                  + p10 * wyv * (1.f - wxv) + p11 * wyv * wxv;
        crow[o] = __float2bfloat16(val);
    }
    if (tid < LDK - CD4) crow[CD4 + tid] = __float2bfloat16(0.f);
}

// ---------------- weight prep: transpose + bf16 ----------------

__global__ __launch_bounds__(256) void prep_w1t(const float* __restrict__ w1,
                                                __hip_bfloat16* __restrict__ w1t) {
    int idx = blockIdx.x * 256 + threadIdx.x;  // n*LDK + kk
    if (idx >= NH1 * LDK) return;
    int n = idx / LDK, kk = idx - n * LDK;
    float v = (kk < CD4) ? w1[(size_t)kk * NH1 + n] : 0.f;
    w1t[idx] = __float2bfloat16(v);
}

__global__ __launch_bounds__(256) void prep_w2t(const float* __restrict__ w2,
                                                __hip_bfloat16* __restrict__ w2t) {
    int idx = blockIdx.x * 256 + threadIdx.x;  // n*NH1 + j
    if (idx >= NH2 * NH1) return;
    int n = idx / NH1, j = idx - n * NH1;
    w2t[idx] = __float2bfloat16(w2[(size_t)j * NH2 + n]);
}

// ---------------- GEMM1 MFMA: (6144 x LDK) @ w1t^T -> gelu -> H bf16 ----------------
// BM=128 BN=64 BK=32, 4 waves (2x2), wave tile 64x32 = 4x2 frags of 16x16

__global__ __launch_bounds__(256) void gemm1_mfma(
    const __hip_bfloat16* __restrict__ A,    // [6144][LDK]
    const __hip_bfloat16* __restrict__ Bt,   // [NH1][LDK]
    const float* __restrict__ b1,
    __hip_bfloat16* __restrict__ H) {        // [6144][NH1]
    __shared__ __align__(16) char smem[12288];
    char* Asm = smem;          // 128 rows x 64B
    char* Bsm = smem + 8192;   // 64 rows x 64B
    const int m0 = blockIdx.x * 128, n0 = blockIdx.y * 64;
    const int tid = threadIdx.x;
    const int w = tid >> 6, l = tid & 63;
    const int wr = w >> 1, wc = w & 1;
    const int l15 = l & 15, l4 = l >> 4;
    f32x4 acc[4][2];
    #pragma unroll
    for (int m = 0; m < 4; ++m)
        #pragma unroll
        for (int n = 0; n < 2; ++n) acc[m][n] = (f32x4){0.f, 0.f, 0.f, 0.f};
    const char* Ag = (const char*)(A + (size_t)(m0 + (tid >> 2)) * LDK) + (tid & 3) * 16;
    const char* Bg = (const char*)(Bt + (size_t)(n0 + (tid >> 2)) * LDK) + (tid & 3) * 16;
    char* AsmW = Asm + w * 1024;
    char* BsmW = Bsm + w * 1024;
    for (int kb = 0; kb < LDK * 2; kb += 64) {  // byte offset along K
        gload16(Ag + kb, AsmW);                               // rows 0..63
        gload16(Ag + (size_t)64 * LDK * 2 + kb, AsmW + 4096); // rows 64..127
        gload16(Bg + kb, BsmW);
        __syncthreads();
        short8 af[4], bfr[2];
        #pragma unroll
        for (int m = 0; m < 4; ++m)
            af[m] = *(const short8*)(Asm + (wr * 64 + m * 16 + l15) * 64 + l4 * 16);
        #pragma unroll
        for (int n = 0; n < 2; ++n)
            bfr[n] = *(const short8*)(Bsm + (wc * 32 + n * 16 + l15) * 64 + l4 * 16);
        #pragma unroll
        for (int m = 0; m < 4; ++m)
            #pragma unroll
            for (int n = 0; n < 2; ++n)
                acc[m][n] = __builtin_amdgcn_mfma_f32_16x16x32_bf16(af[m], bfr[n], acc[m][n], 0, 0, 0);
        __syncthreads();
    }
    #pragma unroll
    for (int m = 0; m < 4; ++m) {
        int row = m0 + wr * 64 + m * 16 + l4 * 4;
        #pragma unroll
        for (int n = 0; n < 2; ++n) {
            int col = n0 + wc * 32 + n * 16 + l15;
            float bias = b1[col];
            #pragma unroll
            for (int j = 0; j < 4; ++j)
                H[(size_t)(row + j) * NH1 + col] = __float2bfloat16(gelu_tanh(acc[m][n][j] + bias));
        }
    }
}

// ---------------- GEMM2 MFMA: (2048 x 1152) @ stacked w2t -> out slice ----------------

__global__ __launch_bounds__(256) void gemm2_mfma(
    const __hip_bfloat16* __restrict__ Hin,  // [3*2048][NH1]
    const __hip_bfloat16* __restrict__ Bt,   // [NH2][NH1]
    const float* __restrict__ b2,
    float* __restrict__ out, int level) {
    __shared__ __align__(16) char smem[8192];
    char* Asm = smem;         // 64 rows x 64B
    char* Bsm = smem + 4096;
    const int m0 = blockIdx.x * 64, n0 = blockIdx.y * 64;
    const int tid = threadIdx.x;
    const int w = tid >> 6, l = tid & 63;
    const int wr = w >> 1, wc = w & 1;
    const int l15 = l & 15, l4 = l >> 4;
    f32x4 acc[2][2];
    #pragma unroll
    for (int m = 0; m < 2; ++m)
        #pragma unroll
        for (int n = 0; n < 2; ++n) acc[m][n] = (f32x4){0.f, 0.f, 0.f, 0.f};
    const char* Bg = (const char*)(Bt + (size_t)(n0 + (tid >> 2)) * NH1) + (tid & 3) * 16;
    char* AsmW = Asm + w * 1024;
    char* BsmW = Bsm + w * 1024;
    for (int p = 0; p < 3; ++p) {
        const char* Ag = (const char*)(Hin + (size_t)(p * 2048 + m0 + (tid >> 2)) * NH1) + (tid & 3) * 16;
        for (int jb = 0; jb < NH1 * 2; jb += 64) {
            gload16(Ag + jb, AsmW);
            gload16(Bg + jb, BsmW);
            __syncthreads();
            short8 af[2], bfr[2];
            #pragma unroll
            for (int m = 0; m < 2; ++m)
                af[m] = *(const short8*)(Asm + (wr * 32 + m * 16 + l15) * 64 + l4 * 16);
            #pragma unroll
            for (int n = 0; n < 2; ++n)
                bfr[n] = *(const short8*)(Bsm + (wc * 32 + n * 16 + l15) * 64 + l4 * 16);
            #pragma unroll
            for (int m = 0; m < 2; ++m)
                #pragma unroll
                for (int n = 0; n < 2; ++n)
                    acc[m][n] = __builtin_amdgcn_mfma_f32_16x16x32_bf16(af[m], bfr[n], acc[m][n], 0, 0, 0);
            __syncthreads();
        }
    }
    #pragma unroll
    for (int m = 0; m < 2; ++m) {
        int row = m0 + wr * 32 + m * 16 + l4 * 4;
        #pragma unroll
        for (int n = 0; n < 2; ++n) {
            int col = n0 + wc * 32 + n * 16 + l15;
            float bias3 = 3.f * b2[col];
            #pragma unroll
            for (int j = 0; j < 4; ++j)
                out[(size_t)(row + j) * 1024 + level * NH2 + col] = acc[m][n][j] + bias3;
        }
    }
}

// ---------------- launch ----------------

extern "C" void kernel_launch(void* const* d_in, const int* in_sizes, int n_in,
                              void* d_out, int out_size, void* d_ws, size_t ws_size,
                              hipStream_t stream) {
    const float* coords      = (const float*)d_in[0];
    const float* coords_init = (const float*)d_in[1];
    const float* fp0         = (const float*)d_in[2];
    const float* w1          = (const float*)d_in[3];
    const float* b1          = (const float*)d_in[4];
    const float* w2          = (const float*)d_in[5];
    const float* b2          = (const float*)d_in[6];
    float* out = (float*)d_out;
    char* ws = (char*)d_ws;

    const size_t SZ_L0 = (size_t)3 * 8 * 96 * 96 * 128;   // channel-last elems
    const size_t SZ_L1 = (size_t)3 * 8 * 48 * 48 * 128;
    const size_t SZ_L2 = (size_t)3 * 8 * 24 * 24 * 128;
    const size_t SZ_L3 = (size_t)3 * 8 * 12 * 12 * 128;
    const size_t SZ_TF = (size_t)3 * NTRK * DLAT * CD2;

    __hip_bfloat16* lev0 = (__hip_bfloat16*)ws;      ws += SZ_L0 * 2;
    __hip_bfloat16* lev1 = (__hip_bfloat16*)ws;      ws += SZ_L1 * 2;
    __hip_bfloat16* lev2 = (__hip_bfloat16*)ws;      ws += SZ_L2 * 2;
    __hip_bfloat16* lev3 = (__hip_bfloat16*)ws;      ws += SZ_L3 * 2;
    __hip_bfloat16* tfb  = (__hip_bfloat16*)ws;      ws += SZ_TF * 2;
    __hip_bfloat16* c4b  = (__hip_bfloat16*)ws;      ws += (size_t)6144 * LDK * 2;
    __hip_bfloat16* h_ws = (__hip_bfloat16*)ws;      ws += (size_t)6144 * NH1 * 2;
    __hip_bfloat16* w1t  = (__hip_bfloat16*)ws;      ws += (size_t)NH1 * LDK * 2;
    __hip_bfloat16* w2t  = (__hip_bfloat16*)ws;      ws += (size_t)NH2 * NH1 * 2;

    prep_w1t<<<(NH1 * LDK + 255) / 256, 256, 0, stream>>>(w1, w1t);
    prep_w2t<<<(NH2 * NH1 + 255) / 256, 256, 0, stream>>>(w2, w2t);

    cvt_cl_kernel<<<24 * 96, 256, 0, stream>>>(fp0, lev0);
    pool_cl<<<(int)((SZ_L1 / 8 + 255) / 256), 256, 0, stream>>>(lev0, lev1, 96, (int)(SZ_L1 / 8));
    pool_cl<<<(int)((SZ_L2 / 8 + 255) / 256), 256, 0, stream>>>(lev1, lev2, 48, (int)(SZ_L2 / 8));
    pool_cl<<<(int)((SZ_L3 / 8 + 255) / 256), 256, 0, stream>>>(lev2, lev3, 24, (int)(SZ_L3 / 8));

    const __hip_bfloat16* levs[4] = {lev0, lev1, lev2, lev3};
    const int vs[4] = {96, 48, 24, 12};
    for (int i = 0; i < 4; ++i) {
        float inv = 1.f / (float)(1 << i);
        tf_kernel<<<3 * NTRK, 256, 0, stream>>>(levs[i], coords_init, tfb, vs[i], inv);
        corr_mfma<<<3 * 2048, 256, 0, stream>>>(levs[i], coords, tfb, c4b, vs[i], inv);
        gemm1_mfma<<<dim3(48, 6), 256, 0, stream>>>(c4b, w1t, b1, h_ws);
        gemm2_mfma<<<dim3(32, 4), 256, 0, stream>>>(h_ws, w2t, b2, out, i);
    }
}

// Round 9
// 323.695 us; speedup vs baseline: 8.1919x; 1.3586x over previous
//
#include <hip/hip_runtime.h>
#include <hip/hip_bf16.h>
#include <math.h>

#define NTRK 256
#define DLAT 128
#define CDIM 7
#define CD2  49
#define CD4  2401
#define NH1  384
#define NH2  256
#define LDK  2432    // CD4 padded to multiple of 32
#define PITCHB 272   // corr LDS row pitch in bytes (136 bf16 / 68 dwords) -> 4-bank skew per row

// channel-last level sizes (elements)
#define SZ_L0 ((size_t)3 * 8 * 96 * 96 * 128)
#define SZ_L1 ((size_t)3 * 8 * 48 * 48 * 128)
#define SZ_L2 ((size_t)3 * 8 * 24 * 24 * 128)
#define SZ_L3 ((size_t)3 * 8 * 12 * 12 * 128)
#define SZ_TF ((size_t)3 * NTRK * DLAT * CD2)

typedef __attribute__((ext_vector_type(8))) short short8;
typedef __attribute__((ext_vector_type(4))) float f32x4;
typedef __attribute__((ext_vector_type(4))) unsigned int u32x4;

// ---------------- helpers ----------------

__device__ __forceinline__ float b2f(unsigned short u) {
    union { unsigned int i; float f; } c;
    c.i = ((unsigned int)u) << 16;
    return c.f;
}
__device__ __forceinline__ unsigned int f2b(float x) {
    __hip_bfloat16 h = __float2bfloat16(x);
    return (unsigned int)(*(unsigned short*)&h);
}

__device__ __forceinline__ float gelu_tanh(float x) {
    float x3 = x * x * x;
    float u = 0.7978845608028654f * (x + 0.044715f * x3);
    return 0.5f * x * (1.f + tanhf(u));
}

__device__ __forceinline__ int plane_a(int k) { return (k == 2) ? 1 : 0; }
__device__ __forceinline__ int plane_b(int k) { return (k == 0) ? 1 : 2; }

// per-level tables (computed at compile time)
__device__ __forceinline__ int lev_v(int lev) { return 96 >> lev; }
__device__ __forceinline__ size_t lev_off(int lev) {
    return (lev > 0 ? SZ_L0 : 0) + (lev > 1 ? SZ_L1 : 0) + (lev > 2 ? SZ_L2 : 0);
}

// async global->LDS, 16B per lane; LDS dst must be wave-uniform base
__device__ __forceinline__ void gload16(const void* g, void* l) {
    __builtin_amdgcn_global_load_lds(
        (const __attribute__((address_space(1))) unsigned int*)g,
        (__attribute__((address_space(3))) unsigned int*)l,
        16, 0, 0);
}

// ---------------- fp32 channel-first -> bf16 channel-last transpose ----------------
// in:  fp0[((s*384 + dd*3 + k)*96 + y)*96 + x]  fp32
// out: lev0[(((k*8+s)*96 + y)*96 + x)*128 + dd] bf16
// one block per (k,s,y); LDS u32 tile [64][97] = packed bf16 pairs (24.8 KB).

__global__ __launch_bounds__(256) void cvt_cl_kernel(const float* __restrict__ in,
                                                     __hip_bfloat16* __restrict__ out) {
    __shared__ unsigned int lds[64][97];   // lds[d2][x] = bf16(2*d2) | bf16(2*d2+1)<<16
    const int b = blockIdx.x;      // (k*8+s)*96 + y
    const int y = b % 96;
    const int ks = b / 96;         // k*8+s
    const int k = ks >> 3, s = ks & 7;
    const int tid = threadIdx.x;
    for (int idx = tid; idx < 64 * 24; idx += 256) {
        int d2 = idx / 24, x4 = (idx - d2 * 24) * 4;
        const float* rlo = in + (((size_t)s * 384 + (2 * d2) * 3 + k) * 96 + y) * 96 + x4;
        const float* rhi = in + (((size_t)s * 384 + (2 * d2 + 1) * 3 + k) * 96 + y) * 96 + x4;
        float4 lo = *(const float4*)rlo;
        float4 hi = *(const float4*)rhi;
        lds[d2][x4 + 0] = f2b(lo.x) | (f2b(hi.x) << 16);
        lds[d2][x4 + 1] = f2b(lo.y) | (f2b(hi.y) << 16);
        lds[d2][x4 + 2] = f2b(lo.z) | (f2b(hi.z) << 16);
        lds[d2][x4 + 3] = f2b(lo.w) | (f2b(hi.w) << 16);
    }
    __syncthreads();
    unsigned int* orow = (unsigned int*)((unsigned short*)out + ((size_t)ks * 96 + y) * 96 * 128);
    for (int idx = tid; idx < 96 * 16; idx += 256) {
        int x = idx >> 4, q = idx & 15;   // q = group of 4 d2 (8 channels)
        u32x4 r;
        r[0] = lds[4 * q + 0][x];
        r[1] = lds[4 * q + 1][x];
        r[2] = lds[4 * q + 2][x];
        r[3] = lds[4 * q + 3][x];
        *(u32x4*)(orow + x * 64 + q * 4) = r;
    }
}

// ---------------- 2x2 avg pool, channel-last bf16 ----------------

__global__ __launch_bounds__(256) void pool_cl(const __hip_bfloat16* __restrict__ in,
                                               __hip_bfloat16* __restrict__ out,
                                               int vin, int total8) {
    int idx = blockIdx.x * 256 + threadIdx.x;
    if (idx >= total8) return;
    int vout = vin >> 1;
    int d8 = idx & 15;
    int t = idx >> 4;
    int x = t % vout; t /= vout;
    int y = t % vout; t /= vout;   // t = ks
    const unsigned short* base = (const unsigned short*)in
        + (((size_t)t * vin + 2 * y) * vin + 2 * x) * 128 + d8 * 8;
    short8 a = *(const short8*)(base);
    short8 bq = *(const short8*)(base + 128);
    short8 c = *(const short8*)(base + (size_t)vin * 128);
    short8 d = *(const short8*)(base + (size_t)vin * 128 + 128);
    short8 r;
    #pragma unroll
    for (int j = 0; j < 8; ++j) {
        float sum = b2f((unsigned short)a[j]) + b2f((unsigned short)bq[j])
                  + b2f((unsigned short)c[j]) + b2f((unsigned short)d[j]);
        r[j] = (short)f2b(0.25f * sum);
    }
    *(short8*)((unsigned short*)out + ((((size_t)t * vout + y) * vout + x)) * 128 + d8 * 8) = r;
}

// ---------------- track features, all levels: grid 4*768 ----------------
// bid = lev*768 + r; r: XCD-local decode g = (r&7)*96 + (r>>3); k=g>>8, n=g&255
// tfb layout: [lev][k][n][xy][dd]

__global__ __launch_bounds__(256) void tf_all(const __hip_bfloat16* __restrict__ levbase,
                                              const float* __restrict__ coords_init,
                                              __hip_bfloat16* __restrict__ tfb) {
    const int bid = blockIdx.x;
    const int lev = bid / 768;
    const int r0 = bid - lev * 768;
    const int g = (r0 & 7) * 96 + (r0 >> 3);
    const int k = g >> 8;
    const int n = g & 255;
    const int v = lev_v(lev);
    const float inv_scale = 1.f / (float)(1 << lev);
    const float vm1 = (float)(v - 1);
    float cx = coords_init[n * 3 + plane_a(k)] * inv_scale;
    float cy = coords_init[n * 3 + plane_b(k)] * inv_scale;
    const unsigned short* frame = (const unsigned short*)levbase + lev_off(lev)
        + (size_t)(k * 8) * v * v * 128;
    unsigned short* dst = (unsigned short*)tfb + (size_t)lev * SZ_TF
        + ((size_t)(k * NTRK + n)) * (DLAT * CD2);
    for (int idx = threadIdx.x; idx < CD2 * 16; idx += 256) {
        int xy = idx >> 4;
        int c8 = idx & 15;
        int i = xy / CDIM, j = xy % CDIM;
        float X = fminf(fmaxf(cx + (float)(i - 3), 0.f), vm1);
        float Y = fminf(fmaxf(cy + (float)(j - 3), 0.f), vm1);
        float xf = floorf(X), yf = floorf(Y);
        int x0 = (int)xf, y0 = (int)yf;
        int x1 = min(x0 + 1, v - 1), y1 = min(y0 + 1, v - 1);
        float wx = X - xf, wy = Y - yf;
        const unsigned short* r00 = frame + ((size_t)y0 * v + x0) * 128 + c8 * 8;
        const unsigned short* r01 = frame + ((size_t)y0 * v + x1) * 128 + c8 * 8;
        const unsigned short* r10 = frame + ((size_t)y1 * v + x0) * 128 + c8 * 8;
        const unsigned short* r11 = frame + ((size_t)y1 * v + x1) * 128 + c8 * 8;
        short8 a = *(const short8*)r00, bq = *(const short8*)r01;
        short8 c = *(const short8*)r10, d = *(const short8*)r11;
        float w00 = (1.f - wy) * (1.f - wx), w01 = (1.f - wy) * wx;
        float w10 = wy * (1.f - wx), w11 = wy * wx;
        short8 r;
        #pragma unroll
        for (int e = 0; e < 8; ++e) {
            float val = b2f((unsigned short)a[e]) * w00 + b2f((unsigned short)bq[e]) * w01
                      + b2f((unsigned short)c[e]) * w10 + b2f((unsigned short)d[e]) * w11;
            r[e] = (short)f2b(val);
        }
        *(short8*)(dst + xy * 128 + c8 * 8) = r;
    }
}

// ---------------- fused patch-MFMA correlation, all levels: grid 4*6144 ----------------
// bid = lev*6144 + r; r: s = r&7, n = (r>>3)&255, k = r>>11  (XCD locality per level)
// c4 = W_interp (P @ tf^T); P = 8x8 integer-aligned patch per channel.
// Output (h,w) samples X = cx+(h-3), Y = cy+(w-3); tap for (h,w) is pos = w*8 + h.

__global__ __launch_bounds__(256) void corr_all(const __hip_bfloat16* __restrict__ levbase,
                                                const float* __restrict__ coords,
                                                const __hip_bfloat16* __restrict__ tfb,
                                                __hip_bfloat16* __restrict__ c4b) {
    __shared__ __align__(16) char patch[64 * PITCHB];  // P: [pos][dd] bf16; later Cfull fp32 [pos][xy]
    __shared__ __align__(16) char tfs[64 * PITCHB];    // B: [xy][dd] bf16
    __shared__ float wxs[8], wys[8];
    const int B = blockIdx.x;
    const int lev = B / 6144;
    const int r0 = B - lev * 6144;
    const int s = r0 & 7;
    const int n = (r0 >> 3) & 255;
    const int k = r0 >> 11;
    const int sn = s * 256 + n;
    const int v = lev_v(lev);
    const float inv_scale = 1.f / (float)(1 << lev);
    const int tid = threadIdx.x;
    const float vm1 = (float)(v - 1);
    float cx = coords[sn * 3 + plane_a(k)] * inv_scale;
    float cy = coords[sn * 3 + plane_b(k)] * inv_scale;
    const int fx = (int)floorf(cx), fy = (int)floorf(cy);

    // block-uniform interpolation weights (0 at clamped taps)
    if (tid < 7) {
        float X = fminf(fmaxf(cx + (float)(tid - 3), 0.f), vm1);
        int g = min(max(fx + tid - 3, 0), v - 1);
        wxs[tid] = X - (float)g;
        float Y = fminf(fmaxf(cy + (float)(tid - 3), 0.f), vm1);
        int gy_ = min(max(fy + tid - 3, 0), v - 1);
        wys[tid] = Y - (float)gy_;
    }

    // stage tf: 49 rows x 256B = 784 x 16B chunks
    const short8* tfg = (const short8*)(tfb + (size_t)lev * SZ_TF
        + ((size_t)(k * NTRK + n)) * (DLAT * CD2));
    for (int idx = tid; idx < 784; idx += 256) {
        int row = idx >> 4, c16 = idx & 15;
        *(short8*)(tfs + row * PITCHB + c16 * 16) = tfg[idx];
    }

    // stage patch: 64 pos x 16 chunks, coalesced 256B channel-last rows
    {
        const unsigned short* frame = (const unsigned short*)levbase + lev_off(lev)
            + (size_t)(k * 8 + s) * v * v * 128;
        for (int idx = tid; idx < 1024; idx += 256) {
            int pos = idx >> 4, c8 = idx & 15;
            int px = pos & 7, py = pos >> 3;
            int gx = min(max(fx + px - 3, 0), v - 1);
            int gy = min(max(fy + py - 3, 0), v - 1);
            short8 val = *(const short8*)(frame + ((size_t)gy * v + gx) * 128 + c8 * 8);
            *(short8*)(patch + pos * PITCHB + c8 * 16) = val;
        }
    }
    __syncthreads();

    const int w4 = tid >> 6, l = tid & 63;
    const int l15 = l & 15, l4 = l >> 4;
    f32x4 acc[4];
    #pragma unroll
    for (int nt = 0; nt < 4; ++nt) acc[nt] = (f32x4){0.f, 0.f, 0.f, 0.f};
    #pragma unroll
    for (int ks = 0; ks < 4; ++ks) {
        short8 af = *(const short8*)(patch + (16 * w4 + l15) * PITCHB + ks * 64 + l4 * 16);
        #pragma unroll
        for (int nt = 0; nt < 4; ++nt) {
            short8 bf = *(const short8*)(tfs + (16 * nt + l15) * PITCHB + ks * 64 + l4 * 16);
            acc[nt] = __builtin_amdgcn_mfma_f32_16x16x32_bf16(af, bf, acc[nt], 0, 0, 0);
        }
    }
    __syncthreads();  // all patch reads done before overwrite

    // write Cfull fp32 [pos][xy] into the patch region (64 x 272B >= 64 x 256B)
    {
        const int row0 = 16 * w4 + l4 * 4;
        #pragma unroll
        for (int nt = 0; nt < 4; ++nt) {
            int col = nt * 16 + l15;
            #pragma unroll
            for (int j = 0; j < 4; ++j)
                *(float*)(patch + (row0 + j) * PITCHB + col * 4) = acc[nt][j];
        }
    }
    __syncthreads();

    // 4-tap interpolation on the 49x49 output.
    // Output (h,w): tap pos = w*8 + h; +PITCHB = x+1 (weight wx=wxs[h]);
    // +8*PITCHB = y+1 (weight wy=wys[w]).
    __hip_bfloat16* crow = c4b + (size_t)B * LDK;   // row = lev*6144 + k*2048 + sn (s,n,k within r0)
    {
        // note: row must be lev*6144 + k*2048 + sn, but B = lev*6144 + r0 where
        // r0 = k*2048 + (n<<3|s) ... r0's layout is s|n|k, so recompute:
    }
    crow = c4b + ((size_t)lev * 6144 + (size_t)k * 2048 + sn) * LDK;
    for (int o = tid; o < CD4; o += 256) {
        int hw = o / CD2;
        int xy = o - hw * CD2;
        int h = hw / CDIM, w_ = hw - h * CDIM;
        float wxv = wxs[h], wyv = wys[w_];
        const char* base = patch + (w_ * 8 + h) * PITCHB + xy * 4;
        float p00 = *(const float*)(base);
        float p01 = *(const float*)(base + PITCHB);        // x+1
        float p10 = *(const float*)(base + 8 * PITCHB);    // y+1
        float p11 = *(const float*)(base + 9 * PITCHB);
        float val = p00 * (1.f - wyv) * (1.f - wxv) + p01 * (1.f - wyv) * wxv
                  + p10 * wyv * (1.f - wxv) + p11 * wyv * wxv;
        crow[o] = __float2bfloat16(val);
    }
    if (tid < LDK - CD4) crow[CD4 + tid] = __float2bfloat16(0.f);
}

// ---------------- weight prep: transpose + bf16 ----------------

__global__ __launch_bounds__(256) void prep_w1t(const float* __restrict__ w1,
                                                __hip_bfloat16* __restrict__ w1t) {
    int idx = blockIdx.x * 256 + threadIdx.x;  // n*LDK + kk
    if (idx >= NH1 * LDK) return;
    int n = idx / LDK, kk = idx - n * LDK;
    float v = (kk < CD4) ? w1[(size_t)kk * NH1 + n] : 0.f;
    w1t[idx] = __float2bfloat16(v);
}

__global__ __launch_bounds__(256) void prep_w2t(const float* __restrict__ w2,
                                                __hip_bfloat16* __restrict__ w2t) {
    int idx = blockIdx.x * 256 + threadIdx.x;  // n*NH1 + j
    if (idx >= NH2 * NH1) return;
    int n = idx / NH1, j = idx - n * NH1;
    w2t[idx] = __float2bfloat16(w2[(size_t)j * NH2 + n]);
}

// ---------------- GEMM1 MFMA, all levels: (24576 x LDK) @ w1t^T -> gelu -> H bf16 ----------------
// BM=128 BN=64 BK=32, 4 waves (2x2); grid (192, 6) = 1152 blocks

__global__ __launch_bounds__(256) void gemm1_all(
    const __hip_bfloat16* __restrict__ A,    // [24576][LDK]
    const __hip_bfloat16* __restrict__ Bt,   // [NH1][LDK]
    const float* __restrict__ b1,
    __hip_bfloat16* __restrict__ H) {        // [24576][NH1]
    __shared__ __align__(16) char smem[12288];
    char* Asm = smem;          // 128 rows x 64B
    char* Bsm = smem + 8192;   // 64 rows x 64B
    const int m0 = blockIdx.x * 128, n0 = blockIdx.y * 64;
    const int tid = threadIdx.x;
    const int w = tid >> 6, l = tid & 63;
    const int wr = w >> 1, wc = w & 1;
    const int l15 = l & 15, l4 = l >> 4;
    f32x4 acc[4][2];
    #pragma unroll
    for (int m = 0; m < 4; ++m)
        #pragma unroll
        for (int n = 0; n < 2; ++n) acc[m][n] = (f32x4){0.f, 0.f, 0.f, 0.f};
    const char* Ag = (const char*)(A + (size_t)(m0 + (tid >> 2)) * LDK) + (tid & 3) * 16;
    const char* Bg = (const char*)(Bt + (size_t)(n0 + (tid >> 2)) * LDK) + (tid & 3) * 16;
    char* AsmW = Asm + w * 1024;
    char* BsmW = Bsm + w * 1024;
    for (int kb = 0; kb < LDK * 2; kb += 64) {  // byte offset along K
        gload16(Ag + kb, AsmW);                               // rows 0..63
        gload16(Ag + (size_t)64 * LDK * 2 + kb, AsmW + 4096); // rows 64..127
        gload16(Bg + kb, BsmW);
        __syncthreads();
        short8 af[4], bfr[2];
        #pragma unroll
        for (int m = 0; m < 4; ++m)
            af[m] = *(const short8*)(Asm + (wr * 64 + m * 16 + l15) * 64 + l4 * 16);
        #pragma unroll
        for (int n = 0; n < 2; ++n)
            bfr[n] = *(const short8*)(Bsm + (wc * 32 + n * 16 + l15) * 64 + l4 * 16);
        #pragma unroll
        for (int m = 0; m < 4; ++m)
            #pragma unroll
            for (int n = 0; n < 2; ++n)
                acc[m][n] = __builtin_amdgcn_mfma_f32_16x16x32_bf16(af[m], bfr[n], acc[m][n], 0, 0, 0);
        __syncthreads();
    }
    #pragma unroll
    for (int m = 0; m < 4; ++m) {
        int row = m0 + wr * 64 + m * 16 + l4 * 4;
        #pragma unroll
        for (int n = 0; n < 2; ++n) {
            int col = n0 + wc * 32 + n * 16 + l15;
            float bias = b1[col];
            #pragma unroll
            for (int j = 0; j < 4; ++j)
                H[(size_t)(row + j) * NH1 + col] = __float2bfloat16(gelu_tanh(acc[m][n][j] + bias));
        }
    }
}

// ---------------- GEMM2 MFMA, all levels: per level (2048 x 1152) -> out slice ----------------
// grid (4*32, 4); lev = blockIdx.x>>5, m-block = blockIdx.x&31

__global__ __launch_bounds__(256) void gemm2_all(
    const __hip_bfloat16* __restrict__ Hin,  // [4][3][2048][NH1]
    const __hip_bfloat16* __restrict__ Bt,   // [NH2][NH1]
    const float* __restrict__ b2,
    float* __restrict__ out) {
    __shared__ __align__(16) char smem[8192];
    char* Asm = smem;         // 64 rows x 64B
    char* Bsm = smem + 4096;
    const int lev = blockIdx.x >> 5;
    const int m0 = (blockIdx.x & 31) * 64, n0 = blockIdx.y * 64;
    const int tid = threadIdx.x;
    const int w = tid >> 6, l = tid & 63;
    const int wr = w >> 1, wc = w & 1;
    const int l15 = l & 15, l4 = l >> 4;
    f32x4 acc[2][2];
    #pragma unroll
    for (int m = 0; m < 2; ++m)
        #pragma unroll
        for (int n = 0; n < 2; ++n) acc[m][n] = (f32x4){0.f, 0.f, 0.f, 0.f};
    const char* Bg = (const char*)(Bt + (size_t)(n0 + (tid >> 2)) * NH1) + (tid & 3) * 16;
    char* AsmW = Asm + w * 1024;
    char* BsmW = Bsm + w * 1024;
    for (int p = 0; p < 3; ++p) {
        const char* Ag = (const char*)(Hin
            + (size_t)((lev * 3 + p) * 2048 + m0 + (tid >> 2)) * NH1) + (tid & 3) * 16;
        for (int jb = 0; jb < NH1 * 2; jb += 64) {
            gload16(Ag + jb, AsmW);
            gload16(Bg + jb, BsmW);
            __syncthreads();
            short8 af[2], bfr[2];
            #pragma unroll
            for (int m = 0; m < 2; ++m)
                af[m] = *(const short8*)(Asm + (wr * 32 + m * 16 + l15) * 64 + l4 * 16);
            #pragma unroll
            for (int n = 0; n < 2; ++n)
                bfr[n] = *(const short8*)(Bsm + (wc * 32 + n * 16 + l15) * 64 + l4 * 16);
            #pragma unroll
            for (int m = 0; m < 2; ++m)
                #pragma unroll
                for (int n = 0; n < 2; ++n)
                    acc[m][n] = __builtin_amdgcn_mfma_f32_16x16x32_bf16(af[m], bfr[n], acc[m][n], 0, 0, 0);
            __syncthreads();
        }
    }
    #pragma unroll
    for (int m = 0; m < 2; ++m) {
        int row = m0 + wr * 32 + m * 16 + l4 * 4;
        #pragma unroll
        for (int n = 0; n < 2; ++n) {
            int col = n0 + wc * 32 + n * 16 + l15;
            float bias3 = 3.f * b2[col];
            #pragma unroll
            for (int j = 0; j < 4; ++j)
                out[(size_t)(row + j) * 1024 + lev * NH2 + col] = acc[m][n][j] + bias3;
        }
    }
}

// ---------------- launch ----------------

extern "C" void kernel_launch(void* const* d_in, const int* in_sizes, int n_in,
                              void* d_out, int out_size, void* d_ws, size_t ws_size,
                              hipStream_t stream) {
    const float* coords      = (const float*)d_in[0];
    const float* coords_init = (const float*)d_in[1];
    const float* fp0         = (const float*)d_in[2];
    const float* w1          = (const float*)d_in[3];
    const float* b1          = (const float*)d_in[4];
    const float* w2          = (const float*)d_in[5];
    const float* b2          = (const float*)d_in[6];
    float* out = (float*)d_out;
    char* ws = (char*)d_ws;

    __hip_bfloat16* lev0 = (__hip_bfloat16*)ws;      ws += SZ_L0 * 2;
    __hip_bfloat16* lev1 = (__hip_bfloat16*)ws;      ws += SZ_L1 * 2;
    __hip_bfloat16* lev2 = (__hip_bfloat16*)ws;      ws += SZ_L2 * 2;
    __hip_bfloat16* lev3 = (__hip_bfloat16*)ws;      ws += SZ_L3 * 2;
    __hip_bfloat16* tfb  = (__hip_bfloat16*)ws;      ws += (size_t)4 * SZ_TF * 2;
    __hip_bfloat16* c4b  = (__hip_bfloat16*)ws;      ws += (size_t)24576 * LDK * 2;
    __hip_bfloat16* h_ws = (__hip_bfloat16*)ws;      ws += (size_t)24576 * NH1 * 2;
    __hip_bfloat16* w1t  = (__hip_bfloat16*)ws;      ws += (size_t)NH1 * LDK * 2;
    __hip_bfloat16* w2t  = (__hip_bfloat16*)ws;      ws += (size_t)NH2 * NH1 * 2;

    prep_w1t<<<(NH1 * LDK + 255) / 256, 256, 0, stream>>>(w1, w1t);
    prep_w2t<<<(NH2 * NH1 + 255) / 256, 256, 0, stream>>>(w2, w2t);

    cvt_cl_kernel<<<24 * 96, 256, 0, stream>>>(fp0, lev0);
    pool_cl<<<(int)((SZ_L1 / 8 + 255) / 256), 256, 0, stream>>>(lev0, lev1, 96, (int)(SZ_L1 / 8));
    pool_cl<<<(int)((SZ_L2 / 8 + 255) / 256), 256, 0, stream>>>(lev1, lev2, 48, (int)(SZ_L2 / 8));
    pool_cl<<<(int)((SZ_L3 / 8 + 255) / 256), 256, 0, stream>>>(lev2, lev3, 24, (int)(SZ_L3 / 8));

    tf_all<<<4 * 768, 256, 0, stream>>>(lev0, coords_init, tfb);
    corr_all<<<4 * 6144, 256, 0, stream>>>(lev0, coords, tfb, c4b);
    gemm1_all<<<dim3(192, 6), 256, 0, stream>>>(c4b, w1t, b1, h_ws);
    gemm2_all<<<dim3(128, 4), 256, 0, stream>>>(h_ws, w2t, b2, out);
}

// Round 10
// 263.710 us; speedup vs baseline: 10.0553x; 1.2275x over previous
//
#include <hip/hip_runtime.h>
#include <hip/hip_bf16.h>
#include <math.h>

#define NTRK 256
#define DLAT 128
#define CDIM 7
#define CD2  49
#define CD4  2401
#define NH1  384
#define NH2  256
#define LDK  2432    // CD4 padded to multiple of 32
#define PITCHB 272   // corr LDS row pitch in bytes (136 bf16 / 68 dwords) -> 4-bank skew per row

// channel-last level sizes (elements)
#define SZ_L0 ((size_t)3 * 8 * 96 * 96 * 128)
#define SZ_L1 ((size_t)3 * 8 * 48 * 48 * 128)
#define SZ_L2 ((size_t)3 * 8 * 24 * 24 * 128)
#define SZ_L3 ((size_t)3 * 8 * 12 * 12 * 128)
#define SZ_TF ((size_t)3 * NTRK * DLAT * CD2)

typedef __attribute__((ext_vector_type(8))) short short8;
typedef __attribute__((ext_vector_type(4))) float f32x4;
typedef __attribute__((ext_vector_type(4))) unsigned int u32x4;

// ---------------- helpers ----------------

__device__ __forceinline__ float b2f(unsigned short u) {
    union { unsigned int i; float f; } c;
    c.i = ((unsigned int)u) << 16;
    return c.f;
}
__device__ __forceinline__ unsigned int f2b(float x) {
    __hip_bfloat16 h = __float2bfloat16(x);
    return (unsigned int)(*(unsigned short*)&h);
}

// 0.5x(1+tanh(u)) == x*sigmoid(2u), u = 0.7978845608(x + 0.044715 x^3)
__device__ __forceinline__ float gelu_tanh(float x) {
    float x2 = x * x;
    float p = x * fmaf(0.044715f, x2, 1.0f);
    float e = __expf(-1.5957691216f * p);   // e^{-2u}
    return __fdividef(x, 1.0f + e);
}

__device__ __forceinline__ int plane_a(int k) { return (k == 2) ? 1 : 0; }
__device__ __forceinline__ int plane_b(int k) { return (k == 0) ? 1 : 2; }

__device__ __forceinline__ int lev_v(int lev) { return 96 >> lev; }
__device__ __forceinline__ size_t lev_off(int lev) {
    return (lev > 0 ? SZ_L0 : 0) + (lev > 1 ? SZ_L1 : 0) + (lev > 2 ? SZ_L2 : 0);
}

// async global->LDS, 16B per lane; LDS dst must be wave-uniform base
__device__ __forceinline__ void gload16(const void* g, void* l) {
    __builtin_amdgcn_global_load_lds(
        (const __attribute__((address_space(1))) unsigned int*)g,
        (__attribute__((address_space(3))) unsigned int*)l,
        16, 0, 0);
}

// ---------------- fp32 channel-first -> bf16 channel-last transpose ----------------

__global__ __launch_bounds__(256) void cvt_cl_kernel(const float* __restrict__ in,
                                                     __hip_bfloat16* __restrict__ out) {
    __shared__ unsigned int lds[64][97];   // lds[d2][x] = bf16(2*d2) | bf16(2*d2+1)<<16
    const int b = blockIdx.x;      // (k*8+s)*96 + y
    const int y = b % 96;
    const int ks = b / 96;         // k*8+s
    const int k = ks >> 3, s = ks & 7;
    const int tid = threadIdx.x;
    for (int idx = tid; idx < 64 * 24; idx += 256) {
        int d2 = idx / 24, x4 = (idx - d2 * 24) * 4;
        const float* rlo = in + (((size_t)s * 384 + (2 * d2) * 3 + k) * 96 + y) * 96 + x4;
        const float* rhi = in + (((size_t)s * 384 + (2 * d2 + 1) * 3 + k) * 96 + y) * 96 + x4;
        float4 lo = *(const float4*)rlo;
        float4 hi = *(const float4*)rhi;
        lds[d2][x4 + 0] = f2b(lo.x) | (f2b(hi.x) << 16);
        lds[d2][x4 + 1] = f2b(lo.y) | (f2b(hi.y) << 16);
        lds[d2][x4 + 2] = f2b(lo.z) | (f2b(hi.z) << 16);
        lds[d2][x4 + 3] = f2b(lo.w) | (f2b(hi.w) << 16);
    }
    __syncthreads();
    unsigned int* orow = (unsigned int*)((unsigned short*)out + ((size_t)ks * 96 + y) * 96 * 128);
    for (int idx = tid; idx < 96 * 16; idx += 256) {
        int x = idx >> 4, q = idx & 15;
        u32x4 r;
        r[0] = lds[4 * q + 0][x];
        r[1] = lds[4 * q + 1][x];
        r[2] = lds[4 * q + 2][x];
        r[3] = lds[4 * q + 3][x];
        *(u32x4*)(orow + x * 64 + q * 4) = r;
    }
}

// ---------------- 2x2 avg pool, channel-last bf16 ----------------

__global__ __launch_bounds__(256) void pool_cl(const __hip_bfloat16* __restrict__ in,
                                               __hip_bfloat16* __restrict__ out,
                                               int vin, int total8) {
    int idx = blockIdx.x * 256 + threadIdx.x;
    if (idx >= total8) return;
    int vout = vin >> 1;
    int d8 = idx & 15;
    int t = idx >> 4;
    int x = t % vout; t /= vout;
    int y = t % vout; t /= vout;   // t = ks
    const unsigned short* base = (const unsigned short*)in
        + (((size_t)t * vin + 2 * y) * vin + 2 * x) * 128 + d8 * 8;
    short8 a = *(const short8*)(base);
    short8 bq = *(const short8*)(base + 128);
    short8 c = *(const short8*)(base + (size_t)vin * 128);
    short8 d = *(const short8*)(base + (size_t)vin * 128 + 128);
    short8 r;
    #pragma unroll
    for (int j = 0; j < 8; ++j) {
        float sum = b2f((unsigned short)a[j]) + b2f((unsigned short)bq[j])
                  + b2f((unsigned short)c[j]) + b2f((unsigned short)d[j]);
        r[j] = (short)f2b(0.25f * sum);
    }
    *(short8*)((unsigned short*)out + ((((size_t)t * vout + y) * vout + x)) * 128 + d8 * 8) = r;
}

// ---------------- track features, all levels: grid 4*768 ----------------

__global__ __launch_bounds__(256) void tf_all(const __hip_bfloat16* __restrict__ levbase,
                                              const float* __restrict__ coords_init,
                                              __hip_bfloat16* __restrict__ tfb) {
    const int bid = blockIdx.x;
    const int lev = bid / 768;
    const int r0 = bid - lev * 768;
    const int g = (r0 & 7) * 96 + (r0 >> 3);
    const int k = g >> 8;
    const int n = g & 255;
    const int v = lev_v(lev);
    const float inv_scale = 1.f / (float)(1 << lev);
    const float vm1 = (float)(v - 1);
    float cx = coords_init[n * 3 + plane_a(k)] * inv_scale;
    float cy = coords_init[n * 3 + plane_b(k)] * inv_scale;
    const unsigned short* frame = (const unsigned short*)levbase + lev_off(lev)
        + (size_t)(k * 8) * v * v * 128;
    unsigned short* dst = (unsigned short*)tfb + (size_t)lev * SZ_TF
        + ((size_t)(k * NTRK + n)) * (DLAT * CD2);
    for (int idx = threadIdx.x; idx < CD2 * 16; idx += 256) {
        int xy = idx >> 4;
        int c8 = idx & 15;
        int i = xy / CDIM, j = xy % CDIM;
        float X = fminf(fmaxf(cx + (float)(i - 3), 0.f), vm1);
        float Y = fminf(fmaxf(cy + (float)(j - 3), 0.f), vm1);
        float xf = floorf(X), yf = floorf(Y);
        int x0 = (int)xf, y0 = (int)yf;
        int x1 = min(x0 + 1, v - 1), y1 = min(y0 + 1, v - 1);
        float wx = X - xf, wy = Y - yf;
        const unsigned short* r00 = frame + ((size_t)y0 * v + x0) * 128 + c8 * 8;
        const unsigned short* r01 = frame + ((size_t)y0 * v + x1) * 128 + c8 * 8;
        const unsigned short* r10 = frame + ((size_t)y1 * v + x0) * 128 + c8 * 8;
        const unsigned short* r11 = frame + ((size_t)y1 * v + x1) * 128 + c8 * 8;
        short8 a = *(const short8*)r00, bq = *(const short8*)r01;
        short8 c = *(const short8*)r10, d = *(const short8*)r11;
        float w00 = (1.f - wy) * (1.f - wx), w01 = (1.f - wy) * wx;
        float w10 = wy * (1.f - wx), w11 = wy * wx;
        short8 r;
        #pragma unroll
        for (int e = 0; e < 8; ++e) {
            float val = b2f((unsigned short)a[e]) * w00 + b2f((unsigned short)bq[e]) * w01
                      + b2f((unsigned short)c[e]) * w10 + b2f((unsigned short)d[e]) * w11;
            r[e] = (short)f2b(val);
        }
        *(short8*)(dst + xy * 128 + c8 * 8) = r;
    }
}

// ---------------- fused patch-MFMA correlation, s-batched: grid 3072 ----------------
// bid = lk*256 + n, lk = lev*3 + k. Stage tf once; loop s=0..7:
//   {weights, stage patch, MFMA 64x64x128, Cfull->LDS, division-free interp}.
// Patch axis convention (verified r6): output (h,w) samples X=cx+(h-3), Y=cy+(w-3);
// patch pos = py*8+px (px<->x); tap for (h,w) is pos = w*8+h; wx=wxs[h], wy=wys[w].

__global__ __launch_bounds__(256) void corr_all(const __hip_bfloat16* __restrict__ levbase,
                                                const float* __restrict__ coords,
                                                const __hip_bfloat16* __restrict__ tfb,
                                                __hip_bfloat16* __restrict__ c4b) {
    __shared__ __align__(16) char patch[64 * PITCHB];  // P bf16 [pos][dd]; later Cfull fp32 [pos][xy]
    __shared__ __align__(16) char tfs[64 * PITCHB];    // tf bf16 [xy][dd]
    __shared__ float wxs[8], wys[8];
    const int bid = blockIdx.x;
    const int lk = bid >> 8;          // lev*3 + k
    const int n = bid & 255;
    const int lev = lk / 3;
    const int k = lk - lev * 3;
    const int v = lev_v(lev);
    const int vv = v * v;
    const float inv_scale = 1.f / (float)(1 << lev);
    const int tid = threadIdx.x;
    const float vm1 = (float)(v - 1);

    // stage tf once (s-invariant)
    const short8* tfg = (const short8*)(tfb + (size_t)lev * SZ_TF
        + ((size_t)(k * NTRK + n)) * (DLAT * CD2));
    for (int idx = tid; idx < 784; idx += 256) {
        int row = idx >> 4, c16 = idx & 15;
        *(short8*)(tfs + row * PITCHB + c16 * 16) = tfg[idx];
    }

    // per-thread interp decode, computed once: hw = hwb + 5*it, xy fixed
    const int hwb = tid / 49;           // 0..5 (valid <245)
    const int xy  = tid - hwb * 49;
    const bool act = tid < 245;

    const unsigned short* fbase = (const unsigned short*)levbase + lev_off(lev)
        + (size_t)(k * 8) * vv * 128;
    const int w4 = tid >> 6, l = tid & 63;
    const int l15 = l & 15, l4 = l >> 4;

    for (int s = 0; s < 8; ++s) {
        const int sn = s * 256 + n;
        float cx = coords[sn * 3 + plane_a(k)] * inv_scale;
        float cy = coords[sn * 3 + plane_b(k)] * inv_scale;
        const int fx = (int)floorf(cx), fy = (int)floorf(cy);

        if (tid < 7) {
            float X = fminf(fmaxf(cx + (float)(tid - 3), 0.f), vm1);
            int g = min(max(fx + tid - 3, 0), v - 1);
            wxs[tid] = X - (float)g;
            float Y = fminf(fmaxf(cy + (float)(tid - 3), 0.f), vm1);
            int gy_ = min(max(fy + tid - 3, 0), v - 1);
            wys[tid] = Y - (float)gy_;
        }
        // stage patch: 64 pos x 16 chunks, coalesced channel-last rows
        {
            const unsigned short* frame = fbase + (size_t)s * vv * 128;
            for (int idx = tid; idx < 1024; idx += 256) {
                int pos = idx >> 4, c8 = idx & 15;
                int px = pos & 7, py = pos >> 3;
                int gx = min(max(fx + px - 3, 0), v - 1);
                int gy = min(max(fy + py - 3, 0), v - 1);
                *(short8*)(patch + pos * PITCHB + c8 * 16) =
                    *(const short8*)(frame + ((size_t)gy * v + gx) * 128 + c8 * 8);
            }
        }
        __syncthreads();

        f32x4 acc[4];
        #pragma unroll
        for (int nt = 0; nt < 4; ++nt) acc[nt] = (f32x4){0.f, 0.f, 0.f, 0.f};
        #pragma unroll
        for (int ks = 0; ks < 4; ++ks) {
            short8 af = *(const short8*)(patch + (16 * w4 + l15) * PITCHB + ks * 64 + l4 * 16);
            #pragma unroll
            for (int nt = 0; nt < 4; ++nt) {
                short8 bf = *(const short8*)(tfs + (16 * nt + l15) * PITCHB + ks * 64 + l4 * 16);
                acc[nt] = __builtin_amdgcn_mfma_f32_16x16x32_bf16(af, bf, acc[nt], 0, 0, 0);
            }
        }
        __syncthreads();  // all patch reads done before overwrite

        // write Cfull fp32 [pos][xy] into the patch region
        {
            const int row0 = 16 * w4 + l4 * 4;
            #pragma unroll
            for (int nt = 0; nt < 4; ++nt) {
                int col = nt * 16 + l15;
                #pragma unroll
                for (int j = 0; j < 4; ++j)
                    *(float*)(patch + (row0 + j) * PITCHB + col * 4) = acc[nt][j];
            }
        }
        __syncthreads();

        // division-free 4-tap interpolation; output (h,w): tap pos = w*8+h
        unsigned short* crow = (unsigned short*)c4b + ((size_t)lk * 2048 + sn) * LDK;
        if (act) {
            int h = 0, w = hwb;
            unsigned short* op = crow + tid;   // hwb*49 + xy == tid
            const char* colbase = patch + xy * 4;
            #pragma unroll
            for (int it = 0; it < 10; ++it) {
                if (h < 7) {
                    float wxv = wxs[h], wyv = wys[w];
                    const char* tap = colbase + (w * 8 + h) * PITCHB;
                    float p00 = *(const float*)(tap);
                    float p01 = *(const float*)(tap + PITCHB);        // x+1
                    float p10 = *(const float*)(tap + 8 * PITCHB);    // y+1
                    float p11 = *(const float*)(tap + 9 * PITCHB);
                    float a  = fmaf(wxv, p01 - p00, p00);
                    float bq = fmaf(wxv, p11 - p10, p10);
                    *op = (unsigned short)f2b(fmaf(wyv, bq - a, a));
                }
                w += 5; if (w >= 7) { w -= 7; h += 1; }
                op += 245;
            }
        }
        if (tid < LDK - CD4) crow[CD4 + tid] = 0;   // bf16 zero pad
        __syncthreads();  // interp reads done before next-s staging
    }
}

// ---------------- weight prep: transpose + bf16 ----------------

__global__ __launch_bounds__(256) void prep_w1t(const float* __restrict__ w1,
                                                __hip_bfloat16* __restrict__ w1t) {
    int idx = blockIdx.x * 256 + threadIdx.x;  // n*LDK + kk
    if (idx >= NH1 * LDK) return;
    int n = idx / LDK, kk = idx - n * LDK;
    float v = (kk < CD4) ? w1[(size_t)kk * NH1 + n] : 0.f;
    w1t[idx] = __float2bfloat16(v);
}

__global__ __launch_bounds__(256) void prep_w2t(const float* __restrict__ w2,
                                                __hip_bfloat16* __restrict__ w2t) {
    int idx = blockIdx.x * 256 + threadIdx.x;  // n*NH1 + j
    if (idx >= NH2 * NH1) return;
    int n = idx / NH1, j = idx - n * NH1;
    w2t[idx] = __float2bfloat16(w2[(size_t)j * NH2 + n]);
}

// ---------------- GEMM1 MFMA, all levels: (24576 x LDK) @ w1t^T -> gelu -> H bf16 ----------------
// BM=128 BN=128 BK=32, 4 waves (2x2), wave tile 64x64 = 4x4 frags; grid (192, 3)

__global__ __launch_bounds__(256) void gemm1_all(
    const __hip_bfloat16* __restrict__ A,    // [24576][LDK]
    const __hip_bfloat16* __restrict__ Bt,   // [NH1][LDK]
    const float* __restrict__ b1,
    __hip_bfloat16* __restrict__ H) {        // [24576][NH1]
    __shared__ __align__(16) char smem[16384];
    char* Asm = smem;          // 128 rows x 64B
    char* Bsm = smem + 8192;   // 128 rows x 64B
    const int m0 = blockIdx.x * 128, n0 = blockIdx.y * 128;
    const int tid = threadIdx.x;
    const int w = tid >> 6, l = tid & 63;
    const int wr = w >> 1, wc = w & 1;
    const int l15 = l & 15, l4 = l >> 4;
    f32x4 acc[4][4];
    #pragma unroll
    for (int m = 0; m < 4; ++m)
        #pragma unroll
        for (int n = 0; n < 4; ++n) acc[m][n] = (f32x4){0.f, 0.f, 0.f, 0.f};
    const char* Ag = (const char*)(A + (size_t)(m0 + (tid >> 2)) * LDK) + (tid & 3) * 16;
    const char* Bg = (const char*)(Bt + (size_t)(n0 + (tid >> 2)) * LDK) + (tid & 3) * 16;
    char* AsmW = Asm + w * 1024;
    char* BsmW = Bsm + w * 1024;
    for (int kb = 0; kb < LDK * 2; kb += 64) {  // byte offset along K
        gload16(Ag + kb, AsmW);
        gload16(Ag + (size_t)64 * LDK * 2 + kb, AsmW + 4096);
        gload16(Bg + kb, BsmW);
        gload16(Bg + (size_t)64 * LDK * 2 + kb, BsmW + 4096);
        __syncthreads();
        short8 af[4], bfr[4];
        #pragma unroll
        for (int m = 0; m < 4; ++m)
            af[m] = *(const short8*)(Asm + (wr * 64 + m * 16 + l15) * 64 + l4 * 16);
        #pragma unroll
        for (int n = 0; n < 4; ++n)
            bfr[n] = *(const short8*)(Bsm + (wc * 64 + n * 16 + l15) * 64 + l4 * 16);
        #pragma unroll
        for (int m = 0; m < 4; ++m)
            #pragma unroll
            for (int n = 0; n < 4; ++n)
                acc[m][n] = __builtin_amdgcn_mfma_f32_16x16x32_bf16(af[m], bfr[n], acc[m][n], 0, 0, 0);
        __syncthreads();
    }
    #pragma unroll
    for (int m = 0; m < 4; ++m) {
        int row = m0 + wr * 64 + m * 16 + l4 * 4;
        #pragma unroll
        for (int n = 0; n < 4; ++n) {
            int col = n0 + wc * 64 + n * 16 + l15;
            float bias = b1[col];
            #pragma unroll
            for (int j = 0; j < 4; ++j)
                H[(size_t)(row + j) * NH1 + col] = __float2bfloat16(gelu_tanh(acc[m][n][j] + bias));
        }
    }
}

// ---------------- GEMM2 MFMA, all levels: per level (2048 x 1152) -> out slice ----------------

__global__ __launch_bounds__(256) void gemm2_all(
    const __hip_bfloat16* __restrict__ Hin,  // [4][3][2048][NH1]
    const __hip_bfloat16* __restrict__ Bt,   // [NH2][NH1]
    const float* __restrict__ b2,
    float* __restrict__ out) {
    __shared__ __align__(16) char smem[8192];
    char* Asm = smem;         // 64 rows x 64B
    char* Bsm = smem + 4096;
    const int lev = blockIdx.x >> 5;
    const int m0 = (blockIdx.x & 31) * 64, n0 = blockIdx.y * 64;
    const int tid = threadIdx.x;
    const int w = tid >> 6, l = tid & 63;
    const int wr = w >> 1, wc = w & 1;
    const int l15 = l & 15, l4 = l >> 4;
    f32x4 acc[2][2];
    #pragma unroll
    for (int m = 0; m < 2; ++m)
        #pragma unroll
        for (int n = 0; n < 2; ++n) acc[m][n] = (f32x4){0.f, 0.f, 0.f, 0.f};
    const char* Bg = (const char*)(Bt + (size_t)(n0 + (tid >> 2)) * NH1) + (tid & 3) * 16;
    char* AsmW = Asm + w * 1024;
    char* BsmW = Bsm + w * 1024;
    for (int p = 0; p < 3; ++p) {
        const char* Ag = (const char*)(Hin
            + (size_t)((lev * 3 + p) * 2048 + m0 + (tid >> 2)) * NH1) + (tid & 3) * 16;
        for (int jb = 0; jb < NH1 * 2; jb += 64) {
            gload16(Ag + jb, AsmW);
            gload16(Bg + jb, BsmW);
            __syncthreads();
            short8 af[2], bfr[2];
            #pragma unroll
            for (int m = 0; m < 2; ++m)
                af[m] = *(const short8*)(Asm + (wr * 32 + m * 16 + l15) * 64 + l4 * 16);
            #pragma unroll
            for (int n = 0; n < 2; ++n)
                bfr[n] = *(const short8*)(Bsm + (wc * 32 + n * 16 + l15) * 64 + l4 * 16);
            #pragma unroll
            for (int m = 0; m < 2; ++m)
                #pragma unroll
                for (int n = 0; n < 2; ++n)
                    acc[m][n] = __builtin_amdgcn_mfma_f32_16x16x32_bf16(af[m], bfr[n], acc[m][n], 0, 0, 0);
            __syncthreads();
        }
    }
    #pragma unroll
    for (int m = 0; m < 2; ++m) {
        int row = m0 + wr * 32 + m * 16 + l4 * 4;
        #pragma unroll
        for (int n = 0; n < 2; ++n) {
            int col = n0 + wc * 32 + n * 16 + l15;
            float bias3 = 3.f * b2[col];
            #pragma unroll
            for (int j = 0; j < 4; ++j)
                out[(size_t)(row + j) * 1024 + lev * NH2 + col] = acc[m][n][j] + bias3;
        }
    }
}

// ---------------- launch ----------------

extern "C" void kernel_launch(void* const* d_in, const int* in_sizes, int n_in,
                              void* d_out, int out_size, void* d_ws, size_t ws_size,
                              hipStream_t stream) {
    const float* coords      = (const float*)d_in[0];
    const float* coords_init = (const float*)d_in[1];
    const float* fp0         = (const float*)d_in[2];
    const float* w1          = (const float*)d_in[3];
    const float* b1          = (const float*)d_in[4];
    const float* w2          = (const float*)d_in[5];
    const float* b2          = (const float*)d_in[6];
    float* out = (float*)d_out;
    char* ws = (char*)d_ws;

    __hip_bfloat16* lev0 = (__hip_bfloat16*)ws;      ws += SZ_L0 * 2;
    __hip_bfloat16* lev1 = (__hip_bfloat16*)ws;      ws += SZ_L1 * 2;
    __hip_bfloat16* lev2 = (__hip_bfloat16*)ws;      ws += SZ_L2 * 2;
    __hip_bfloat16* lev3 = (__hip_bfloat16*)ws;      ws += SZ_L3 * 2;
    __hip_bfloat16* tfb  = (__hip_bfloat16*)ws;      ws += (size_t)4 * SZ_TF * 2;
    __hip_bfloat16* c4b  = (__hip_bfloat16*)ws;      ws += (size_t)24576 * LDK * 2;
    __hip_bfloat16* h_ws = (__hip_bfloat16*)ws;      ws += (size_t)24576 * NH1 * 2;
    __hip_bfloat16* w1t  = (__hip_bfloat16*)ws;      ws += (size_t)NH1 * LDK * 2;
    __hip_bfloat16* w2t  = (__hip_bfloat16*)ws;      ws += (size_t)NH2 * NH1 * 2;

    prep_w1t<<<(NH1 * LDK + 255) / 256, 256, 0, stream>>>(w1, w1t);
    prep_w2t<<<(NH2 * NH1 + 255) / 256, 256, 0, stream>>>(w2, w2t);

    cvt_cl_kernel<<<24 * 96, 256, 0, stream>>>(fp0, lev0);
    pool_cl<<<(int)((SZ_L1 / 8 + 255) / 256), 256, 0, stream>>>(lev0, lev1, 96, (int)(SZ_L1 / 8));
    pool_cl<<<(int)((SZ_L2 / 8 + 255) / 256), 256, 0, stream>>>(lev1, lev2, 48, (int)(SZ_L2 / 8));
    pool_cl<<<(int)((SZ_L3 / 8 + 255) / 256), 256, 0, stream>>>(lev2, lev3, 24, (int)(SZ_L3 / 8));

    tf_all<<<4 * 768, 256, 0, stream>>>(lev0, coords_init, tfb);
    corr_all<<<3072, 256, 0, stream>>>(lev0, coords, tfb, c4b);
    gemm1_all<<<dim3(192, 3), 256, 0, stream>>>(c4b, w1t, b1, h_ws);
    gemm2_all<<<dim3(128, 4), 256, 0, stream>>>(h_ws, w2t, b2, out);
}

// Round 11
// 260.000 us; speedup vs baseline: 10.1988x; 1.0143x over previous
//
#include <hip/hip_runtime.h>
#include <hip/hip_bf16.h>
#include <math.h>

#define NTRK 256
#define DLAT 128
#define CDIM 7
#define CD2  49
#define CD4  2401
#define NH1  384
#define NH2  256
#define LDK  2432    // CD4 padded to multiple of 32
#define PITCHB 272   // corr LDS row pitch in bytes (136 bf16 / 68 dwords) -> 4-bank skew per row

// channel-last level sizes (elements)
#define SZ_L0 ((size_t)3 * 8 * 96 * 96 * 128)
#define SZ_L1 ((size_t)3 * 8 * 48 * 48 * 128)
#define SZ_L2 ((size_t)3 * 8 * 24 * 24 * 128)
#define SZ_L3 ((size_t)3 * 8 * 12 * 12 * 128)
#define SZ_TF ((size_t)3 * NTRK * DLAT * CD2)

typedef __attribute__((ext_vector_type(8))) short short8;
typedef __attribute__((ext_vector_type(4))) float f32x4;
typedef __attribute__((ext_vector_type(4))) unsigned int u32x4;

// ---------------- helpers ----------------

__device__ __forceinline__ float b2f(unsigned short u) {
    union { unsigned int i; float f; } c;
    c.i = ((unsigned int)u) << 16;
    return c.f;
}
__device__ __forceinline__ unsigned int f2b(float x) {
    __hip_bfloat16 h = __float2bfloat16(x);
    return (unsigned int)(*(unsigned short*)&h);
}

// 0.5x(1+tanh(u)) == x*sigmoid(2u), u = 0.7978845608(x + 0.044715 x^3)
__device__ __forceinline__ float gelu_tanh(float x) {
    float x2 = x * x;
    float p = x * fmaf(0.044715f, x2, 1.0f);
    float e = __expf(-1.5957691216f * p);   // e^{-2u}
    return __fdividef(x, 1.0f + e);
}

__device__ __forceinline__ int plane_a(int k) { return (k == 2) ? 1 : 0; }
__device__ __forceinline__ int plane_b(int k) { return (k == 0) ? 1 : 2; }

__device__ __forceinline__ int lev_v(int lev) { return 96 >> lev; }
__device__ __forceinline__ size_t lev_off(int lev) {
    return (lev > 0 ? SZ_L0 : 0) + (lev > 1 ? SZ_L1 : 0) + (lev > 2 ? SZ_L2 : 0);
}

// async global->LDS, 16B per lane; LDS dst must be wave-uniform base
__device__ __forceinline__ void gload16(const void* g, void* l) {
    __builtin_amdgcn_global_load_lds(
        (const __attribute__((address_space(1))) unsigned int*)g,
        (__attribute__((address_space(3))) unsigned int*)l,
        16, 0, 0);
}

// ---------------- fp32 channel-first -> bf16 channel-last transpose ----------------

__global__ __launch_bounds__(256) void cvt_cl_kernel(const float* __restrict__ in,
                                                     __hip_bfloat16* __restrict__ out) {
    __shared__ unsigned int lds[64][97];   // lds[d2][x] = bf16(2*d2) | bf16(2*d2+1)<<16
    const int b = blockIdx.x;      // (k*8+s)*96 + y
    const int y = b % 96;
    const int ks = b / 96;         // k*8+s
    const int k = ks >> 3, s = ks & 7;
    const int tid = threadIdx.x;
    for (int idx = tid; idx < 64 * 24; idx += 256) {
        int d2 = idx / 24, x4 = (idx - d2 * 24) * 4;
        const float* rlo = in + (((size_t)s * 384 + (2 * d2) * 3 + k) * 96 + y) * 96 + x4;
        const float* rhi = in + (((size_t)s * 384 + (2 * d2 + 1) * 3 + k) * 96 + y) * 96 + x4;
        float4 lo = *(const float4*)rlo;
        float4 hi = *(const float4*)rhi;
        lds[d2][x4 + 0] = f2b(lo.x) | (f2b(hi.x) << 16);
        lds[d2][x4 + 1] = f2b(lo.y) | (f2b(hi.y) << 16);
        lds[d2][x4 + 2] = f2b(lo.z) | (f2b(hi.z) << 16);
        lds[d2][x4 + 3] = f2b(lo.w) | (f2b(hi.w) << 16);
    }
    __syncthreads();
    unsigned int* orow = (unsigned int*)((unsigned short*)out + ((size_t)ks * 96 + y) * 96 * 128);
    for (int idx = tid; idx < 96 * 16; idx += 256) {
        int x = idx >> 4, q = idx & 15;
        u32x4 r;
        r[0] = lds[4 * q + 0][x];
        r[1] = lds[4 * q + 1][x];
        r[2] = lds[4 * q + 2][x];
        r[3] = lds[4 * q + 3][x];
        *(u32x4*)(orow + x * 64 + q * 4) = r;
    }
}

// ---------------- 2x2 avg pool, channel-last bf16 ----------------

__global__ __launch_bounds__(256) void pool_cl(const __hip_bfloat16* __restrict__ in,
                                               __hip_bfloat16* __restrict__ out,
                                               int vin, int total8) {
    int idx = blockIdx.x * 256 + threadIdx.x;
    if (idx >= total8) return;
    int vout = vin >> 1;
    int d8 = idx & 15;
    int t = idx >> 4;
    int x = t % vout; t /= vout;
    int y = t % vout; t /= vout;   // t = ks
    const unsigned short* base = (const unsigned short*)in
        + (((size_t)t * vin + 2 * y) * vin + 2 * x) * 128 + d8 * 8;
    short8 a = *(const short8*)(base);
    short8 bq = *(const short8*)(base + 128);
    short8 c = *(const short8*)(base + (size_t)vin * 128);
    short8 d = *(const short8*)(base + (size_t)vin * 128 + 128);
    short8 r;
    #pragma unroll
    for (int j = 0; j < 8; ++j) {
        float sum = b2f((unsigned short)a[j]) + b2f((unsigned short)bq[j])
                  + b2f((unsigned short)c[j]) + b2f((unsigned short)d[j]);
        r[j] = (short)f2b(0.25f * sum);
    }
    *(short8*)((unsigned short*)out + ((((size_t)t * vout + y) * vout + x)) * 128 + d8 * 8) = r;
}

// ---------------- track features, all levels: grid 4*768 ----------------

__global__ __launch_bounds__(256) void tf_all(const __hip_bfloat16* __restrict__ levbase,
                                              const float* __restrict__ coords_init,
                                              __hip_bfloat16* __restrict__ tfb) {
    const int bid = blockIdx.x;
    const int lev = bid / 768;
    const int r0 = bid - lev * 768;
    const int g = (r0 & 7) * 96 + (r0 >> 3);
    const int k = g >> 8;
    const int n = g & 255;
    const int v = lev_v(lev);
    const float inv_scale = 1.f / (float)(1 << lev);
    const float vm1 = (float)(v - 1);
    float cx = coords_init[n * 3 + plane_a(k)] * inv_scale;
    float cy = coords_init[n * 3 + plane_b(k)] * inv_scale;
    const unsigned short* frame = (const unsigned short*)levbase + lev_off(lev)
        + (size_t)(k * 8) * v * v * 128;
    unsigned short* dst = (unsigned short*)tfb + (size_t)lev * SZ_TF
        + ((size_t)(k * NTRK + n)) * (DLAT * CD2);
    for (int idx = threadIdx.x; idx < CD2 * 16; idx += 256) {
        int xy = idx >> 4;
        int c8 = idx & 15;
        int i = xy / CDIM, j = xy % CDIM;
        float X = fminf(fmaxf(cx + (float)(i - 3), 0.f), vm1);
        float Y = fminf(fmaxf(cy + (float)(j - 3), 0.f), vm1);
        float xf = floorf(X), yf = floorf(Y);
        int x0 = (int)xf, y0 = (int)yf;
        int x1 = min(x0 + 1, v - 1), y1 = min(y0 + 1, v - 1);
        float wx = X - xf, wy = Y - yf;
        const unsigned short* r00 = frame + ((size_t)y0 * v + x0) * 128 + c8 * 8;
        const unsigned short* r01 = frame + ((size_t)y0 * v + x1) * 128 + c8 * 8;
        const unsigned short* r10 = frame + ((size_t)y1 * v + x0) * 128 + c8 * 8;
        const unsigned short* r11 = frame + ((size_t)y1 * v + x1) * 128 + c8 * 8;
        short8 a = *(const short8*)r00, bq = *(const short8*)r01;
        short8 c = *(const short8*)r10, d = *(const short8*)r11;
        float w00 = (1.f - wy) * (1.f - wx), w01 = (1.f - wy) * wx;
        float w10 = wy * (1.f - wx), w11 = wy * wx;
        short8 r;
        #pragma unroll
        for (int e = 0; e < 8; ++e) {
            float val = b2f((unsigned short)a[e]) * w00 + b2f((unsigned short)bq[e]) * w01
                      + b2f((unsigned short)c[e]) * w10 + b2f((unsigned short)d[e]) * w11;
            r[e] = (short)f2b(val);
        }
        *(short8*)(dst + xy * 128 + c8 * 8) = r;
    }
}

// ---------------- fused patch-MFMA correlation, s-batched + s-pipelined: grid 3072 ----------------
// bid = lk*256 + n, lk = lev*3 + k. Stage tf once; loop s with the NEXT s's patch
// prefetched into registers during the current s's MFMA/interp phases (T14).
// Patch axis convention (verified r6): output (h,w) samples X=cx+(h-3), Y=cy+(w-3);
// patch pos = py*8+px (px<->x); tap for (h,w) is pos = w*8+h; wx=wxs[h], wy=wys[w].

__global__ __launch_bounds__(256) void corr_all(const __hip_bfloat16* __restrict__ levbase,
                                                const float* __restrict__ coords,
                                                const __hip_bfloat16* __restrict__ tfb,
                                                __hip_bfloat16* __restrict__ c4b) {
    __shared__ __align__(16) char patch[64 * PITCHB];  // P bf16 [pos][dd]; later Cfull fp32 [pos][xy]
    __shared__ __align__(16) char tfs[64 * PITCHB];    // tf bf16 [xy][dd]
    __shared__ float wxs[8], wys[8];
    const int bid = blockIdx.x;
    const int lk = bid >> 8;          // lev*3 + k
    const int n = bid & 255;
    const int lev = lk / 3;
    const int k = lk - lev * 3;
    const int v = lev_v(lev);
    const int vv = v * v;
    const float inv_scale = 1.f / (float)(1 << lev);
    const int tid = threadIdx.x;
    const float vm1 = (float)(v - 1);

    // stage tf once (s-invariant)
    const short8* tfg = (const short8*)(tfb + (size_t)lev * SZ_TF
        + ((size_t)(k * NTRK + n)) * (DLAT * CD2));
    for (int idx = tid; idx < 784; idx += 256) {
        int row = idx >> 4, c16 = idx & 15;
        *(short8*)(tfs + row * PITCHB + c16 * 16) = tfg[idx];
    }

    // per-thread interp decode, computed once: hw = hwb + 5*it, xy fixed
    const int hwb = tid / 49;           // 0..5 (valid <245)
    const int xy  = tid - hwb * 49;
    const bool act = tid < 245;

    const unsigned short* fbase = (const unsigned short*)levbase + lev_off(lev)
        + (size_t)(k * 8) * vv * 128;
    const int w4 = tid >> 6, l = tid & 63;
    const int l15 = l & 15, l4 = l >> 4;

    // per-lane staging geometry: pos = posb + 16q, fixed c8
    const int c8 = tid & 15;
    const int posb = tid >> 4;

    float cxc, cyc; int fxc, fyc;
    short8 pre[4];

    auto CALC = [&](int s) {
        const int sn = s * 256 + n;
        cxc = coords[sn * 3 + plane_a(k)] * inv_scale;
        cyc = coords[sn * 3 + plane_b(k)] * inv_scale;
        fxc = (int)floorf(cxc);
        fyc = (int)floorf(cyc);
    };
    auto PREF = [&](int s) {
        const unsigned short* frame = fbase + (size_t)s * vv * 128;
        #pragma unroll
        for (int q = 0; q < 4; ++q) {
            int pos = posb + 16 * q;
            int px = pos & 7, py = pos >> 3;
            int gx = min(max(fxc + px - 3, 0), v - 1);
            int gy = min(max(fyc + py - 3, 0), v - 1);
            pre[q] = *(const short8*)(frame + ((size_t)gy * v + gx) * 128 + c8 * 8);
        }
    };

    CALC(0); PREF(0);
    for (int s = 0; s < 8; ++s) {
        const float cx = cxc, cy = cyc;
        const int fx = fxc, fy = fyc;
        // block-uniform interpolation weights (0 at clamped taps)
        if (tid < 7) {
            float X = fminf(fmaxf(cx + (float)(tid - 3), 0.f), vm1);
            int g = min(max(fx + tid - 3, 0), v - 1);
            wxs[tid] = X - (float)g;
            float Y = fminf(fmaxf(cy + (float)(tid - 3), 0.f), vm1);
            int gy_ = min(max(fy + tid - 3, 0), v - 1);
            wys[tid] = Y - (float)gy_;
        }
        // commit prefetched patch to LDS
        #pragma unroll
        for (int q = 0; q < 4; ++q)
            *(short8*)(patch + (posb + 16 * q) * PITCHB + c8 * 16) = pre[q];
        __syncthreads();

        f32x4 acc[4];
        #pragma unroll
        for (int nt = 0; nt < 4; ++nt) acc[nt] = (f32x4){0.f, 0.f, 0.f, 0.f};
        #pragma unroll
        for (int ks = 0; ks < 4; ++ks) {
            short8 af = *(const short8*)(patch + (16 * w4 + l15) * PITCHB + ks * 64 + l4 * 16);
            #pragma unroll
            for (int nt = 0; nt < 4; ++nt) {
                short8 bf = *(const short8*)(tfs + (16 * nt + l15) * PITCHB + ks * 64 + l4 * 16);
                acc[nt] = __builtin_amdgcn_mfma_f32_16x16x32_bf16(af, bf, acc[nt], 0, 0, 0);
            }
        }
        // issue next-s global loads; they complete under Cfull+interp phases
        if (s < 7) { CALC(s + 1); PREF(s + 1); }
        __syncthreads();  // all patch reads done before overwrite

        // write Cfull fp32 [pos][xy] into the patch region
        {
            const int row0 = 16 * w4 + l4 * 4;
            #pragma unroll
            for (int nt = 0; nt < 4; ++nt) {
                int col = nt * 16 + l15;
                #pragma unroll
                for (int j = 0; j < 4; ++j)
                    *(float*)(patch + (row0 + j) * PITCHB + col * 4) = acc[nt][j];
            }
        }
        __syncthreads();

        // division-free 4-tap interpolation; output (h,w): tap pos = w*8+h
        unsigned short* crow = (unsigned short*)c4b + ((size_t)lk * 2048 + s * 256 + n) * LDK;
        if (act) {
            int h = 0, w = hwb;
            unsigned short* op = crow + tid;   // hwb*49 + xy == tid
            const char* colbase = patch + xy * 4;
            #pragma unroll
            for (int it = 0; it < 10; ++it) {
                if (h < 7) {
                    float wxv = wxs[h], wyv = wys[w];
                    const char* tap = colbase + (w * 8 + h) * PITCHB;
                    float p00 = *(const float*)(tap);
                    float p01 = *(const float*)(tap + PITCHB);        // x+1
                    float p10 = *(const float*)(tap + 8 * PITCHB);    // y+1
                    float p11 = *(const float*)(tap + 9 * PITCHB);
                    float a  = fmaf(wxv, p01 - p00, p00);
                    float bq = fmaf(wxv, p11 - p10, p10);
                    *op = (unsigned short)f2b(fmaf(wyv, bq - a, a));
                }
                w += 5; if (w >= 7) { w -= 7; h += 1; }
                op += 245;
            }
        }
        if (tid < LDK - CD4) crow[CD4 + tid] = 0;   // bf16 zero pad
        __syncthreads();  // interp reads done before next-s staging
    }
}

// ---------------- weight prep: coalesced LDS-tile transpose + bf16 ----------------
// w1 [CD4][NH1] fp32 -> w1t [NH1][LDK] bf16 (pad zeroed). grid (38, 6), 64x64 tiles.

__global__ __launch_bounds__(256) void prep_w1t(const float* __restrict__ w1,
                                                __hip_bfloat16* __restrict__ w1t) {
    __shared__ float t[64][65];
    const int kk0 = blockIdx.x * 64, n0 = blockIdx.y * 64;
    const int tid = threadIdx.x;
    for (int idx = tid; idx < 4096; idx += 256) {
        int r = idx >> 6, c = idx & 63;        // r: kk offset, c: n offset
        int kk = kk0 + r;
        t[r][c] = (kk < CD4) ? w1[(size_t)kk * NH1 + n0 + c] : 0.f;
    }
    __syncthreads();
    for (int idx = tid; idx < 4096; idx += 256) {
        int r = idx >> 6, c = idx & 63;        // r: n offset, c: kk offset
        w1t[(size_t)(n0 + r) * LDK + kk0 + c] = __float2bfloat16(t[c][r]);
    }
}

__global__ __launch_bounds__(256) void prep_w2t(const float* __restrict__ w2,
                                                __hip_bfloat16* __restrict__ w2t) {
    int idx = blockIdx.x * 256 + threadIdx.x;  // n*NH1 + j
    if (idx >= NH2 * NH1) return;
    int n = idx / NH1, j = idx - n * NH1;
    w2t[idx] = __float2bfloat16(w2[(size_t)j * NH2 + n]);
}

// ---------------- GEMM1 MFMA, all levels: (24576 x LDK) @ w1t^T -> gelu -> H bf16 ----------------
// BM=128 BN=128 BK=32, 4 waves (2x2), wave tile 64x64 = 4x4 frags; grid (192, 3)

__global__ __launch_bounds__(256) void gemm1_all(
    const __hip_bfloat16* __restrict__ A,    // [24576][LDK]
    const __hip_bfloat16* __restrict__ Bt,   // [NH1][LDK]
    const float* __restrict__ b1,
    __hip_bfloat16* __restrict__ H) {        // [24576][NH1]
    __shared__ __align__(16) char smem[16384];
    char* Asm = smem;          // 128 rows x 64B
    char* Bsm = smem + 8192;   // 128 rows x 64B
    const int m0 = blockIdx.x * 128, n0 = blockIdx.y * 128;
    const int tid = threadIdx.x;
    const int w = tid >> 6, l = tid & 63;
    const int wr = w >> 1, wc = w & 1;
    const int l15 = l & 15, l4 = l >> 4;
    f32x4 acc[4][4];
    #pragma unroll
    for (int m = 0; m < 4; ++m)
        #pragma unroll
        for (int n = 0; n < 4; ++n) acc[m][n] = (f32x4){0.f, 0.f, 0.f, 0.f};
    const char* Ag = (const char*)(A + (size_t)(m0 + (tid >> 2)) * LDK) + (tid & 3) * 16;
    const char* Bg = (const char*)(Bt + (size_t)(n0 + (tid >> 2)) * LDK) + (tid & 3) * 16;
    char* AsmW = Asm + w * 1024;
    char* BsmW = Bsm + w * 1024;
    for (int kb = 0; kb < LDK * 2; kb += 64) {  // byte offset along K
        gload16(Ag + kb, AsmW);
        gload16(Ag + (size_t)64 * LDK * 2 + kb, AsmW + 4096);
        gload16(Bg + kb, BsmW);
        gload16(Bg + (size_t)64 * LDK * 2 + kb, BsmW + 4096);
        __syncthreads();
        short8 af[4], bfr[4];
        #pragma unroll
        for (int m = 0; m < 4; ++m)
            af[m] = *(const short8*)(Asm + (wr * 64 + m * 16 + l15) * 64 + l4 * 16);
        #pragma unroll
        for (int n = 0; n < 4; ++n)
            bfr[n] = *(const short8*)(Bsm + (wc * 64 + n * 16 + l15) * 64 + l4 * 16);
        #pragma unroll
        for (int m = 0; m < 4; ++m)
            #pragma unroll
            for (int n = 0; n < 4; ++n)
                acc[m][n] = __builtin_amdgcn_mfma_f32_16x16x32_bf16(af[m], bfr[n], acc[m][n], 0, 0, 0);
        __syncthreads();
    }
    #pragma unroll
    for (int m = 0; m < 4; ++m) {
        int row = m0 + wr * 64 + m * 16 + l4 * 4;
        #pragma unroll
        for (int n = 0; n < 4; ++n) {
            int col = n0 + wc * 64 + n * 16 + l15;
            float bias = b1[col];
            #pragma unroll
            for (int j = 0; j < 4; ++j)
                H[(size_t)(row + j) * NH1 + col] = __float2bfloat16(gelu_tanh(acc[m][n][j] + bias));
        }
    }
}

// ---------------- GEMM2 MFMA, all levels: per level (2048 x 1152) -> out slice ----------------

__global__ __launch_bounds__(256) void gemm2_all(
    const __hip_bfloat16* __restrict__ Hin,  // [4][3][2048][NH1]
    const __hip_bfloat16* __restrict__ Bt,   // [NH2][NH1]
    const float* __restrict__ b2,
    float* __restrict__ out) {
    __shared__ __align__(16) char smem[8192];
    char* Asm = smem;         // 64 rows x 64B
    char* Bsm = smem + 4096;
    const int lev = blockIdx.x >> 5;
    const int m0 = (blockIdx.x & 31) * 64, n0 = blockIdx.y * 64;
    const int tid = threadIdx.x;
    const int w = tid >> 6, l = tid & 63;
    const int wr = w >> 1, wc = w & 1;
    const int l15 = l & 15, l4 = l >> 4;
    f32x4 acc[2][2];
    #pragma unroll
    for (int m = 0; m < 2; ++m)
        #pragma unroll
        for (int n = 0; n < 2; ++n) acc[m][n] = (f32x4){0.f, 0.f, 0.f, 0.f};
    const char* Bg = (const char*)(Bt + (size_t)(n0 + (tid >> 2)) * NH1) + (tid & 3) * 16;
    char* AsmW = Asm + w * 1024;
    char* BsmW = Bsm + w * 1024;
    for (int p = 0; p < 3; ++p) {
        const char* Ag = (const char*)(Hin
            + (size_t)((lev * 3 + p) * 2048 + m0 + (tid >> 2)) * NH1) + (tid & 3) * 16;
        for (int jb = 0; jb < NH1 * 2; jb += 64) {
            gload16(Ag + jb, AsmW);
            gload16(Bg + jb, BsmW);
            __syncthreads();
            short8 af[2], bfr[2];
            #pragma unroll
            for (int m = 0; m < 2; ++m)
                af[m] = *(const short8*)(Asm + (wr * 32 + m * 16 + l15) * 64 + l4 * 16);
            #pragma unroll
            for (int n = 0; n < 2; ++n)
                bfr[n] = *(const short8*)(Bsm + (wc * 32 + n * 16 + l15) * 64 + l4 * 16);
            #pragma unroll
            for (int m = 0; m < 2; ++m)
                #pragma unroll
                for (int n = 0; n < 2; ++n)
                    acc[m][n] = __builtin_amdgcn_mfma_f32_16x16x32_bf16(af[m], bfr[n], acc[m][n], 0, 0, 0);
            __syncthreads();
        }
    }
    #pragma unroll
    for (int m = 0; m < 2; ++m) {
        int row = m0 + wr * 32 + m * 16 + l4 * 4;
        #pragma unroll
        for (int n = 0; n < 2; ++n) {
            int col = n0 + wc * 32 + n * 16 + l15;
            float bias3 = 3.f * b2[col];
            #pragma unroll
            for (int j = 0; j < 4; ++j)
                out[(size_t)(row + j) * 1024 + lev * NH2 + col] = acc[m][n][j] + bias3;
        }
    }
}

// ---------------- launch ----------------

extern "C" void kernel_launch(void* const* d_in, const int* in_sizes, int n_in,
                              void* d_out, int out_size, void* d_ws, size_t ws_size,
                              hipStream_t stream) {
    const float* coords      = (const float*)d_in[0];
    const float* coords_init = (const float*)d_in[1];
    const float* fp0         = (const float*)d_in[2];
    const float* w1          = (const float*)d_in[3];
    const float* b1          = (const float*)d_in[4];
    const float* w2          = (const float*)d_in[5];
    const float* b2          = (const float*)d_in[6];
    float* out = (float*)d_out;
    char* ws = (char*)d_ws;

    __hip_bfloat16* lev0 = (__hip_bfloat16*)ws;      ws += SZ_L0 * 2;
    __hip_bfloat16* lev1 = (__hip_bfloat16*)ws;      ws += SZ_L1 * 2;
    __hip_bfloat16* lev2 = (__hip_bfloat16*)ws;      ws += SZ_L2 * 2;
    __hip_bfloat16* lev3 = (__hip_bfloat16*)ws;      ws += SZ_L3 * 2;
    __hip_bfloat16* tfb  = (__hip_bfloat16*)ws;      ws += (size_t)4 * SZ_TF * 2;
    __hip_bfloat16* c4b  = (__hip_bfloat16*)ws;      ws += (size_t)24576 * LDK * 2;
    __hip_bfloat16* h_ws = (__hip_bfloat16*)ws;      ws += (size_t)24576 * NH1 * 2;
    __hip_bfloat16* w1t  = (__hip_bfloat16*)ws;      ws += (size_t)NH1 * LDK * 2;
    __hip_bfloat16* w2t  = (__hip_bfloat16*)ws;      ws += (size_t)NH2 * NH1 * 2;

    prep_w1t<<<dim3(38, 6), 256, 0, stream>>>(w1, w1t);
    prep_w2t<<<(NH2 * NH1 + 255) / 256, 256, 0, stream>>>(w2, w2t);

    cvt_cl_kernel<<<24 * 96, 256, 0, stream>>>(fp0, lev0);
    pool_cl<<<(int)((SZ_L1 / 8 + 255) / 256), 256, 0, stream>>>(lev0, lev1, 96, (int)(SZ_L1 / 8));
    pool_cl<<<(int)((SZ_L2 / 8 + 255) / 256), 256, 0, stream>>>(lev1, lev2, 48, (int)(SZ_L2 / 8));
    pool_cl<<<(int)((SZ_L3 / 8 + 255) / 256), 256, 0, stream>>>(lev2, lev3, 24, (int)(SZ_L3 / 8));

    tf_all<<<4 * 768, 256, 0, stream>>>(lev0, coords_init, tfb);
    corr_all<<<3072, 256, 0, stream>>>(lev0, coords, tfb, c4b);
    gemm1_all<<<dim3(192, 3), 256, 0, stream>>>(c4b, w1t, b1, h_ws);
    gemm2_all<<<dim3(128, 4), 256, 0, stream>>>(h_ws, w2t, b2, out);
}